// Round 2
// baseline (1735.587 us; speedup 1.0000x reference)
//
#include <hip/hip_runtime.h>
#include <cstdint>
#include <cstddef>

#define DEVINL __device__ __forceinline__

typedef float    f32x4 __attribute__((ext_vector_type(4)));
typedef _Float16 f16x8 __attribute__((ext_vector_type(8)));
typedef _Float16 f16x4 __attribute__((ext_vector_type(4)));

// ---------------- constants ----------------
constexpr int BB = 16, NN = 2048, MM = 32768;

// ---------------- ws layout (bytes) ----------------
constexpr size_t OFF_WE1 = 0;                          // 128x32 f16
constexpr size_t OFF_WE2 = OFF_WE1 + 128 * 32 * 2;
constexpr size_t OFF_W1  = OFF_WE2 + 128 * 128 * 2;
constexpr size_t OFF_W2  = OFF_W1  + 3 * 128 * 128 * 2;
constexpr size_t OFF_WF  = OFF_W2  + 3 * 128 * 128 * 2;
constexpr size_t OFF_WC1 = OFF_WF  + 1024 * 384 * 2;
constexpr size_t OFF_WC2 = OFF_WC1 + 512 * 1024 * 2;
constexpr size_t OFF_WC3 = OFF_WC2 + 256 * 512 * 2;
constexpr size_t OFF_BC2 = OFF_WC3 + 64 * 256 * 2;     // 256 f32
constexpr size_t OFF_BC3 = OFF_BC2 + 256 * 4;          // 64 f32
constexpr size_t OFF_CVEC= OFF_BC3 + 64 * 4;           // 16x512 f32
constexpr size_t OFF_XMAX= OFF_CVEC+ 16 * 512 * 4;
constexpr size_t OFF_XAVG= OFF_XMAX+ 16 * 1024 * 4;
constexpr size_t OFF_PMAX= OFF_XAVG+ 16 * 1024 * 4;
constexpr size_t OFF_PSUM= OFF_PMAX+ 16 * 8 * 1024 * 4;
constexpr size_t OFF_IDX = OFF_PSUM+ 16 * 8 * 1024 * 4;
constexpr size_t OFF_R1  = 6ull << 20;                 // > OFF_IDX + 2MB
constexpr size_t OFF_X0  = OFF_R1;                     // 2MB  (M x 32 f16)
constexpr size_t OFF_HT  = OFF_R1 + (2ull  << 20);     // 8MB  (M x 128 f16)
constexpr size_t OFF_TT  = OFF_R1 + (10ull << 20);     // 8MB
constexpr size_t OFF_MT  = OFF_R1 + (18ull << 20);     // 8MB
constexpr size_t OFF_C1  = OFF_R1;                     // 32MB (M x 512 f16), aliases x0/h/t/m (dead)
constexpr size_t OFF_XCAT= OFF_R1 + (32ull << 20);     // 24MB (M x 384 f16)
constexpr size_t OFF_C2  = OFF_XCAT;                   // 16MB (M x 256 f16), aliases xcat (dead)
constexpr size_t OFF_XF  = OFF_XCAT + (24ull << 20);   // 64MB (M x 1024 f16)
constexpr size_t OFF_C3  = OFF_XF;                     // 8MB  (M x 64 f32), aliases xf (dead)

// ---------------- weight folding: dst[o*Kp+k] = f16( W[o,k] * g[o] ), zero-padded ----------------
__global__ __launch_bounds__(256) void fold_w_kernel(
    const float* We1, const float* ge1, const float* We2, const float* ge2,
    const float* W1,  const float* g1,  const float* W2,  const float* g2,
    const float* Wf,  const float* gf,  const float* Wc1, const float* gc1,
    const float* Wc2, const float* gc2, const float* Wc3, char* ws)
{
    const int id = blockIdx.y;
    const float* src = nullptr; const float* g = nullptr; _Float16* dst = nullptr;
    int O = 0, K = 0, lds = 0, Kp = 0, Opad = 0;
    switch (id) {
        case 0:  src = We1; g = ge1; O = 128; K = 6;    lds = 6;    Kp = 32;   Opad = 128; dst = (_Float16*)(ws + OFF_WE1); break;
        case 1:  src = We2; g = ge2; O = 128; K = 128;  lds = 128;  Kp = 128;  Opad = 128; dst = (_Float16*)(ws + OFF_WE2); break;
        case 2: case 3: case 4: {
            int i = id - 2;
            src = W1 + (size_t)i * 16384; g = g1 + i * 128; O = 128; K = 128; lds = 128; Kp = 128; Opad = 128;
            dst = (_Float16*)(ws + OFF_W1) + (size_t)i * 16384; break; }
        case 5: case 6: case 7: {
            int i = id - 5;
            src = W2 + (size_t)i * 16384; g = g2 + i * 128; O = 128; K = 128; lds = 128; Kp = 128; Opad = 128;
            dst = (_Float16*)(ws + OFF_W2) + (size_t)i * 16384; break; }
        case 8:  src = Wf;  g = gf;  O = 1024; K = 384;  lds = 384;  Kp = 384;  Opad = 1024; dst = (_Float16*)(ws + OFF_WF);  break;
        case 9:  src = Wc1; g = gc1; O = 512;  K = 1024; lds = 3136; Kp = 1024; Opad = 512;  dst = (_Float16*)(ws + OFF_WC1); break;
        case 10: src = Wc2; g = gc2; O = 256;  K = 512;  lds = 512;  Kp = 512;  Opad = 256;  dst = (_Float16*)(ws + OFF_WC2); break;
        default: src = Wc3; g = nullptr; O = 50; K = 256; lds = 256; Kp = 256;  Opad = 64;   dst = (_Float16*)(ws + OFF_WC3); break;
    }
    int e = blockIdx.x * 256 + threadIdx.x;
    if (e >= Opad * Kp) return;
    int o = e / Kp, k = e - o * Kp;
    float v = 0.f;
    if (o < O && k < K) {
        v = src[(size_t)o * lds + k];
        if (g) v *= g[o];
    }
    dst[e] = (_Float16)v;
}

// ---------------- bias folding (only the two that need compute) ----------------
__global__ __launch_bounds__(256) void fold_bias_kernel(
    const float* gc2, const float* bc2, const float* bb2, const float* bc3, char* ws)
{
    const int id = blockIdx.x, tid = threadIdx.x;
    if (id == 0) {
        ((float*)(ws + OFF_BC2))[tid] = gc2[tid] * bc2[tid] + bb2[tid];
    } else if (tid < 64) {
        ((float*)(ws + OFF_BC3))[tid] = (tid < 50) ? bc3[tid] : 0.f;
    }
}

// ---------------- x0 prep: (B,6,N) f32 -> (M x 32) f16 K-contig, zero pad ----------------
__global__ __launch_bounds__(256) void x0prep_kernel(const float* __restrict__ pts, _Float16* __restrict__ x0)
{
    int m = blockIdx.x * 256 + threadIdx.x;
    int b = m >> 11, n = m & 2047;
    const float* ps = pts + (size_t)b * 6 * 2048 + n;
    _Float16 tmp[32];
#pragma unroll
    for (int c = 0; c < 32; ++c) tmp[c] = (_Float16)0.f;
#pragma unroll
    for (int c = 0; c < 6; ++c) tmp[c] = (_Float16)ps[(size_t)c << 11];
    _Float16* dst = x0 + (size_t)m * 32;
#pragma unroll
    for (int v = 0; v < 4; ++v) *(f16x8*)(dst + v * 8) = *(const f16x8*)(tmp + v * 8);
}

// ---------------- KNN: top-16 smallest d = |q|^2+|p|^2-2 q.p (all f32) ----------------
__global__ __launch_bounds__(256) void knn_kernel(const float* __restrict__ pts, int* __restrict__ idxout)
{
    __shared__ float4 P[2048];
    const int b = blockIdx.x, tid = threadIdx.x;
    const float* pb = pts + (size_t)b * 6 * 2048;
    for (int i = tid; i < 2048; i += 256) {
        float x = pb[i];
        float y = pb[2048 + i];
        float z = pb[4096 + i];
        P[i] = make_float4(x, y, z, x * x + y * y + z * z);
    }
    __syncthreads();
    const int q = blockIdx.y * 256 + tid;
    const float4 pq = P[q];
    float dist[16]; int idv[16];
#pragma unroll
    for (int j = 0; j < 16; ++j) { dist[j] = 3.4e38f; idv[j] = 0; }
    for (int m = 0; m < 2048; ++m) {
        float4 pm = P[m];
        float d = pq.w + pm.w - 2.f * (pq.x * pm.x + pq.y * pm.y + pq.z * pm.z);
        if (d < dist[15]) {
            dist[15] = d; idv[15] = m;
#pragma unroll
            for (int j = 15; j > 0; --j) {
                if (dist[j] < dist[j - 1]) {
                    float td = dist[j]; dist[j] = dist[j - 1]; dist[j - 1] = td;
                    int ti = idv[j]; idv[j] = idv[j - 1]; idv[j - 1] = ti;
                }
            }
        }
    }
    int* op = idxout + ((size_t)(b * 2048 + q)) * 16;
#pragma unroll
    for (int j = 0; j < 16; ++j) op[j] = idv[j];
}

// ---------------- GEMM: Y[m, yoff+o] = act( W(Opad x Kp) . X[m, xoff+:] + bias (+ Res) ) ----------------
// block: 256 thr = 4 waves; tile 128(m) x 64(o); wave: 16 o x 128 m (8 MFMA chains)
// If Y32 != nullptr, stores f32 to Y32 instead of f16 to Y.
__global__ __launch_bounds__(256) void gemm_bt(
    const _Float16* __restrict__ W, const _Float16* __restrict__ X,
    _Float16* __restrict__ Y, float* __restrict__ Y32,
    const float* __restrict__ bias, const _Float16* __restrict__ Res,
    int Kp, int ldX, int xoff, int ldY, int yoff, int Opad,
    int act, int biasPerBatch, int ldR, int roff)
{
    const int tid  = threadIdx.x;
    const int wave = tid >> 6;
    const int lane = tid & 63;
    const int r    = lane & 15;
    const int quad = lane >> 4;
    const int m_base = blockIdx.x * 128;
    const int o_base = blockIdx.y * 64 + wave * 16;

    f32x4 acc[8];
#pragma unroll
    for (int s = 0; s < 8; ++s) acc[s] = (f32x4){0.f, 0.f, 0.f, 0.f};

    const _Float16* Ap = W + (size_t)(o_base + r) * Kp + quad * 8;
    const _Float16* Bp = X + (size_t)(m_base + r) * ldX + xoff + quad * 8;
    const size_t bstep = (size_t)16 * ldX;

    for (int k = 0; k < Kp; k += 32) {
        f16x8 a = *(const f16x8*)(Ap + k);
#pragma unroll
        for (int s = 0; s < 8; ++s) {
            f16x8 bfrag = *(const f16x8*)(Bp + (size_t)s * bstep + k);
            acc[s] = __builtin_amdgcn_mfma_f32_16x16x32_f16(a, bfrag, acc[s], 0, 0, 0);
        }
    }

    const int o0 = o_base + quad * 4;
    const float* bptr = bias + (biasPerBatch ? (size_t)(m_base >> 11) * Opad : (size_t)0);
    const f32x4 bv = *(const f32x4*)(bptr + o0);

#pragma unroll
    for (int s = 0; s < 8; ++s) {
        int m = m_base + s * 16 + r;
        f32x4 v = acc[s] + bv;
        if (Res) {
            f16x4 rr = *(const f16x4*)(Res + (size_t)m * ldR + roff + o0);
#pragma unroll
            for (int j = 0; j < 4; ++j) v[j] += (float)rr[j];
        }
#pragma unroll
        for (int j = 0; j < 4; ++j) {
            float x = v[j];
            if (act == 1)      x = (x > 0.f) ? x : 0.0f;   // relu, +0 guaranteed
            else if (act == 2) x = (x > 0.f) ? x : 0.2f * x;
            v[j] = x;
        }
        if (Y32) {
            *(f32x4*)(Y32 + (size_t)m * ldY + yoff + o0) = v;
        } else {
            f16x4 ov;
#pragma unroll
            for (int j = 0; j < 4; ++j) ov[j] = (_Float16)v[j];
            *(f16x4*)(Y + (size_t)m * ldY + yoff + o0) = ov;
        }
    }
}

// ---------------- neighbor gather + channel max (relu outputs => ushort-monotonic f16 bits) ----------------
typedef short s16x8 __attribute__((ext_vector_type(8)));
__global__ __launch_bounds__(256) void gather_max_kernel(
    const short* __restrict__ T, const int* __restrict__ idx, short* __restrict__ Mo)
{
    const int tid = threadIdx.x;
    const int p = blockIdx.x * 16 + (tid >> 4);
    const int l = tid & 15;
    const int b = p >> 11;
    const int* ip = idx + (size_t)p * 16;
    size_t row = (size_t)((b << 11) + ip[0]);
    s16x8 cur = *(const s16x8*)(T + row * 128 + l * 8);
    unsigned short best[8];
#pragma unroll
    for (int e = 0; e < 8; ++e) best[e] = (unsigned short)cur[e];
#pragma unroll
    for (int j = 1; j < 16; ++j) {
        row = (size_t)((b << 11) + ip[j]);
        s16x8 v = *(const s16x8*)(T + row * 128 + l * 8);
#pragma unroll
        for (int e = 0; e < 8; ++e) {
            unsigned short u = (unsigned short)v[e];
            if (u > best[e]) best[e] = u;
        }
    }
    s16x8 ov;
#pragma unroll
    for (int e = 0; e < 8; ++e) ov[e] = (short)best[e];
    *(s16x8*)(Mo + (size_t)p * 128 + l * 8) = ov;
}

// ---------------- pooling reductions over n ----------------
__global__ __launch_bounds__(256) void reduce1_kernel(const _Float16* __restrict__ xf, float* __restrict__ pmax, float* __restrict__ psum)
{
    const int b = blockIdx.x, oc = blockIdx.y, ch = blockIdx.z, tid = threadIdx.x;
    const int o = oc * 256 + tid;
    const _Float16* p = xf + ((size_t)(b << 11) + ch * 256) * 1024 + o;
    float mx = -3.4e38f, sm = 0.f;
    for (int n = 0; n < 256; ++n) {
        float v = (float)p[(size_t)n * 1024];
        mx = fmaxf(mx, v); sm += v;
    }
    pmax[((size_t)(b * 8 + ch) << 10) + o] = mx;
    psum[((size_t)(b * 8 + ch) << 10) + o] = sm;
}

__global__ __launch_bounds__(256) void reduce2_kernel(const float* __restrict__ pmax, const float* __restrict__ psum,
                                                      float* __restrict__ xmax, float* __restrict__ xavg)
{
    const int b = blockIdx.x, oc = blockIdx.y, tid = threadIdx.x;
    const int o = oc * 256 + tid;
    float mx = -3.4e38f, sm = 0.f;
#pragma unroll
    for (int c = 0; c < 8; ++c) {
        mx = fmaxf(mx, pmax[((size_t)(b * 8 + c) << 10) + o]);
        sm += psum[((size_t)(b * 8 + c) << 10) + o];
    }
    xmax[((size_t)b << 10) + o] = mx;
    xavg[((size_t)b << 10) + o] = sm * (1.f / 2048.f);
}

// ---------------- per-batch constant vector for Wc1 (broadcast cols 1024..3135 + bias/bn) ----------------
__global__ __launch_bounds__(256) void cvec_kernel(
    const float* __restrict__ label, const float* __restrict__ Wl, const float* __restrict__ gl, const float* __restrict__ bl,
    const float* __restrict__ Wc1, const float* __restrict__ bc1, const float* __restrict__ gc1, const float* __restrict__ bb1,
    const float* __restrict__ xmax, const float* __restrict__ xavg, float* __restrict__ cvec)
{
    __shared__ float v[2112];
    __shared__ float red[256];
    const int b = blockIdx.x, og = blockIdx.y, tid = threadIdx.x;
    for (int i = tid; i < 1024; i += 256) v[i] = xmax[((size_t)b << 10) + i];
    for (int i = tid; i < 1024; i += 256) v[1024 + i] = xavg[((size_t)b << 10) + i];
    if (tid < 64) {
        float s = 0.f;
        for (int i = 0; i < 16; ++i) s += Wl[tid * 16 + i] * label[b * 16 + i];
        s = gl[tid] * s + bl[tid];
        v[2048 + tid] = (s > 0.f) ? s : 0.2f * s;
    }
    __syncthreads();
    const int o = og * 64 + (tid >> 2), part = tid & 3;
    const float* wrow = Wc1 + (size_t)o * 3136 + 1024 + part * 528;
    float s = 0.f;
    for (int j = 0; j < 528; ++j) s += wrow[j] * v[part * 528 + j];
    red[tid] = s;
    __syncthreads();
    if (part == 0) {
        float tot = red[tid] + red[tid + 1] + red[tid + 2] + red[tid + 3];
        cvec[((size_t)b << 9) + o] = gc1[o] * (tot + bc1[o]) + bb1[o];
    }
}

// ---------------- final layout (M x 64 f32) -> (B,50,N) f32 ----------------
__global__ __launch_bounds__(256) void reformat_kernel(const float* __restrict__ c3, float* __restrict__ out)
{
    int i = blockIdx.x * 256 + threadIdx.x;       // 16*50*2048 total
    int n = i & 2047;
    int t = i >> 11;        // b*50 + o
    int o = t % 50;
    int b = t / 50;
    out[i] = c3[((size_t)((b << 11) + n)) * 64 + o];
}

// ---------------- launch ----------------
extern "C" void kernel_launch(void* const* d_in, const int* in_sizes, int n_in,
                              void* d_out, int out_size, void* d_ws, size_t ws_size,
                              hipStream_t stream)
{
    (void)in_sizes; (void)n_in; (void)out_size; (void)ws_size;
    const float* points = (const float*)d_in[0];
    const float* label  = (const float*)d_in[1];
    const float* We1 = (const float*)d_in[2];
    const float* ge1 = (const float*)d_in[3];
    const float* be1 = (const float*)d_in[4];
    const float* We2 = (const float*)d_in[5];
    const float* ge2 = (const float*)d_in[6];
    const float* be2 = (const float*)d_in[7];
    const float* W1  = (const float*)d_in[8];
    const float* g1  = (const float*)d_in[9];
    const float* b1  = (const float*)d_in[10];
    const float* W2  = (const float*)d_in[11];
    const float* g2  = (const float*)d_in[12];
    const float* b2  = (const float*)d_in[13];
    const float* Wf  = (const float*)d_in[14];
    const float* gf  = (const float*)d_in[15];
    const float* bfv = (const float*)d_in[16];
    const float* Wl  = (const float*)d_in[17];
    const float* gl  = (const float*)d_in[18];
    const float* bl  = (const float*)d_in[19];
    const float* Wc1 = (const float*)d_in[20];
    const float* bc1 = (const float*)d_in[21];
    const float* gc1 = (const float*)d_in[22];
    const float* bb1 = (const float*)d_in[23];
    const float* Wc2 = (const float*)d_in[24];
    const float* bc2 = (const float*)d_in[25];
    const float* gc2 = (const float*)d_in[26];
    const float* bb2 = (const float*)d_in[27];
    const float* Wc3 = (const float*)d_in[28];
    const float* bc3 = (const float*)d_in[29];

    char* ws = (char*)d_ws;
    _Float16* x0  = (_Float16*)(ws + OFF_X0);
    _Float16* hT  = (_Float16*)(ws + OFF_HT);
    _Float16* tT  = (_Float16*)(ws + OFF_TT);
    _Float16* mT  = (_Float16*)(ws + OFF_MT);
    _Float16* xct = (_Float16*)(ws + OFF_XCAT);
    _Float16* xf  = (_Float16*)(ws + OFF_XF);
    _Float16* c1  = (_Float16*)(ws + OFF_C1);
    _Float16* c2  = (_Float16*)(ws + OFF_C2);
    float*    c3  = (float*)   (ws + OFF_C3);
    int*      idx = (int*)     (ws + OFF_IDX);

    _Float16* wE1 = (_Float16*)(ws + OFF_WE1);
    _Float16* wE2 = (_Float16*)(ws + OFF_WE2);
    _Float16* w1f = (_Float16*)(ws + OFF_W1);
    _Float16* w2f = (_Float16*)(ws + OFF_W2);
    _Float16* wF  = (_Float16*)(ws + OFF_WF);
    _Float16* wC1 = (_Float16*)(ws + OFF_WC1);
    _Float16* wC2 = (_Float16*)(ws + OFF_WC2);
    _Float16* wC3 = (_Float16*)(ws + OFF_WC3);
    float* bC2 = (float*)(ws + OFF_BC2);
    float* bC3 = (float*)(ws + OFF_BC3);
    float* cv  = (float*)(ws + OFF_CVEC);
    float* xmx = (float*)(ws + OFF_XMAX);
    float* xav = (float*)(ws + OFF_XAVG);
    float* pmx = (float*)(ws + OFF_PMAX);
    float* psm = (float*)(ws + OFF_PSUM);

    // prep
    fold_w_kernel<<<dim3(2048, 12), 256, 0, stream>>>(We1, ge1, We2, ge2, W1, g1, W2, g2, Wf, gf, Wc1, gc1, Wc2, gc2, Wc3, ws);
    fold_bias_kernel<<<dim3(2), 256, 0, stream>>>(gc2, bc2, bb2, bc3, ws);
    x0prep_kernel<<<dim3(MM / 256), 256, 0, stream>>>(points, x0);
    knn_kernel<<<dim3(BB, NN / 256), 256, 0, stream>>>(points, idx);

    // e1: x0(Mx32) -> tT(Mx128), relu
    gemm_bt<<<dim3(256, 2), 256, 0, stream>>>(wE1, x0, tT, nullptr, be1, nullptr, 32, 32, 0, 128, 0, 128, 1, 0, 0, 0);
    // e2: tT -> hT, relu
    gemm_bt<<<dim3(256, 2), 256, 0, stream>>>(wE2, tT, hT, nullptr, be2, nullptr, 128, 128, 0, 128, 0, 128, 1, 0, 0, 0);

    for (int i = 0; i < 3; ++i) {
        const _Float16* hin = (i == 0) ? hT : xct;
        int ldH  = (i == 0) ? 128 : 384;
        int offH = (i == 0) ? 0 : (i - 1) * 128;
        // t = relu(bn(W1 h))
        gemm_bt<<<dim3(256, 2), 256, 0, stream>>>(w1f + (size_t)i * 16384, hin, tT, nullptr, b1 + i * 128, nullptr,
                                                  128, ldH, offH, 128, 0, 128, 1, 0, 0, 0);
        // m = neighbor max
        gather_max_kernel<<<dim3(MM / 16), 256, 0, stream>>>((const short*)tT, idx, (short*)mT);
        // h' = relu(bn(W2 m) + h) -> xcat slice i
        gemm_bt<<<dim3(256, 2), 256, 0, stream>>>(w2f + (size_t)i * 16384, mT, xct, nullptr, b2 + i * 128, hin,
                                                  128, 128, 0, 384, i * 128, 128, 1, 0, ldH, offH);
    }

    // xf = leaky(bn(Wf xcat))
    gemm_bt<<<dim3(256, 16), 256, 0, stream>>>(wF, xct, xf, nullptr, bfv, nullptr, 384, 384, 0, 1024, 0, 1024, 2, 0, 0, 0);

    // pooling + per-batch classifier constant
    reduce1_kernel<<<dim3(BB, 4, 8), 256, 0, stream>>>(xf, pmx, psm);
    reduce2_kernel<<<dim3(BB, 4), 256, 0, stream>>>(pmx, psm, xmx, xav);
    cvec_kernel<<<dim3(BB, 8), 256, 0, stream>>>(label, Wl, gl, bl, Wc1, bc1, gc1, bb1, xmx, xav, cv);

    // c1 = relu(gc1*Wc1[:, :1024] xf + cvec[b])
    gemm_bt<<<dim3(256, 8), 256, 0, stream>>>(wC1, xf, c1, nullptr, cv, nullptr, 1024, 1024, 0, 512, 0, 512, 1, 1, 0, 0);
    // c2 = relu(bn(Wc2 c1 + bc2))
    gemm_bt<<<dim3(256, 4), 256, 0, stream>>>(wC2, c1, c2, nullptr, bC2, nullptr, 512, 512, 0, 256, 0, 256, 1, 0, 0, 0);
    // c3 = Wc3 c2 + bc3 (no act), f32 out
    gemm_bt<<<dim3(256, 1), 256, 0, stream>>>(wC3, c2, nullptr, c3, bC3, nullptr, 256, 256, 0, 64, 0, 64, 0, 0, 0, 0);

    // (M x 64) -> (B,50,N)
    reformat_kernel<<<dim3(BB * 50 * NN / 256), 256, 0, stream>>>(c3, (float*)d_out);
}

// Round 3
// 1338.562 us; speedup vs baseline: 1.2966x; 1.2966x over previous
//
#include <hip/hip_runtime.h>
#include <cstdint>
#include <cstddef>

#define DEVINL __device__ __forceinline__

typedef float    f32x4 __attribute__((ext_vector_type(4)));
typedef _Float16 f16x8 __attribute__((ext_vector_type(8)));
typedef _Float16 f16x4 __attribute__((ext_vector_type(4)));

// ---------------- constants ----------------
constexpr int BB = 16, NN = 2048, MM = 32768;

// ---------------- ws layout (bytes) ----------------
constexpr size_t OFF_WE1 = 0;                          // 128x32 f16
constexpr size_t OFF_WE2 = OFF_WE1 + 128 * 32 * 2;
constexpr size_t OFF_W1  = OFF_WE2 + 128 * 128 * 2;
constexpr size_t OFF_W2  = OFF_W1  + 3 * 128 * 128 * 2;
constexpr size_t OFF_WF  = OFF_W2  + 3 * 128 * 128 * 2;
constexpr size_t OFF_WC1 = OFF_WF  + 1024 * 384 * 2;
constexpr size_t OFF_WC2 = OFF_WC1 + 512 * 1024 * 2;
constexpr size_t OFF_WC3 = OFF_WC2 + 256 * 512 * 2;
constexpr size_t OFF_BC2 = OFF_WC3 + 64 * 256 * 2;     // 256 f32
constexpr size_t OFF_BC3 = OFF_BC2 + 256 * 4;          // 64 f32
constexpr size_t OFF_CVEC= OFF_BC3 + 64 * 4;           // 16x512 f32
constexpr size_t OFF_XMAX= OFF_CVEC+ 16 * 512 * 4;
constexpr size_t OFF_XAVG= OFF_XMAX+ 16 * 1024 * 4;
constexpr size_t OFF_PMAX= OFF_XAVG+ 16 * 1024 * 4;
constexpr size_t OFF_PSUM= OFF_PMAX+ 16 * 8 * 1024 * 4;
constexpr size_t OFF_IDX = OFF_PSUM+ 16 * 8 * 1024 * 4;
constexpr size_t OFF_R1  = 6ull << 20;                 // > OFF_IDX + 2MB
constexpr size_t OFF_X0  = OFF_R1;                     // 2MB  (M x 32 f16)
constexpr size_t OFF_HT  = OFF_R1 + (2ull  << 20);     // 8MB  (M x 128 f16)
constexpr size_t OFF_TT  = OFF_R1 + (10ull << 20);     // 8MB
constexpr size_t OFF_MT  = OFF_R1 + (18ull << 20);     // 8MB
constexpr size_t OFF_C1  = OFF_R1;                     // 32MB (M x 512 f16), aliases x0/h/t/m (dead)
constexpr size_t OFF_XCAT= OFF_R1 + (32ull << 20);     // 24MB (M x 384 f16)
constexpr size_t OFF_C2  = OFF_XCAT;                   // 16MB (M x 256 f16), aliases xcat (dead)
constexpr size_t OFF_XF  = OFF_XCAT + (24ull << 20);   // 64MB (M x 1024 f16)
constexpr size_t OFF_C3  = OFF_XF;                     // 8MB  (M x 64 f32), aliases xf (dead)

// ---------------- weight folding: dst[o*Kp+k] = f16( W[o,k] * g[o] ), zero-padded ----------------
__global__ __launch_bounds__(256) void fold_w_kernel(
    const float* We1, const float* ge1, const float* We2, const float* ge2,
    const float* W1,  const float* g1,  const float* W2,  const float* g2,
    const float* Wf,  const float* gf,  const float* Wc1, const float* gc1,
    const float* Wc2, const float* gc2, const float* Wc3, char* ws)
{
    const int id = blockIdx.y;
    const float* src = nullptr; const float* g = nullptr; _Float16* dst = nullptr;
    int O = 0, K = 0, lds = 0, Kp = 0, Opad = 0;
    switch (id) {
        case 0:  src = We1; g = ge1; O = 128; K = 6;    lds = 6;    Kp = 32;   Opad = 128; dst = (_Float16*)(ws + OFF_WE1); break;
        case 1:  src = We2; g = ge2; O = 128; K = 128;  lds = 128;  Kp = 128;  Opad = 128; dst = (_Float16*)(ws + OFF_WE2); break;
        case 2: case 3: case 4: {
            int i = id - 2;
            src = W1 + (size_t)i * 16384; g = g1 + i * 128; O = 128; K = 128; lds = 128; Kp = 128; Opad = 128;
            dst = (_Float16*)(ws + OFF_W1) + (size_t)i * 16384; break; }
        case 5: case 6: case 7: {
            int i = id - 5;
            src = W2 + (size_t)i * 16384; g = g2 + i * 128; O = 128; K = 128; lds = 128; Kp = 128; Opad = 128;
            dst = (_Float16*)(ws + OFF_W2) + (size_t)i * 16384; break; }
        case 8:  src = Wf;  g = gf;  O = 1024; K = 384;  lds = 384;  Kp = 384;  Opad = 1024; dst = (_Float16*)(ws + OFF_WF);  break;
        case 9:  src = Wc1; g = gc1; O = 512;  K = 1024; lds = 3136; Kp = 1024; Opad = 512;  dst = (_Float16*)(ws + OFF_WC1); break;
        case 10: src = Wc2; g = gc2; O = 256;  K = 512;  lds = 512;  Kp = 512;  Opad = 256;  dst = (_Float16*)(ws + OFF_WC2); break;
        default: src = Wc3; g = nullptr; O = 50; K = 256; lds = 256; Kp = 256;  Opad = 64;   dst = (_Float16*)(ws + OFF_WC3); break;
    }
    int e = blockIdx.x * 256 + threadIdx.x;
    if (e >= Opad * Kp) return;
    int o = e / Kp, k = e - o * Kp;
    float v = 0.f;
    if (o < O && k < K) {
        v = src[(size_t)o * lds + k];
        if (g) v *= g[o];
    }
    dst[e] = (_Float16)v;
}

// ---------------- bias folding (only the two that need compute) ----------------
__global__ __launch_bounds__(256) void fold_bias_kernel(
    const float* gc2, const float* bc2, const float* bb2, const float* bc3, char* ws)
{
    const int id = blockIdx.x, tid = threadIdx.x;
    if (id == 0) {
        ((float*)(ws + OFF_BC2))[tid] = gc2[tid] * bc2[tid] + bb2[tid];
    } else if (tid < 64) {
        ((float*)(ws + OFF_BC3))[tid] = (tid < 50) ? bc3[tid] : 0.f;
    }
}

// ---------------- x0 prep: (B,6,N) f32 -> (M x 32) f16 K-contig, zero pad ----------------
__global__ __launch_bounds__(256) void x0prep_kernel(const float* __restrict__ pts, _Float16* __restrict__ x0)
{
    int m = blockIdx.x * 256 + threadIdx.x;
    int b = m >> 11, n = m & 2047;
    const float* ps = pts + (size_t)b * 6 * 2048 + n;
    _Float16 tmp[32];
#pragma unroll
    for (int c = 0; c < 32; ++c) tmp[c] = (_Float16)0.f;
#pragma unroll
    for (int c = 0; c < 6; ++c) tmp[c] = (_Float16)ps[(size_t)c << 11];
    _Float16* dst = x0 + (size_t)m * 32;
#pragma unroll
    for (int v = 0; v < 4; ++v) *(f16x8*)(dst + v * 8) = *(const f16x8*)(tmp + v * 8);
}

// ---------------- KNN v2: 8 threads per query, stride-8 scan + LDS list merge ----------------
// block: 256 threads = 32 queries x 8 partitions. grid: (B, N/32).
// LDS: P[2048] float4 (32KB) for the scan; after the scan the same 32KB is
// reused as the merge buffer (md[16][256] dists + mi[16][256] idx).
__global__ __launch_bounds__(256) void knn_kernel(const float* __restrict__ pts, int* __restrict__ idxout)
{
    __shared__ float4 P[2048];
    const int tid = threadIdx.x;
    const int b = blockIdx.x;
    const float* pb = pts + (size_t)b * 6 * 2048;
    for (int i = tid; i < 2048; i += 256) {
        float x = pb[i];
        float y = pb[2048 + i];
        float z = pb[4096 + i];
        P[i] = make_float4(x, y, z, x * x + y * y + z * z);
    }
    __syncthreads();

    const int p = tid & 7;          // candidate partition (m == 8*i + p)
    const int g = tid >> 3;         // query within block (0..31)
    const int q = blockIdx.y * 32 + g;
    const float4 pq = P[q];

    float dist[16]; int idv[16];
#pragma unroll
    for (int j = 0; j < 16; ++j) { dist[j] = 3.4e38f; idv[j] = 0; }

    float4 nxt = P[p];
    for (int i = 0; i < 256; ++i) {
        const float4 pm = nxt;
        const int m = i * 8 + p;
        nxt = P[(m + 8) & 2047];    // prefetch next candidate (wraps harmlessly on last)
        float d = pq.w + pm.w - 2.f * (pq.x * pm.x + pq.y * pm.y + pq.z * pm.z);
        if (d < dist[15]) {
            dist[15] = d; idv[15] = m;
#pragma unroll
            for (int j = 15; j > 0; --j) {
                if (dist[j] < dist[j - 1]) {
                    float td = dist[j]; dist[j] = dist[j - 1]; dist[j - 1] = td;
                    int ti = idv[j]; idv[j] = idv[j - 1]; idv[j - 1] = ti;
                }
            }
        }
    }

    __syncthreads();                 // everyone done reading P; reuse its LDS
    float* md = (float*)P;           // md[j*256 + tid]
    int*   mi = (int*)(P + 1024);    // mi[j*256 + tid]
#pragma unroll
    for (int j = 0; j < 16; ++j) {
        md[j * 256 + tid] = dist[j];
        mi[j * 256 + tid] = idv[j];
    }
    __syncthreads();

    if (p == 0) {
        // merge the 7 other sorted lists; each list is ascending -> early exit
        for (int s = 1; s < 8; ++s) {
            const int base = g * 8 + s;
#pragma unroll
            for (int j = 0; j < 16; ++j) {
                float d = md[j * 256 + base];
                if (d >= dist[15]) break;
                int m = mi[j * 256 + base];
                dist[15] = d; idv[15] = m;
#pragma unroll
                for (int t = 15; t > 0; --t) {
                    if (dist[t] < dist[t - 1]) {
                        float td = dist[t]; dist[t] = dist[t - 1]; dist[t - 1] = td;
                        int ti = idv[t]; idv[t] = idv[t - 1]; idv[t - 1] = ti;
                    }
                }
            }
        }
        int* op = idxout + ((size_t)(b * 2048 + q)) * 16;
#pragma unroll
        for (int j = 0; j < 16; ++j) op[j] = idv[j];
    }
}

// ---------------- GEMM: Y[m, yoff+o] = act( W(Opad x Kp) . X[m, xoff+:] + bias (+ Res) ) ----------------
// block: 256 thr = 4 waves; tile 128(m) x 64(o); wave: 16 o x 128 m (8 MFMA chains)
// If Y32 != nullptr, stores f32 to Y32 instead of f16 to Y.
__global__ __launch_bounds__(256) void gemm_bt(
    const _Float16* __restrict__ W, const _Float16* __restrict__ X,
    _Float16* __restrict__ Y, float* __restrict__ Y32,
    const float* __restrict__ bias, const _Float16* __restrict__ Res,
    int Kp, int ldX, int xoff, int ldY, int yoff, int Opad,
    int act, int biasPerBatch, int ldR, int roff)
{
    const int tid  = threadIdx.x;
    const int wave = tid >> 6;
    const int lane = tid & 63;
    const int r    = lane & 15;
    const int quad = lane >> 4;
    const int m_base = blockIdx.x * 128;
    const int o_base = blockIdx.y * 64 + wave * 16;

    f32x4 acc[8];
#pragma unroll
    for (int s = 0; s < 8; ++s) acc[s] = (f32x4){0.f, 0.f, 0.f, 0.f};

    const _Float16* Ap = W + (size_t)(o_base + r) * Kp + quad * 8;
    const _Float16* Bp = X + (size_t)(m_base + r) * ldX + xoff + quad * 8;
    const size_t bstep = (size_t)16 * ldX;

    for (int k = 0; k < Kp; k += 32) {
        f16x8 a = *(const f16x8*)(Ap + k);
#pragma unroll
        for (int s = 0; s < 8; ++s) {
            f16x8 bfrag = *(const f16x8*)(Bp + (size_t)s * bstep + k);
            acc[s] = __builtin_amdgcn_mfma_f32_16x16x32_f16(a, bfrag, acc[s], 0, 0, 0);
        }
    }

    const int o0 = o_base + quad * 4;
    const float* bptr = bias + (biasPerBatch ? (size_t)(m_base >> 11) * Opad : (size_t)0);
    const f32x4 bv = *(const f32x4*)(bptr + o0);

#pragma unroll
    for (int s = 0; s < 8; ++s) {
        int m = m_base + s * 16 + r;
        f32x4 v = acc[s] + bv;
        if (Res) {
            f16x4 rr = *(const f16x4*)(Res + (size_t)m * ldR + roff + o0);
#pragma unroll
            for (int j = 0; j < 4; ++j) v[j] += (float)rr[j];
        }
#pragma unroll
        for (int j = 0; j < 4; ++j) {
            float x = v[j];
            if (act == 1)      x = (x > 0.f) ? x : 0.0f;   // relu, +0 guaranteed
            else if (act == 2) x = (x > 0.f) ? x : 0.2f * x;
            v[j] = x;
        }
        if (Y32) {
            *(f32x4*)(Y32 + (size_t)m * ldY + yoff + o0) = v;
        } else {
            f16x4 ov;
#pragma unroll
            for (int j = 0; j < 4; ++j) ov[j] = (_Float16)v[j];
            *(f16x4*)(Y + (size_t)m * ldY + yoff + o0) = ov;
        }
    }
}

// ---------------- neighbor gather + channel max (relu outputs => ushort-monotonic f16 bits) ----------------
typedef short s16x8 __attribute__((ext_vector_type(8)));
__global__ __launch_bounds__(256) void gather_max_kernel(
    const short* __restrict__ T, const int* __restrict__ idx, short* __restrict__ Mo)
{
    const int tid = threadIdx.x;
    const int p = blockIdx.x * 16 + (tid >> 4);
    const int l = tid & 15;
    const int b = p >> 11;
    const int* ip = idx + (size_t)p * 16;
    size_t row = (size_t)((b << 11) + ip[0]);
    s16x8 cur = *(const s16x8*)(T + row * 128 + l * 8);
    unsigned short best[8];
#pragma unroll
    for (int e = 0; e < 8; ++e) best[e] = (unsigned short)cur[e];
#pragma unroll
    for (int j = 1; j < 16; ++j) {
        row = (size_t)((b << 11) + ip[j]);
        s16x8 v = *(const s16x8*)(T + row * 128 + l * 8);
#pragma unroll
        for (int e = 0; e < 8; ++e) {
            unsigned short u = (unsigned short)v[e];
            if (u > best[e]) best[e] = u;
        }
    }
    s16x8 ov;
#pragma unroll
    for (int e = 0; e < 8; ++e) ov[e] = (short)best[e];
    *(s16x8*)(Mo + (size_t)p * 128 + l * 8) = ov;
}

// ---------------- pooling reductions over n ----------------
__global__ __launch_bounds__(256) void reduce1_kernel(const _Float16* __restrict__ xf, float* __restrict__ pmax, float* __restrict__ psum)
{
    const int b = blockIdx.x, oc = blockIdx.y, ch = blockIdx.z, tid = threadIdx.x;
    const int o = oc * 256 + tid;
    const _Float16* p = xf + ((size_t)(b << 11) + ch * 256) * 1024 + o;
    float mx = -3.4e38f, sm = 0.f;
    for (int n = 0; n < 256; ++n) {
        float v = (float)p[(size_t)n * 1024];
        mx = fmaxf(mx, v); sm += v;
    }
    pmax[((size_t)(b * 8 + ch) << 10) + o] = mx;
    psum[((size_t)(b * 8 + ch) << 10) + o] = sm;
}

__global__ __launch_bounds__(256) void reduce2_kernel(const float* __restrict__ pmax, const float* __restrict__ psum,
                                                      float* __restrict__ xmax, float* __restrict__ xavg)
{
    const int b = blockIdx.x, oc = blockIdx.y, tid = threadIdx.x;
    const int o = oc * 256 + tid;
    float mx = -3.4e38f, sm = 0.f;
#pragma unroll
    for (int c = 0; c < 8; ++c) {
        mx = fmaxf(mx, pmax[((size_t)(b * 8 + c) << 10) + o]);
        sm += psum[((size_t)(b * 8 + c) << 10) + o];
    }
    xmax[((size_t)b << 10) + o] = mx;
    xavg[((size_t)b << 10) + o] = sm * (1.f / 2048.f);
}

// ---------------- per-batch constant vector for Wc1 (broadcast cols 1024..3135 + bias/bn) ----------------
__global__ __launch_bounds__(256) void cvec_kernel(
    const float* __restrict__ label, const float* __restrict__ Wl, const float* __restrict__ gl, const float* __restrict__ bl,
    const float* __restrict__ Wc1, const float* __restrict__ bc1, const float* __restrict__ gc1, const float* __restrict__ bb1,
    const float* __restrict__ xmax, const float* __restrict__ xavg, float* __restrict__ cvec)
{
    __shared__ float v[2112];
    __shared__ float red[256];
    const int b = blockIdx.x, og = blockIdx.y, tid = threadIdx.x;
    for (int i = tid; i < 1024; i += 256) v[i] = xmax[((size_t)b << 10) + i];
    for (int i = tid; i < 1024; i += 256) v[1024 + i] = xavg[((size_t)b << 10) + i];
    if (tid < 64) {
        float s = 0.f;
        for (int i = 0; i < 16; ++i) s += Wl[tid * 16 + i] * label[b * 16 + i];
        s = gl[tid] * s + bl[tid];
        v[2048 + tid] = (s > 0.f) ? s : 0.2f * s;
    }
    __syncthreads();
    const int o = og * 64 + (tid >> 2), part = tid & 3;
    const float* wrow = Wc1 + (size_t)o * 3136 + 1024 + part * 528;
    float s = 0.f;
    for (int j = 0; j < 528; ++j) s += wrow[j] * v[part * 528 + j];
    red[tid] = s;
    __syncthreads();
    if (part == 0) {
        float tot = red[tid] + red[tid + 1] + red[tid + 2] + red[tid + 3];
        cvec[((size_t)b << 9) + o] = gc1[o] * (tot + bc1[o]) + bb1[o];
    }
}

// ---------------- final layout (M x 64 f32) -> (B,50,N) f32 ----------------
__global__ __launch_bounds__(256) void reformat_kernel(const float* __restrict__ c3, float* __restrict__ out)
{
    int i = blockIdx.x * 256 + threadIdx.x;       // 16*50*2048 total
    int n = i & 2047;
    int t = i >> 11;        // b*50 + o
    int o = t % 50;
    int b = t / 50;
    out[i] = c3[((size_t)((b << 11) + n)) * 64 + o];
}

// ---------------- launch ----------------
extern "C" void kernel_launch(void* const* d_in, const int* in_sizes, int n_in,
                              void* d_out, int out_size, void* d_ws, size_t ws_size,
                              hipStream_t stream)
{
    (void)in_sizes; (void)n_in; (void)out_size; (void)ws_size;
    const float* points = (const float*)d_in[0];
    const float* label  = (const float*)d_in[1];
    const float* We1 = (const float*)d_in[2];
    const float* ge1 = (const float*)d_in[3];
    const float* be1 = (const float*)d_in[4];
    const float* We2 = (const float*)d_in[5];
    const float* ge2 = (const float*)d_in[6];
    const float* be2 = (const float*)d_in[7];
    const float* W1  = (const float*)d_in[8];
    const float* g1  = (const float*)d_in[9];
    const float* b1  = (const float*)d_in[10];
    const float* W2  = (const float*)d_in[11];
    const float* g2  = (const float*)d_in[12];
    const float* b2  = (const float*)d_in[13];
    const float* Wf  = (const float*)d_in[14];
    const float* gf  = (const float*)d_in[15];
    const float* bfv = (const float*)d_in[16];
    const float* Wl  = (const float*)d_in[17];
    const float* gl  = (const float*)d_in[18];
    const float* bl  = (const float*)d_in[19];
    const float* Wc1 = (const float*)d_in[20];
    const float* bc1 = (const float*)d_in[21];
    const float* gc1 = (const float*)d_in[22];
    const float* bb1 = (const float*)d_in[23];
    const float* Wc2 = (const float*)d_in[24];
    const float* bc2 = (const float*)d_in[25];
    const float* gc2 = (const float*)d_in[26];
    const float* bb2 = (const float*)d_in[27];
    const float* Wc3 = (const float*)d_in[28];
    const float* bc3 = (const float*)d_in[29];

    char* ws = (char*)d_ws;
    _Float16* x0  = (_Float16*)(ws + OFF_X0);
    _Float16* hT  = (_Float16*)(ws + OFF_HT);
    _Float16* tT  = (_Float16*)(ws + OFF_TT);
    _Float16* mT  = (_Float16*)(ws + OFF_MT);
    _Float16* xct = (_Float16*)(ws + OFF_XCAT);
    _Float16* xf  = (_Float16*)(ws + OFF_XF);
    _Float16* c1  = (_Float16*)(ws + OFF_C1);
    _Float16* c2  = (_Float16*)(ws + OFF_C2);
    float*    c3  = (float*)   (ws + OFF_C3);
    int*      idx = (int*)     (ws + OFF_IDX);

    _Float16* wE1 = (_Float16*)(ws + OFF_WE1);
    _Float16* wE2 = (_Float16*)(ws + OFF_WE2);
    _Float16* w1f = (_Float16*)(ws + OFF_W1);
    _Float16* w2f = (_Float16*)(ws + OFF_W2);
    _Float16* wF  = (_Float16*)(ws + OFF_WF);
    _Float16* wC1 = (_Float16*)(ws + OFF_WC1);
    _Float16* wC2 = (_Float16*)(ws + OFF_WC2);
    _Float16* wC3 = (_Float16*)(ws + OFF_WC3);
    float* bC2 = (float*)(ws + OFF_BC2);
    float* bC3 = (float*)(ws + OFF_BC3);
    float* cv  = (float*)(ws + OFF_CVEC);
    float* xmx = (float*)(ws + OFF_XMAX);
    float* xav = (float*)(ws + OFF_XAVG);
    float* pmx = (float*)(ws + OFF_PMAX);
    float* psm = (float*)(ws + OFF_PSUM);

    // prep
    fold_w_kernel<<<dim3(2048, 12), 256, 0, stream>>>(We1, ge1, We2, ge2, W1, g1, W2, g2, Wf, gf, Wc1, gc1, Wc2, gc2, Wc3, ws);
    fold_bias_kernel<<<dim3(2), 256, 0, stream>>>(gc2, bc2, bb2, bc3, ws);
    x0prep_kernel<<<dim3(MM / 256), 256, 0, stream>>>(points, x0);
    knn_kernel<<<dim3(BB, NN / 32), 256, 0, stream>>>(points, idx);

    // e1: x0(Mx32) -> tT(Mx128), relu
    gemm_bt<<<dim3(256, 2), 256, 0, stream>>>(wE1, x0, tT, nullptr, be1, nullptr, 32, 32, 0, 128, 0, 128, 1, 0, 0, 0);
    // e2: tT -> hT, relu
    gemm_bt<<<dim3(256, 2), 256, 0, stream>>>(wE2, tT, hT, nullptr, be2, nullptr, 128, 128, 0, 128, 0, 128, 1, 0, 0, 0);

    for (int i = 0; i < 3; ++i) {
        const _Float16* hin = (i == 0) ? hT : xct;
        int ldH  = (i == 0) ? 128 : 384;
        int offH = (i == 0) ? 0 : (i - 1) * 128;
        // t = relu(bn(W1 h))
        gemm_bt<<<dim3(256, 2), 256, 0, stream>>>(w1f + (size_t)i * 16384, hin, tT, nullptr, b1 + i * 128, nullptr,
                                                  128, ldH, offH, 128, 0, 128, 1, 0, 0, 0);
        // m = neighbor max
        gather_max_kernel<<<dim3(MM / 16), 256, 0, stream>>>((const short*)tT, idx, (short*)mT);
        // h' = relu(bn(W2 m) + h) -> xcat slice i
        gemm_bt<<<dim3(256, 2), 256, 0, stream>>>(w2f + (size_t)i * 16384, mT, xct, nullptr, b2 + i * 128, hin,
                                                  128, 128, 0, 384, i * 128, 128, 1, 0, ldH, offH);
    }

    // xf = leaky(bn(Wf xcat))
    gemm_bt<<<dim3(256, 16), 256, 0, stream>>>(wF, xct, xf, nullptr, bfv, nullptr, 384, 384, 0, 1024, 0, 1024, 2, 0, 0, 0);

    // pooling + per-batch classifier constant
    reduce1_kernel<<<dim3(BB, 4, 8), 256, 0, stream>>>(xf, pmx, psm);
    reduce2_kernel<<<dim3(BB, 4), 256, 0, stream>>>(pmx, psm, xmx, xav);
    cvec_kernel<<<dim3(BB, 8), 256, 0, stream>>>(label, Wl, gl, bl, Wc1, bc1, gc1, bb1, xmx, xav, cv);

    // c1 = relu(gc1*Wc1[:, :1024] xf + cvec[b])
    gemm_bt<<<dim3(256, 8), 256, 0, stream>>>(wC1, xf, c1, nullptr, cv, nullptr, 1024, 1024, 0, 512, 0, 512, 1, 1, 0, 0);
    // c2 = relu(bn(Wc2 c1 + bc2))
    gemm_bt<<<dim3(256, 4), 256, 0, stream>>>(wC2, c1, c2, nullptr, bC2, nullptr, 512, 512, 0, 256, 0, 256, 1, 0, 0, 0);
    // c3 = Wc3 c2 + bc3 (no act), f32 out
    gemm_bt<<<dim3(256, 1), 256, 0, stream>>>(wC3, c2, nullptr, c3, bC3, nullptr, 256, 256, 0, 64, 0, 64, 0, 0, 0, 0);

    // (M x 64) -> (B,50,N)
    reformat_kernel<<<dim3(BB * 50 * NN / 256), 256, 0, stream>>>(c3, (float*)d_out);
}

// Round 4
// 1236.405 us; speedup vs baseline: 1.4037x; 1.0826x over previous
//
#include <hip/hip_runtime.h>
#include <cstdint>
#include <cstddef>

#define DEVINL __device__ __forceinline__

typedef float    f32x4 __attribute__((ext_vector_type(4)));
typedef _Float16 f16x8 __attribute__((ext_vector_type(8)));
typedef _Float16 f16x4 __attribute__((ext_vector_type(4)));

// ---------------- constants ----------------
constexpr int BB = 16, NN = 2048, MM = 32768;

// ---------------- ws layout (bytes) ----------------
constexpr size_t OFF_WE1 = 0;                          // 128x32 f16
constexpr size_t OFF_WE2 = OFF_WE1 + 128 * 32 * 2;
constexpr size_t OFF_W1  = OFF_WE2 + 128 * 128 * 2;
constexpr size_t OFF_W2  = OFF_W1  + 3 * 128 * 128 * 2;
constexpr size_t OFF_WF  = OFF_W2  + 3 * 128 * 128 * 2;
constexpr size_t OFF_WC1 = OFF_WF  + 1024 * 384 * 2;
constexpr size_t OFF_WC2 = OFF_WC1 + 512 * 1024 * 2;
constexpr size_t OFF_WC3 = OFF_WC2 + 256 * 512 * 2;
constexpr size_t OFF_BC2 = OFF_WC3 + 64 * 256 * 2;     // 256 f32
constexpr size_t OFF_BC3 = OFF_BC2 + 256 * 4;          // 64 f32
constexpr size_t OFF_CVEC= OFF_BC3 + 64 * 4;           // 16x512 f32
constexpr size_t OFF_XMAX= OFF_CVEC+ 16 * 512 * 4;
constexpr size_t OFF_XAVG= OFF_XMAX+ 16 * 1024 * 4;
constexpr size_t OFF_PMAX= OFF_XAVG+ 16 * 1024 * 4;
constexpr size_t OFF_PSUM= OFF_PMAX+ 16 * 8 * 1024 * 4;
constexpr size_t OFF_IDX = OFF_PSUM+ 16 * 8 * 1024 * 4;
constexpr size_t OFF_R1  = 6ull << 20;                 // > OFF_IDX + 2MB
constexpr size_t OFF_X0  = OFF_R1;                     // 2MB  (M x 32 f16)
constexpr size_t OFF_HT  = OFF_R1 + (2ull  << 20);     // 8MB  (M x 128 f16)
constexpr size_t OFF_TT  = OFF_R1 + (10ull << 20);     // 8MB
constexpr size_t OFF_MT  = OFF_R1 + (18ull << 20);     // 8MB
constexpr size_t OFF_C1  = OFF_R1;                     // 32MB (M x 512 f16), aliases x0/h/t/m (dead)
constexpr size_t OFF_XCAT= OFF_R1 + (32ull << 20);     // 24MB (M x 384 f16)
constexpr size_t OFF_C2  = OFF_XCAT;                   // 16MB (M x 256 f16), aliases xcat (dead)
constexpr size_t OFF_XF  = OFF_XCAT + (24ull << 20);   // 64MB (M x 1024 f16)
constexpr size_t OFF_C3  = OFF_XF;                     // 8MB  (M x 64 f32), aliases xf (dead)

// ---------------- weight folding: dst[o*Kp+k] = f16( W[o,k] * g[o] ), zero-padded ----------------
__global__ __launch_bounds__(256) void fold_w_kernel(
    const float* We1, const float* ge1, const float* We2, const float* ge2,
    const float* W1,  const float* g1,  const float* W2,  const float* g2,
    const float* Wf,  const float* gf,  const float* Wc1, const float* gc1,
    const float* Wc2, const float* gc2, const float* Wc3, char* ws)
{
    const int id = blockIdx.y;
    const float* src = nullptr; const float* g = nullptr; _Float16* dst = nullptr;
    int O = 0, K = 0, lds = 0, Kp = 0, Opad = 0;
    switch (id) {
        case 0:  src = We1; g = ge1; O = 128; K = 6;    lds = 6;    Kp = 32;   Opad = 128; dst = (_Float16*)(ws + OFF_WE1); break;
        case 1:  src = We2; g = ge2; O = 128; K = 128;  lds = 128;  Kp = 128;  Opad = 128; dst = (_Float16*)(ws + OFF_WE2); break;
        case 2: case 3: case 4: {
            int i = id - 2;
            src = W1 + (size_t)i * 16384; g = g1 + i * 128; O = 128; K = 128; lds = 128; Kp = 128; Opad = 128;
            dst = (_Float16*)(ws + OFF_W1) + (size_t)i * 16384; break; }
        case 5: case 6: case 7: {
            int i = id - 5;
            src = W2 + (size_t)i * 16384; g = g2 + i * 128; O = 128; K = 128; lds = 128; Kp = 128; Opad = 128;
            dst = (_Float16*)(ws + OFF_W2) + (size_t)i * 16384; break; }
        case 8:  src = Wf;  g = gf;  O = 1024; K = 384;  lds = 384;  Kp = 384;  Opad = 1024; dst = (_Float16*)(ws + OFF_WF);  break;
        case 9:  src = Wc1; g = gc1; O = 512;  K = 1024; lds = 3136; Kp = 1024; Opad = 512;  dst = (_Float16*)(ws + OFF_WC1); break;
        case 10: src = Wc2; g = gc2; O = 256;  K = 512;  lds = 512;  Kp = 512;  Opad = 256;  dst = (_Float16*)(ws + OFF_WC2); break;
        default: src = Wc3; g = nullptr; O = 50; K = 256; lds = 256; Kp = 256;  Opad = 64;   dst = (_Float16*)(ws + OFF_WC3); break;
    }
    int e = blockIdx.x * 256 + threadIdx.x;
    if (e >= Opad * Kp) return;
    int o = e / Kp, k = e - o * Kp;
    float v = 0.f;
    if (o < O && k < K) {
        v = src[(size_t)o * lds + k];
        if (g) v *= g[o];
    }
    dst[e] = (_Float16)v;
}

// ---------------- bias folding (only the two that need compute) ----------------
__global__ __launch_bounds__(256) void fold_bias_kernel(
    const float* gc2, const float* bc2, const float* bb2, const float* bc3, char* ws)
{
    const int id = blockIdx.x, tid = threadIdx.x;
    if (id == 0) {
        ((float*)(ws + OFF_BC2))[tid] = gc2[tid] * bc2[tid] + bb2[tid];
    } else if (tid < 64) {
        ((float*)(ws + OFF_BC3))[tid] = (tid < 50) ? bc3[tid] : 0.f;
    }
}

// ---------------- x0 prep: (B,6,N) f32 -> (M x 32) f16 K-contig, zero pad ----------------
__global__ __launch_bounds__(256) void x0prep_kernel(const float* __restrict__ pts, _Float16* __restrict__ x0)
{
    int m = blockIdx.x * 256 + threadIdx.x;
    int b = m >> 11, n = m & 2047;
    const float* ps = pts + (size_t)b * 6 * 2048 + n;
    _Float16 tmp[32];
#pragma unroll
    for (int c = 0; c < 32; ++c) tmp[c] = (_Float16)0.f;
#pragma unroll
    for (int c = 0; c < 6; ++c) tmp[c] = (_Float16)ps[(size_t)c << 11];
    _Float16* dst = x0 + (size_t)m * 32;
#pragma unroll
    for (int v = 0; v < 4; ++v) *(f16x8*)(dst + v * 8) = *(const f16x8*)(tmp + v * 8);
}

// ---------------- KNN v3: 8 threads/query, REGISTERIZED top-16 (named scalars, branchless swaps) ----------------
// block: 256 threads = 32 queries x 8 partitions. grid: (B, N/32).
// LDS: P[2048] float4 (32KB) for the scan; reused afterwards as merge buffer.
// d0..d15 ascending (d0 smallest). Insertion enters at slot 15 and bubbles up.

#define KNN_SWP(A, B) { \
    const bool c_ = d##A < d##B; \
    const float tf_ = c_ ? d##B : d##A; const int ti_ = c_ ? i##B : i##A; \
    d##B = c_ ? d##A : d##B;  i##B = c_ ? i##A : i##B; \
    d##A = tf_;               i##A = ti_; }

#define KNN_BUBBLE \
    KNN_SWP(15,14) KNN_SWP(14,13) KNN_SWP(13,12) KNN_SWP(12,11) \
    KNN_SWP(11,10) KNN_SWP(10,9)  KNN_SWP(9,8)   KNN_SWP(8,7)   \
    KNN_SWP(7,6)   KNN_SWP(6,5)   KNN_SWP(5,4)   KNN_SWP(4,3)   \
    KNN_SWP(3,2)   KNN_SWP(2,1)   KNN_SWP(1,0)

#define KNN_INSERT(DD, MMv) \
    if ((DD) < d15) { d15 = (DD); i15 = (MMv); KNN_BUBBLE }

__global__ __launch_bounds__(256) void knn_kernel(const float* __restrict__ pts, int* __restrict__ idxout)
{
    __shared__ float4 P[2048];
    const int tid = threadIdx.x;
    const int b = blockIdx.x;
    const float* pb = pts + (size_t)b * 6 * 2048;
    for (int i = tid; i < 2048; i += 256) {
        float x = pb[i];
        float y = pb[2048 + i];
        float z = pb[4096 + i];
        P[i] = make_float4(x, y, z, x * x + y * y + z * z);
    }
    __syncthreads();

    const int p = tid & 7;          // candidate partition (m == 8*i + p)
    const int g = tid >> 3;         // query within block (0..31)
    const int q = blockIdx.y * 32 + g;
    const float4 pq = P[q];

    float d0 = 3.4e38f, d1 = 3.4e38f, d2 = 3.4e38f, d3 = 3.4e38f,
          d4 = 3.4e38f, d5 = 3.4e38f, d6 = 3.4e38f, d7 = 3.4e38f,
          d8 = 3.4e38f, d9 = 3.4e38f, d10 = 3.4e38f, d11 = 3.4e38f,
          d12 = 3.4e38f, d13 = 3.4e38f, d14 = 3.4e38f, d15 = 3.4e38f;
    int i0 = 0, i1 = 0, i2 = 0, i3 = 0, i4 = 0, i5 = 0, i6 = 0, i7 = 0,
        i8 = 0, i9 = 0, i10 = 0, i11 = 0, i12 = 0, i13 = 0, i14 = 0, i15 = 0;

    float4 nxt = P[p];
    for (int it = 0; it < 256; ++it) {
        const float4 pm = nxt;
        const int m = it * 8 + p;
        nxt = P[(m + 8) & 2047];    // prefetch next candidate (wraps harmlessly on last)
        const float d = pq.w + pm.w - 2.f * (pq.x * pm.x + pq.y * pm.y + pq.z * pm.z);
        KNN_INSERT(d, m)
    }

    __syncthreads();                 // everyone done reading P; reuse its LDS
    float* md = (float*)P;           // md[j*256 + tid]
    int*   mi = (int*)(P + 1024);    // mi[j*256 + tid]
#define KNN_SPILL(J) { md[J * 256 + tid] = d##J; mi[J * 256 + tid] = i##J; }
    KNN_SPILL(0)  KNN_SPILL(1)  KNN_SPILL(2)  KNN_SPILL(3)
    KNN_SPILL(4)  KNN_SPILL(5)  KNN_SPILL(6)  KNN_SPILL(7)
    KNN_SPILL(8)  KNN_SPILL(9)  KNN_SPILL(10) KNN_SPILL(11)
    KNN_SPILL(12) KNN_SPILL(13) KNN_SPILL(14) KNN_SPILL(15)
#undef KNN_SPILL
    __syncthreads();

    if (p == 0) {
        // merge the 7 other sorted (ascending) lists; early exit per list
        for (int s = 1; s < 8; ++s) {
            const int base = g * 8 + s;
#pragma unroll
            for (int j = 0; j < 16; ++j) {
                const float d = md[j * 256 + base];
                if (d >= d15) break;
                const int m = mi[j * 256 + base];
                d15 = d; i15 = m;
                KNN_BUBBLE
            }
        }
        int* op = idxout + ((size_t)(b * 2048 + q)) * 16;
        op[0]  = i0;  op[1]  = i1;  op[2]  = i2;  op[3]  = i3;
        op[4]  = i4;  op[5]  = i5;  op[6]  = i6;  op[7]  = i7;
        op[8]  = i8;  op[9]  = i9;  op[10] = i10; op[11] = i11;
        op[12] = i12; op[13] = i13; op[14] = i14; op[15] = i15;
    }
}

// ---------------- GEMM: Y[m, yoff+o] = act( W(Opad x Kp) . X[m, xoff+:] + bias (+ Res) ) ----------------
// block: 256 thr = 4 waves; tile 128(m) x 64(o); wave: 16 o x 128 m (8 MFMA chains)
// If Y32 != nullptr, stores f32 to Y32 instead of f16 to Y.
__global__ __launch_bounds__(256) void gemm_bt(
    const _Float16* __restrict__ W, const _Float16* __restrict__ X,
    _Float16* __restrict__ Y, float* __restrict__ Y32,
    const float* __restrict__ bias, const _Float16* __restrict__ Res,
    int Kp, int ldX, int xoff, int ldY, int yoff, int Opad,
    int act, int biasPerBatch, int ldR, int roff)
{
    const int tid  = threadIdx.x;
    const int wave = tid >> 6;
    const int lane = tid & 63;
    const int r    = lane & 15;
    const int quad = lane >> 4;
    const int m_base = blockIdx.x * 128;
    const int o_base = blockIdx.y * 64 + wave * 16;

    f32x4 acc[8];
#pragma unroll
    for (int s = 0; s < 8; ++s) acc[s] = (f32x4){0.f, 0.f, 0.f, 0.f};

    const _Float16* Ap = W + (size_t)(o_base + r) * Kp + quad * 8;
    const _Float16* Bp = X + (size_t)(m_base + r) * ldX + xoff + quad * 8;
    const size_t bstep = (size_t)16 * ldX;

    for (int k = 0; k < Kp; k += 32) {
        f16x8 a = *(const f16x8*)(Ap + k);
#pragma unroll
        for (int s = 0; s < 8; ++s) {
            f16x8 bfrag = *(const f16x8*)(Bp + (size_t)s * bstep + k);
            acc[s] = __builtin_amdgcn_mfma_f32_16x16x32_f16(a, bfrag, acc[s], 0, 0, 0);
        }
    }

    const int o0 = o_base + quad * 4;
    const float* bptr = bias + (biasPerBatch ? (size_t)(m_base >> 11) * Opad : (size_t)0);
    const f32x4 bv = *(const f32x4*)(bptr + o0);

#pragma unroll
    for (int s = 0; s < 8; ++s) {
        int m = m_base + s * 16 + r;
        f32x4 v = acc[s] + bv;
        if (Res) {
            f16x4 rr = *(const f16x4*)(Res + (size_t)m * ldR + roff + o0);
#pragma unroll
            for (int j = 0; j < 4; ++j) v[j] += (float)rr[j];
        }
#pragma unroll
        for (int j = 0; j < 4; ++j) {
            float x = v[j];
            if (act == 1)      x = (x > 0.f) ? x : 0.0f;   // relu, +0 guaranteed
            else if (act == 2) x = (x > 0.f) ? x : 0.2f * x;
            v[j] = x;
        }
        if (Y32) {
            *(f32x4*)(Y32 + (size_t)m * ldY + yoff + o0) = v;
        } else {
            f16x4 ov;
#pragma unroll
            for (int j = 0; j < 4; ++j) ov[j] = (_Float16)v[j];
            *(f16x4*)(Y + (size_t)m * ldY + yoff + o0) = ov;
        }
    }
}

// ---------------- neighbor gather + channel max (relu outputs => ushort-monotonic f16 bits) ----------------
typedef short s16x8 __attribute__((ext_vector_type(8)));
__global__ __launch_bounds__(256) void gather_max_kernel(
    const short* __restrict__ T, const int* __restrict__ idx, short* __restrict__ Mo)
{
    const int tid = threadIdx.x;
    const int p = blockIdx.x * 16 + (tid >> 4);
    const int l = tid & 15;
    const int b = p >> 11;
    const int* ip = idx + (size_t)p * 16;
    size_t row = (size_t)((b << 11) + ip[0]);
    s16x8 cur = *(const s16x8*)(T + row * 128 + l * 8);
    unsigned short best[8];
#pragma unroll
    for (int e = 0; e < 8; ++e) best[e] = (unsigned short)cur[e];
#pragma unroll
    for (int j = 1; j < 16; ++j) {
        row = (size_t)((b << 11) + ip[j]);
        s16x8 v = *(const s16x8*)(T + row * 128 + l * 8);
#pragma unroll
        for (int e = 0; e < 8; ++e) {
            unsigned short u = (unsigned short)v[e];
            if (u > best[e]) best[e] = u;
        }
    }
    s16x8 ov;
#pragma unroll
    for (int e = 0; e < 8; ++e) ov[e] = (short)best[e];
    *(s16x8*)(Mo + (size_t)p * 128 + l * 8) = ov;
}

// ---------------- pooling reductions over n ----------------
__global__ __launch_bounds__(256) void reduce1_kernel(const _Float16* __restrict__ xf, float* __restrict__ pmax, float* __restrict__ psum)
{
    const int b = blockIdx.x, oc = blockIdx.y, ch = blockIdx.z, tid = threadIdx.x;
    const int o = oc * 256 + tid;
    const _Float16* p = xf + ((size_t)(b << 11) + ch * 256) * 1024 + o;
    float mx = -3.4e38f, sm = 0.f;
    for (int n = 0; n < 256; ++n) {
        float v = (float)p[(size_t)n * 1024];
        mx = fmaxf(mx, v); sm += v;
    }
    pmax[((size_t)(b * 8 + ch) << 10) + o] = mx;
    psum[((size_t)(b * 8 + ch) << 10) + o] = sm;
}

__global__ __launch_bounds__(256) void reduce2_kernel(const float* __restrict__ pmax, const float* __restrict__ psum,
                                                      float* __restrict__ xmax, float* __restrict__ xavg)
{
    const int b = blockIdx.x, oc = blockIdx.y, tid = threadIdx.x;
    const int o = oc * 256 + tid;
    float mx = -3.4e38f, sm = 0.f;
#pragma unroll
    for (int c = 0; c < 8; ++c) {
        mx = fmaxf(mx, pmax[((size_t)(b * 8 + c) << 10) + o]);
        sm += psum[((size_t)(b * 8 + c) << 10) + o];
    }
    xmax[((size_t)b << 10) + o] = mx;
    xavg[((size_t)b << 10) + o] = sm * (1.f / 2048.f);
}

// ---------------- per-batch constant vector for Wc1 (broadcast cols 1024..3135 + bias/bn) ----------------
__global__ __launch_bounds__(256) void cvec_kernel(
    const float* __restrict__ label, const float* __restrict__ Wl, const float* __restrict__ gl, const float* __restrict__ bl,
    const float* __restrict__ Wc1, const float* __restrict__ bc1, const float* __restrict__ gc1, const float* __restrict__ bb1,
    const float* __restrict__ xmax, const float* __restrict__ xavg, float* __restrict__ cvec)
{
    __shared__ float v[2112];
    __shared__ float red[256];
    const int b = blockIdx.x, og = blockIdx.y, tid = threadIdx.x;
    for (int i = tid; i < 1024; i += 256) v[i] = xmax[((size_t)b << 10) + i];
    for (int i = tid; i < 1024; i += 256) v[1024 + i] = xavg[((size_t)b << 10) + i];
    if (tid < 64) {
        float s = 0.f;
        for (int i = 0; i < 16; ++i) s += Wl[tid * 16 + i] * label[b * 16 + i];
        s = gl[tid] * s + bl[tid];
        v[2048 + tid] = (s > 0.f) ? s : 0.2f * s;
    }
    __syncthreads();
    const int o = og * 64 + (tid >> 2), part = tid & 3;
    const float* wrow = Wc1 + (size_t)o * 3136 + 1024 + part * 528;
    float s = 0.f;
    for (int j = 0; j < 528; ++j) s += wrow[j] * v[part * 528 + j];
    red[tid] = s;
    __syncthreads();
    if (part == 0) {
        float tot = red[tid] + red[tid + 1] + red[tid + 2] + red[tid + 3];
        cvec[((size_t)b << 9) + o] = gc1[o] * (tot + bc1[o]) + bb1[o];
    }
}

// ---------------- final layout (M x 64 f32) -> (B,50,N) f32 ----------------
__global__ __launch_bounds__(256) void reformat_kernel(const float* __restrict__ c3, float* __restrict__ out)
{
    int i = blockIdx.x * 256 + threadIdx.x;       // 16*50*2048 total
    int n = i & 2047;
    int t = i >> 11;        // b*50 + o
    int o = t % 50;
    int b = t / 50;
    out[i] = c3[((size_t)((b << 11) + n)) * 64 + o];
}

// ---------------- launch ----------------
extern "C" void kernel_launch(void* const* d_in, const int* in_sizes, int n_in,
                              void* d_out, int out_size, void* d_ws, size_t ws_size,
                              hipStream_t stream)
{
    (void)in_sizes; (void)n_in; (void)out_size; (void)ws_size;
    const float* points = (const float*)d_in[0];
    const float* label  = (const float*)d_in[1];
    const float* We1 = (const float*)d_in[2];
    const float* ge1 = (const float*)d_in[3];
    const float* be1 = (const float*)d_in[4];
    const float* We2 = (const float*)d_in[5];
    const float* ge2 = (const float*)d_in[6];
    const float* be2 = (const float*)d_in[7];
    const float* W1  = (const float*)d_in[8];
    const float* g1  = (const float*)d_in[9];
    const float* b1  = (const float*)d_in[10];
    const float* W2  = (const float*)d_in[11];
    const float* g2  = (const float*)d_in[12];
    const float* b2  = (const float*)d_in[13];
    const float* Wf  = (const float*)d_in[14];
    const float* gf  = (const float*)d_in[15];
    const float* bfv = (const float*)d_in[16];
    const float* Wl  = (const float*)d_in[17];
    const float* gl  = (const float*)d_in[18];
    const float* bl  = (const float*)d_in[19];
    const float* Wc1 = (const float*)d_in[20];
    const float* bc1 = (const float*)d_in[21];
    const float* gc1 = (const float*)d_in[22];
    const float* bb1 = (const float*)d_in[23];
    const float* Wc2 = (const float*)d_in[24];
    const float* bc2 = (const float*)d_in[25];
    const float* gc2 = (const float*)d_in[26];
    const float* bb2 = (const float*)d_in[27];
    const float* Wc3 = (const float*)d_in[28];
    const float* bc3 = (const float*)d_in[29];

    char* ws = (char*)d_ws;
    _Float16* x0  = (_Float16*)(ws + OFF_X0);
    _Float16* hT  = (_Float16*)(ws + OFF_HT);
    _Float16* tT  = (_Float16*)(ws + OFF_TT);
    _Float16* mT  = (_Float16*)(ws + OFF_MT);
    _Float16* xct = (_Float16*)(ws + OFF_XCAT);
    _Float16* xf  = (_Float16*)(ws + OFF_XF);
    _Float16* c1  = (_Float16*)(ws + OFF_C1);
    _Float16* c2  = (_Float16*)(ws + OFF_C2);
    float*    c3  = (float*)   (ws + OFF_C3);
    int*      idx = (int*)     (ws + OFF_IDX);

    _Float16* wE1 = (_Float16*)(ws + OFF_WE1);
    _Float16* wE2 = (_Float16*)(ws + OFF_WE2);
    _Float16* w1f = (_Float16*)(ws + OFF_W1);
    _Float16* w2f = (_Float16*)(ws + OFF_W2);
    _Float16* wF  = (_Float16*)(ws + OFF_WF);
    _Float16* wC1 = (_Float16*)(ws + OFF_WC1);
    _Float16* wC2 = (_Float16*)(ws + OFF_WC2);
    _Float16* wC3 = (_Float16*)(ws + OFF_WC3);
    float* bC2 = (float*)(ws + OFF_BC2);
    float* bC3 = (float*)(ws + OFF_BC3);
    float* cv  = (float*)(ws + OFF_CVEC);
    float* xmx = (float*)(ws + OFF_XMAX);
    float* xav = (float*)(ws + OFF_XAVG);
    float* pmx = (float*)(ws + OFF_PMAX);
    float* psm = (float*)(ws + OFF_PSUM);

    // prep
    fold_w_kernel<<<dim3(2048, 12), 256, 0, stream>>>(We1, ge1, We2, ge2, W1, g1, W2, g2, Wf, gf, Wc1, gc1, Wc2, gc2, Wc3, ws);
    fold_bias_kernel<<<dim3(2), 256, 0, stream>>>(gc2, bc2, bb2, bc3, ws);
    x0prep_kernel<<<dim3(MM / 256), 256, 0, stream>>>(points, x0);
    knn_kernel<<<dim3(BB, NN / 32), 256, 0, stream>>>(points, idx);

    // e1: x0(Mx32) -> tT(Mx128), relu
    gemm_bt<<<dim3(256, 2), 256, 0, stream>>>(wE1, x0, tT, nullptr, be1, nullptr, 32, 32, 0, 128, 0, 128, 1, 0, 0, 0);
    // e2: tT -> hT, relu
    gemm_bt<<<dim3(256, 2), 256, 0, stream>>>(wE2, tT, hT, nullptr, be2, nullptr, 128, 128, 0, 128, 0, 128, 1, 0, 0, 0);

    for (int i = 0; i < 3; ++i) {
        const _Float16* hin = (i == 0) ? hT : xct;
        int ldH  = (i == 0) ? 128 : 384;
        int offH = (i == 0) ? 0 : (i - 1) * 128;
        // t = relu(bn(W1 h))
        gemm_bt<<<dim3(256, 2), 256, 0, stream>>>(w1f + (size_t)i * 16384, hin, tT, nullptr, b1 + i * 128, nullptr,
                                                  128, ldH, offH, 128, 0, 128, 1, 0, 0, 0);
        // m = neighbor max
        gather_max_kernel<<<dim3(MM / 16), 256, 0, stream>>>((const short*)tT, idx, (short*)mT);
        // h' = relu(bn(W2 m) + h) -> xcat slice i
        gemm_bt<<<dim3(256, 2), 256, 0, stream>>>(w2f + (size_t)i * 16384, mT, xct, nullptr, b2 + i * 128, hin,
                                                  128, 128, 0, 384, i * 128, 128, 1, 0, ldH, offH);
    }

    // xf = leaky(bn(Wf xcat))
    gemm_bt<<<dim3(256, 16), 256, 0, stream>>>(wF, xct, xf, nullptr, bfv, nullptr, 384, 384, 0, 1024, 0, 1024, 2, 0, 0, 0);

    // pooling + per-batch classifier constant
    reduce1_kernel<<<dim3(BB, 4, 8), 256, 0, stream>>>(xf, pmx, psm);
    reduce2_kernel<<<dim3(BB, 4), 256, 0, stream>>>(pmx, psm, xmx, xav);
    cvec_kernel<<<dim3(BB, 8), 256, 0, stream>>>(label, Wl, gl, bl, Wc1, bc1, gc1, bb1, xmx, xav, cv);

    // c1 = relu(gc1*Wc1[:, :1024] xf + cvec[b])
    gemm_bt<<<dim3(256, 8), 256, 0, stream>>>(wC1, xf, c1, nullptr, cv, nullptr, 1024, 1024, 0, 512, 0, 512, 1, 1, 0, 0);
    // c2 = relu(bn(Wc2 c1 + bc2))
    gemm_bt<<<dim3(256, 4), 256, 0, stream>>>(wC2, c1, c2, nullptr, bC2, nullptr, 512, 512, 0, 256, 0, 256, 1, 0, 0, 0);
    // c3 = Wc3 c2 + bc3 (no act), f32 out
    gemm_bt<<<dim3(256, 1), 256, 0, stream>>>(wC3, c2, nullptr, c3, bC3, nullptr, 256, 256, 0, 64, 0, 64, 0, 0, 0, 0);

    // (M x 64) -> (B,50,N)
    reformat_kernel<<<dim3(BB * 50 * NN / 256), 256, 0, stream>>>(c3, (float*)d_out);
}

// Round 5
// 688.174 us; speedup vs baseline: 2.5220x; 1.7966x over previous
//
#include <hip/hip_runtime.h>
#include <cstdint>
#include <cstddef>

#define DEVINL __device__ __forceinline__

typedef float    f32x4 __attribute__((ext_vector_type(4)));
typedef _Float16 f16x8 __attribute__((ext_vector_type(8)));
typedef _Float16 f16x4 __attribute__((ext_vector_type(4)));

// ---------------- constants ----------------
constexpr int BB = 16, NN = 2048, MM = 32768;

// ---------------- ws layout (bytes) ----------------
constexpr size_t OFF_WE1 = 0;                           // 128x64 f16 (Kp padded 6->64)
constexpr size_t OFF_WE2 = OFF_WE1 + 128 * 64 * 2;
constexpr size_t OFF_W1  = OFF_WE2 + 128 * 128 * 2;
constexpr size_t OFF_W2  = OFF_W1  + 3 * 128 * 128 * 2;
constexpr size_t OFF_WF  = OFF_W2  + 3 * 128 * 128 * 2;
constexpr size_t OFF_WC1 = OFF_WF  + 1024 * 384 * 2;
constexpr size_t OFF_WC2 = OFF_WC1 + 512 * 1024 * 2;
constexpr size_t OFF_WC3 = OFF_WC2 + 256 * 512 * 2;     // 128x256 (Opad 50->128)
constexpr size_t OFF_BC2 = OFF_WC3 + 128 * 256 * 2;     // 256 f32
constexpr size_t OFF_BC3 = OFF_BC2 + 256 * 4;           // 128 f32
constexpr size_t OFF_CVEC= OFF_BC3 + 128 * 4;           // 16x512 f32
constexpr size_t OFF_XMAX= OFF_CVEC+ 16 * 512 * 4;
constexpr size_t OFF_XAVG= OFF_XMAX+ 16 * 1024 * 4;
constexpr size_t OFF_PMAX= OFF_XAVG+ 16 * 1024 * 4;
constexpr size_t OFF_PSUM= OFF_PMAX+ 16 * 8 * 1024 * 4;
constexpr size_t OFF_IDX = OFF_PSUM+ 16 * 8 * 1024 * 4;
constexpr size_t OFF_R1  = 6ull << 20;                  // > OFF_IDX + 2MB
constexpr size_t OFF_X0  = OFF_R1;                      // 4MB  (M x 64 f16, k-padded)
constexpr size_t OFF_HT  = OFF_R1 + (4ull  << 20);      // 8MB  (M x 128 f16)
constexpr size_t OFF_TT  = OFF_R1 + (12ull << 20);      // 8MB
constexpr size_t OFF_MT  = OFF_R1 + (20ull << 20);      // 8MB
constexpr size_t OFF_C1  = OFF_R1;                      // 32MB (M x 512 f16), aliases x0/h/t/m (dead)
constexpr size_t OFF_XCAT= OFF_R1 + (32ull << 20);      // 24MB (M x 384 f16)
constexpr size_t OFF_C2  = OFF_XCAT;                    // 16MB (M x 256 f16), aliases xcat (dead)
constexpr size_t OFF_XF  = OFF_XCAT + (24ull << 20);    // 64MB (M x 1024 f16)
constexpr size_t OFF_C3  = OFF_XF;                      // 8MB  (M x 64 f32), aliases xf (dead)

// ---------------- weight folding: dst[o*Kp+k] = f16( W[o,k] * g[o] ), zero-padded ----------------
__global__ __launch_bounds__(256) void fold_w_kernel(
    const float* We1, const float* ge1, const float* We2, const float* ge2,
    const float* W1,  const float* g1,  const float* W2,  const float* g2,
    const float* Wf,  const float* gf,  const float* Wc1, const float* gc1,
    const float* Wc2, const float* gc2, const float* Wc3, char* ws)
{
    const int id = blockIdx.y;
    const float* src = nullptr; const float* g = nullptr; _Float16* dst = nullptr;
    int O = 0, K = 0, lds = 0, Kp = 0, Opad = 0;
    switch (id) {
        case 0:  src = We1; g = ge1; O = 128; K = 6;    lds = 6;    Kp = 64;   Opad = 128; dst = (_Float16*)(ws + OFF_WE1); break;
        case 1:  src = We2; g = ge2; O = 128; K = 128;  lds = 128;  Kp = 128;  Opad = 128; dst = (_Float16*)(ws + OFF_WE2); break;
        case 2: case 3: case 4: {
            int i = id - 2;
            src = W1 + (size_t)i * 16384; g = g1 + i * 128; O = 128; K = 128; lds = 128; Kp = 128; Opad = 128;
            dst = (_Float16*)(ws + OFF_W1) + (size_t)i * 16384; break; }
        case 5: case 6: case 7: {
            int i = id - 5;
            src = W2 + (size_t)i * 16384; g = g2 + i * 128; O = 128; K = 128; lds = 128; Kp = 128; Opad = 128;
            dst = (_Float16*)(ws + OFF_W2) + (size_t)i * 16384; break; }
        case 8:  src = Wf;  g = gf;  O = 1024; K = 384;  lds = 384;  Kp = 384;  Opad = 1024; dst = (_Float16*)(ws + OFF_WF);  break;
        case 9:  src = Wc1; g = gc1; O = 512;  K = 1024; lds = 3136; Kp = 1024; Opad = 512;  dst = (_Float16*)(ws + OFF_WC1); break;
        case 10: src = Wc2; g = gc2; O = 256;  K = 512;  lds = 512;  Kp = 512;  Opad = 256;  dst = (_Float16*)(ws + OFF_WC2); break;
        default: src = Wc3; g = nullptr; O = 50; K = 256; lds = 256; Kp = 256;  Opad = 128;  dst = (_Float16*)(ws + OFF_WC3); break;
    }
    int e = blockIdx.x * 256 + threadIdx.x;
    if (e >= Opad * Kp) return;
    int o = e / Kp, k = e - o * Kp;
    float v = 0.f;
    if (o < O && k < K) {
        v = src[(size_t)o * lds + k];
        if (g) v *= g[o];
    }
    dst[e] = (_Float16)v;
}

// ---------------- bias folding ----------------
__global__ __launch_bounds__(256) void fold_bias_kernel(
    const float* gc2, const float* bc2, const float* bb2, const float* bc3, char* ws)
{
    const int id = blockIdx.x, tid = threadIdx.x;
    if (id == 0) {
        ((float*)(ws + OFF_BC2))[tid] = gc2[tid] * bc2[tid] + bb2[tid];
    } else if (tid < 128) {
        ((float*)(ws + OFF_BC3))[tid] = (tid < 50) ? bc3[tid] : 0.f;
    }
}

// ---------------- x0 prep: (B,6,N) f32 -> (M x 64) f16 K-contig, zero pad ----------------
__global__ __launch_bounds__(256) void x0prep_kernel(const float* __restrict__ pts, _Float16* __restrict__ x0)
{
    int m = blockIdx.x * 256 + threadIdx.x;
    int b = m >> 11, n = m & 2047;
    const float* ps = pts + (size_t)b * 6 * 2048 + n;
    _Float16 tmp[64];
#pragma unroll
    for (int c = 0; c < 64; ++c) tmp[c] = (_Float16)0.f;
#pragma unroll
    for (int c = 0; c < 6; ++c) tmp[c] = (_Float16)ps[(size_t)c << 11];
    _Float16* dst = x0 + (size_t)m * 64;
#pragma unroll
    for (int v = 0; v < 8; ++v) *(f16x8*)(dst + v * 8) = *(const f16x8*)(tmp + v * 8);
}

// ---------------- KNN v4: parallel-insert top-16 (ILP depth ~3 instead of serial bubble) ----------------
// block: 256 threads = 32 queries x 8 partitions. grid: (B, N/32).
// Invariant: d0 <= d1 <= ... <= d15 (ascending). All q_j computed independently,
// then each slot shifts reading only OLD neighbor values (descending update order).
#define KNN_INS(DV, MV) do { \
    const float dv_ = (DV); const int mv_ = (MV); \
    const bool q0 = dv_ < d0,  q1 = dv_ < d1,  q2 = dv_ < d2,  q3 = dv_ < d3, \
               q4 = dv_ < d4,  q5 = dv_ < d5,  q6 = dv_ < d6,  q7 = dv_ < d7, \
               q8 = dv_ < d8,  q9 = dv_ < d9,  q10 = dv_ < d10, q11 = dv_ < d11, \
               q12 = dv_ < d12, q13 = dv_ < d13, q14 = dv_ < d14, q15 = dv_ < d15; \
    d15 = q14 ? d14 : (q15 ? dv_ : d15); i15 = q14 ? i14 : (q15 ? mv_ : i15); \
    d14 = q13 ? d13 : (q14 ? dv_ : d14); i14 = q13 ? i13 : (q14 ? mv_ : i14); \
    d13 = q12 ? d12 : (q13 ? dv_ : d13); i13 = q12 ? i12 : (q13 ? mv_ : i13); \
    d12 = q11 ? d11 : (q12 ? dv_ : d12); i12 = q11 ? i11 : (q12 ? mv_ : i12); \
    d11 = q10 ? d10 : (q11 ? dv_ : d11); i11 = q10 ? i10 : (q11 ? mv_ : i11); \
    d10 = q9  ? d9  : (q10 ? dv_ : d10); i10 = q9  ? i9  : (q10 ? mv_ : i10); \
    d9  = q8  ? d8  : (q9  ? dv_ : d9);  i9  = q8  ? i8  : (q9  ? mv_ : i9);  \
    d8  = q7  ? d7  : (q8  ? dv_ : d8);  i8  = q7  ? i7  : (q8  ? mv_ : i8);  \
    d7  = q6  ? d6  : (q7  ? dv_ : d7);  i7  = q6  ? i6  : (q7  ? mv_ : i7);  \
    d6  = q5  ? d5  : (q6  ? dv_ : d6);  i6  = q5  ? i5  : (q6  ? mv_ : i6);  \
    d5  = q4  ? d4  : (q5  ? dv_ : d5);  i5  = q4  ? i4  : (q5  ? mv_ : i5);  \
    d4  = q3  ? d3  : (q4  ? dv_ : d4);  i4  = q3  ? i3  : (q4  ? mv_ : i4);  \
    d3  = q2  ? d2  : (q3  ? dv_ : d3);  i3  = q2  ? i2  : (q3  ? mv_ : i3);  \
    d2  = q1  ? d1  : (q2  ? dv_ : d2);  i2  = q1  ? i1  : (q2  ? mv_ : i2);  \
    d1  = q0  ? d0  : (q1  ? dv_ : d1);  i1  = q0  ? i0  : (q1  ? mv_ : i1);  \
    d0  = q0  ? dv_ : d0;                i0  = q0  ? mv_ : i0;                \
} while (0)

__global__ __launch_bounds__(256) void knn_kernel(const float* __restrict__ pts, int* __restrict__ idxout)
{
    __shared__ float4 P[2048];
    const int tid = threadIdx.x;
    const int b = blockIdx.x;
    const float* pb = pts + (size_t)b * 6 * 2048;
    for (int i = tid; i < 2048; i += 256) {
        float x = pb[i];
        float y = pb[2048 + i];
        float z = pb[4096 + i];
        P[i] = make_float4(x, y, z, x * x + y * y + z * z);
    }
    __syncthreads();

    const int p = tid & 7;          // candidate partition (m == 8*i + p)
    const int g = tid >> 3;         // query within block (0..31)
    const int q = blockIdx.y * 32 + g;
    const float4 pq = P[q];

    float d0 = 3.4e38f, d1 = 3.4e38f, d2 = 3.4e38f, d3 = 3.4e38f,
          d4 = 3.4e38f, d5 = 3.4e38f, d6 = 3.4e38f, d7 = 3.4e38f,
          d8 = 3.4e38f, d9 = 3.4e38f, d10 = 3.4e38f, d11 = 3.4e38f,
          d12 = 3.4e38f, d13 = 3.4e38f, d14 = 3.4e38f, d15 = 3.4e38f;
    int i0 = 0, i1 = 0, i2 = 0, i3 = 0, i4 = 0, i5 = 0, i6 = 0, i7 = 0,
        i8 = 0, i9 = 0, i10 = 0, i11 = 0, i12 = 0, i13 = 0, i14 = 0, i15 = 0;

    float4 nxt = P[p];
    for (int it = 0; it < 256; ++it) {
        const float4 pm = nxt;
        const int m = it * 8 + p;
        nxt = P[(m + 8) & 2047];    // prefetch next candidate (wraps harmlessly on last)
        const float d = pq.w + pm.w - 2.f * (pq.x * pm.x + pq.y * pm.y + pq.z * pm.z);
        KNN_INS(d, m);              // branchless: all-false predicates = no-op
    }

    __syncthreads();                 // everyone done reading P; reuse its LDS
    float* md = (float*)P;           // md[j*256 + tid]
    int*   mi = (int*)(P + 1024);    // mi[j*256 + tid]
#define KNN_SPILL(J) { md[J * 256 + tid] = d##J; mi[J * 256 + tid] = i##J; }
    KNN_SPILL(0)  KNN_SPILL(1)  KNN_SPILL(2)  KNN_SPILL(3)
    KNN_SPILL(4)  KNN_SPILL(5)  KNN_SPILL(6)  KNN_SPILL(7)
    KNN_SPILL(8)  KNN_SPILL(9)  KNN_SPILL(10) KNN_SPILL(11)
    KNN_SPILL(12) KNN_SPILL(13) KNN_SPILL(14) KNN_SPILL(15)
#undef KNN_SPILL
    __syncthreads();

    if (p == 0) {
        // merge the 7 other sorted (ascending) lists; early exit per list
        for (int s = 1; s < 8; ++s) {
            const int base = g * 8 + s;
#pragma unroll
            for (int j = 0; j < 16; ++j) {
                const float dd = md[j * 256 + base];
                if (dd >= d15) break;
                const int mm = mi[j * 256 + base];
                KNN_INS(dd, mm);
            }
        }
        int* op = idxout + ((size_t)(b * 2048 + q)) * 16;
        op[0]  = i0;  op[1]  = i1;  op[2]  = i2;  op[3]  = i3;
        op[4]  = i4;  op[5]  = i5;  op[6]  = i6;  op[7]  = i7;
        op[8]  = i8;  op[9]  = i9;  op[10] = i10; op[11] = i11;
        op[12] = i12; op[13] = i13; op[14] = i14; op[15] = i15;
    }
}

// ---------------- GEMM v2 (m97-style): 128m x 128o tile, BK=64, global_load_lds staging ----------------
// 256 threads = 4 waves in 2x2: wave: o-half = (wave>>1)*64, m-half = (wave&1)*64.
// Per wave 4x4 frags of 16x16x32 f16 MFMA. LDS tiles row-major [row][64k] with
// XOR k-slot swizzle (slot ^= row&7) for conflict-free ds_read_b128.
// Requires: Kp % 64 == 0, Opad % 128 == 0. Stores f16 to Y (or f32 to Y32), cols < Olimit.
__global__ __launch_bounds__(256) void gemm_tile(
    const _Float16* __restrict__ W, const _Float16* __restrict__ X,
    _Float16* __restrict__ Y, float* __restrict__ Y32,
    const float* __restrict__ bias, const _Float16* __restrict__ Res,
    int Kp, int ldX, int xoff, int ldY, int yoff, int Opad,
    int act, int biasPerBatch, int ldR, int roff, int Olimit)
{
    __shared__ _Float16 As[128 * 64];
    __shared__ _Float16 Bs[128 * 64];
    const int tid  = threadIdx.x;
    const int lane = tid & 63, wave = tid >> 6;
    const int r = lane & 15, quad = lane >> 4;
    const int m_blk = blockIdx.x * 128, o_blk = blockIdx.y * 128;
    const int oh = (wave >> 1) * 64, mh = (wave & 1) * 64;

    f32x4 acc[4][4];
#pragma unroll
    for (int a = 0; a < 4; ++a)
#pragma unroll
        for (int c = 0; c < 4; ++c) acc[a][c] = (f32x4){0.f, 0.f, 0.f, 0.f};

    const int srow  = wave * 8 + (lane >> 3);   // + t*32 per chunk
    const int sslot = lane & 7;

    for (int k0 = 0; k0 < Kp; k0 += 64) {
        __syncthreads();
#pragma unroll
        for (int t = 0; t < 4; ++t) {
            const int rowA = t * 32 + srow;
            const int gk = k0 + (((sslot ^ (rowA & 7))) << 3);
            const _Float16* gA = W + (size_t)(o_blk + rowA) * Kp + gk;
            const _Float16* gB = X + (size_t)(m_blk + rowA) * ldX + xoff + gk;
            __builtin_amdgcn_global_load_lds(
                (const __attribute__((address_space(1))) unsigned int*)gA,
                (__attribute__((address_space(3))) unsigned int*)(As + t * 2048 + wave * 512),
                16, 0, 0);
            __builtin_amdgcn_global_load_lds(
                (const __attribute__((address_space(1))) unsigned int*)gB,
                (__attribute__((address_space(3))) unsigned int*)(Bs + t * 2048 + wave * 512),
                16, 0, 0);
        }
        __syncthreads();
#pragma unroll
        for (int ks = 0; ks < 2; ++ks) {
            f16x8 af[4], bf[4];
#pragma unroll
            for (int oi = 0; oi < 4; ++oi) {
                const int row = oh + oi * 16 + r;
                const int slot = (ks * 4 + quad) ^ (row & 7);
                af[oi] = *(const f16x8*)(As + row * 64 + slot * 8);
            }
#pragma unroll
            for (int mi = 0; mi < 4; ++mi) {
                const int row = mh + mi * 16 + r;
                const int slot = (ks * 4 + quad) ^ (row & 7);
                bf[mi] = *(const f16x8*)(Bs + row * 64 + slot * 8);
            }
#pragma unroll
            for (int oi = 0; oi < 4; ++oi)
#pragma unroll
                for (int mi = 0; mi < 4; ++mi)
                    acc[oi][mi] = __builtin_amdgcn_mfma_f32_16x16x32_f16(af[oi], bf[mi], acc[oi][mi], 0, 0, 0);
        }
    }

    const int bb = biasPerBatch ? (m_blk >> 11) * Opad : 0;
#pragma unroll
    for (int oi = 0; oi < 4; ++oi) {
        const int og = o_blk + oh + oi * 16 + quad * 4;   // first of 4 output cols
        if (og >= Olimit) continue;
        const f32x4 bv = *(const f32x4*)(bias + bb + og);
#pragma unroll
        for (int mi = 0; mi < 4; ++mi) {
            const int m = m_blk + mh + mi * 16 + r;
            f32x4 v = acc[oi][mi] + bv;
            if (Res) {
                f16x4 rr = *(const f16x4*)(Res + (size_t)m * ldR + roff + og);
#pragma unroll
                for (int j = 0; j < 4; ++j) v[j] += (float)rr[j];
            }
#pragma unroll
            for (int j = 0; j < 4; ++j) {
                float x = v[j];
                if (act == 1)      x = (x > 0.f) ? x : 0.0f;
                else if (act == 2) x = (x > 0.f) ? x : 0.2f * x;
                v[j] = x;
            }
            if (Y32) {
                *(f32x4*)(Y32 + (size_t)m * ldY + yoff + og) = v;
            } else {
                f16x4 ov;
#pragma unroll
                for (int j = 0; j < 4; ++j) ov[j] = (_Float16)v[j];
                *(f16x4*)(Y + (size_t)m * ldY + yoff + og) = ov;
            }
        }
    }
}

// ---------------- neighbor gather + channel max (relu outputs => ushort-monotonic f16 bits) ----------------
typedef short s16x8 __attribute__((ext_vector_type(8)));
__global__ __launch_bounds__(256) void gather_max_kernel(
    const short* __restrict__ T, const int* __restrict__ idx, short* __restrict__ Mo)
{
    const int tid = threadIdx.x;
    const int p = blockIdx.x * 16 + (tid >> 4);
    const int l = tid & 15;
    const int b = p >> 11;
    const int* ip = idx + (size_t)p * 16;
    size_t row = (size_t)((b << 11) + ip[0]);
    s16x8 cur = *(const s16x8*)(T + row * 128 + l * 8);
    unsigned short best[8];
#pragma unroll
    for (int e = 0; e < 8; ++e) best[e] = (unsigned short)cur[e];
#pragma unroll
    for (int j = 1; j < 16; ++j) {
        row = (size_t)((b << 11) + ip[j]);
        s16x8 v = *(const s16x8*)(T + row * 128 + l * 8);
#pragma unroll
        for (int e = 0; e < 8; ++e) {
            unsigned short u = (unsigned short)v[e];
            if (u > best[e]) best[e] = u;
        }
    }
    s16x8 ov;
#pragma unroll
    for (int e = 0; e < 8; ++e) ov[e] = (short)best[e];
    *(s16x8*)(Mo + (size_t)p * 128 + l * 8) = ov;
}

// ---------------- pooling reductions over n ----------------
__global__ __launch_bounds__(256) void reduce1_kernel(const _Float16* __restrict__ xf, float* __restrict__ pmax, float* __restrict__ psum)
{
    const int b = blockIdx.x, oc = blockIdx.y, ch = blockIdx.z, tid = threadIdx.x;
    const int o = oc * 256 + tid;
    const _Float16* p = xf + ((size_t)(b << 11) + ch * 256) * 1024 + o;
    float mx = -3.4e38f, sm = 0.f;
    for (int n = 0; n < 256; ++n) {
        float v = (float)p[(size_t)n * 1024];
        mx = fmaxf(mx, v); sm += v;
    }
    pmax[((size_t)(b * 8 + ch) << 10) + o] = mx;
    psum[((size_t)(b * 8 + ch) << 10) + o] = sm;
}

__global__ __launch_bounds__(256) void reduce2_kernel(const float* __restrict__ pmax, const float* __restrict__ psum,
                                                      float* __restrict__ xmax, float* __restrict__ xavg)
{
    const int b = blockIdx.x, oc = blockIdx.y, tid = threadIdx.x;
    const int o = oc * 256 + tid;
    float mx = -3.4e38f, sm = 0.f;
#pragma unroll
    for (int c = 0; c < 8; ++c) {
        mx = fmaxf(mx, pmax[((size_t)(b * 8 + c) << 10) + o]);
        sm += psum[((size_t)(b * 8 + c) << 10) + o];
    }
    xmax[((size_t)b << 10) + o] = mx;
    xavg[((size_t)b << 10) + o] = sm * (1.f / 2048.f);
}

// ---------------- per-batch constant vector for Wc1 (broadcast cols 1024..3135 + bias/bn) ----------------
__global__ __launch_bounds__(256) void cvec_kernel(
    const float* __restrict__ label, const float* __restrict__ Wl, const float* __restrict__ gl, const float* __restrict__ bl,
    const float* __restrict__ Wc1, const float* __restrict__ bc1, const float* __restrict__ gc1, const float* __restrict__ bb1,
    const float* __restrict__ xmax, const float* __restrict__ xavg, float* __restrict__ cvec)
{
    __shared__ float v[2112];
    __shared__ float red[256];
    const int b = blockIdx.x, og = blockIdx.y, tid = threadIdx.x;
    for (int i = tid; i < 1024; i += 256) v[i] = xmax[((size_t)b << 10) + i];
    for (int i = tid; i < 1024; i += 256) v[1024 + i] = xavg[((size_t)b << 10) + i];
    if (tid < 64) {
        float s = 0.f;
        for (int i = 0; i < 16; ++i) s += Wl[tid * 16 + i] * label[b * 16 + i];
        s = gl[tid] * s + bl[tid];
        v[2048 + tid] = (s > 0.f) ? s : 0.2f * s;
    }
    __syncthreads();
    const int o = og * 64 + (tid >> 2), part = tid & 3;
    const float* wrow = Wc1 + (size_t)o * 3136 + 1024 + part * 528;
    float s = 0.f;
    for (int j = 0; j < 528; ++j) s += wrow[j] * v[part * 528 + j];
    red[tid] = s;
    __syncthreads();
    if (part == 0) {
        float tot = red[tid] + red[tid + 1] + red[tid + 2] + red[tid + 3];
        cvec[((size_t)b << 9) + o] = gc1[o] * (tot + bc1[o]) + bb1[o];
    }
}

// ---------------- final layout (M x 64 f32) -> (B,50,N) f32 ----------------
__global__ __launch_bounds__(256) void reformat_kernel(const float* __restrict__ c3, float* __restrict__ out)
{
    int i = blockIdx.x * 256 + threadIdx.x;       // 16*50*2048 total
    int n = i & 2047;
    int t = i >> 11;        // b*50 + o
    int o = t % 50;
    int b = t / 50;
    out[i] = c3[((size_t)((b << 11) + n)) * 64 + o];
}

// ---------------- launch ----------------
extern "C" void kernel_launch(void* const* d_in, const int* in_sizes, int n_in,
                              void* d_out, int out_size, void* d_ws, size_t ws_size,
                              hipStream_t stream)
{
    (void)in_sizes; (void)n_in; (void)out_size; (void)ws_size;
    const float* points = (const float*)d_in[0];
    const float* label  = (const float*)d_in[1];
    const float* We1 = (const float*)d_in[2];
    const float* ge1 = (const float*)d_in[3];
    const float* be1 = (const float*)d_in[4];
    const float* We2 = (const float*)d_in[5];
    const float* ge2 = (const float*)d_in[6];
    const float* be2 = (const float*)d_in[7];
    const float* W1  = (const float*)d_in[8];
    const float* g1  = (const float*)d_in[9];
    const float* b1  = (const float*)d_in[10];
    const float* W2  = (const float*)d_in[11];
    const float* g2  = (const float*)d_in[12];
    const float* b2  = (const float*)d_in[13];
    const float* Wf  = (const float*)d_in[14];
    const float* gf  = (const float*)d_in[15];
    const float* bfv = (const float*)d_in[16];
    const float* Wl  = (const float*)d_in[17];
    const float* gl  = (const float*)d_in[18];
    const float* bl  = (const float*)d_in[19];
    const float* Wc1 = (const float*)d_in[20];
    const float* bc1 = (const float*)d_in[21];
    const float* gc1 = (const float*)d_in[22];
    const float* bb1 = (const float*)d_in[23];
    const float* Wc2 = (const float*)d_in[24];
    const float* bc2 = (const float*)d_in[25];
    const float* gc2 = (const float*)d_in[26];
    const float* bb2 = (const float*)d_in[27];
    const float* Wc3 = (const float*)d_in[28];
    const float* bc3 = (const float*)d_in[29];

    char* ws = (char*)d_ws;
    _Float16* x0  = (_Float16*)(ws + OFF_X0);
    _Float16* hT  = (_Float16*)(ws + OFF_HT);
    _Float16* tT  = (_Float16*)(ws + OFF_TT);
    _Float16* mT  = (_Float16*)(ws + OFF_MT);
    _Float16* xct = (_Float16*)(ws + OFF_XCAT);
    _Float16* xf  = (_Float16*)(ws + OFF_XF);
    _Float16* c1  = (_Float16*)(ws + OFF_C1);
    _Float16* c2  = (_Float16*)(ws + OFF_C2);
    float*    c3  = (float*)   (ws + OFF_C3);
    int*      idx = (int*)     (ws + OFF_IDX);

    _Float16* wE1 = (_Float16*)(ws + OFF_WE1);
    _Float16* wE2 = (_Float16*)(ws + OFF_WE2);
    _Float16* w1f = (_Float16*)(ws + OFF_W1);
    _Float16* w2f = (_Float16*)(ws + OFF_W2);
    _Float16* wF  = (_Float16*)(ws + OFF_WF);
    _Float16* wC1 = (_Float16*)(ws + OFF_WC1);
    _Float16* wC2 = (_Float16*)(ws + OFF_WC2);
    _Float16* wC3 = (_Float16*)(ws + OFF_WC3);
    float* bC2 = (float*)(ws + OFF_BC2);
    float* bC3 = (float*)(ws + OFF_BC3);
    float* cv  = (float*)(ws + OFF_CVEC);
    float* xmx = (float*)(ws + OFF_XMAX);
    float* xav = (float*)(ws + OFF_XAVG);
    float* pmx = (float*)(ws + OFF_PMAX);
    float* psm = (float*)(ws + OFF_PSUM);

    // prep
    fold_w_kernel<<<dim3(2048, 12), 256, 0, stream>>>(We1, ge1, We2, ge2, W1, g1, W2, g2, Wf, gf, Wc1, gc1, Wc2, gc2, Wc3, ws);
    fold_bias_kernel<<<dim3(2), 256, 0, stream>>>(gc2, bc2, bb2, bc3, ws);
    x0prep_kernel<<<dim3(MM / 256), 256, 0, stream>>>(points, x0);
    knn_kernel<<<dim3(BB, NN / 32), 256, 0, stream>>>(points, idx);

    // e1: x0(Mx64,pad) -> tT(Mx128), relu
    gemm_tile<<<dim3(256, 1), 256, 0, stream>>>(wE1, x0, tT, nullptr, be1, nullptr, 64, 64, 0, 128, 0, 128, 1, 0, 0, 0, 128);
    // e2: tT -> hT, relu
    gemm_tile<<<dim3(256, 1), 256, 0, stream>>>(wE2, tT, hT, nullptr, be2, nullptr, 128, 128, 0, 128, 0, 128, 1, 0, 0, 0, 128);

    for (int i = 0; i < 3; ++i) {
        const _Float16* hin = (i == 0) ? hT : xct;
        int ldH  = (i == 0) ? 128 : 384;
        int offH = (i == 0) ? 0 : (i - 1) * 128;
        // t = relu(bn(W1 h))
        gemm_tile<<<dim3(256, 1), 256, 0, stream>>>(w1f + (size_t)i * 16384, hin, tT, nullptr, b1 + i * 128, nullptr,
                                                    128, ldH, offH, 128, 0, 128, 1, 0, 0, 0, 128);
        // m = neighbor max
        gather_max_kernel<<<dim3(MM / 16), 256, 0, stream>>>((const short*)tT, idx, (short*)mT);
        // h' = relu(bn(W2 m) + h) -> xcat slice i
        gemm_tile<<<dim3(256, 1), 256, 0, stream>>>(w2f + (size_t)i * 16384, mT, xct, nullptr, b2 + i * 128, hin,
                                                    128, 128, 0, 384, i * 128, 128, 1, 0, ldH, offH, 128);
    }

    // xf = leaky(bn(Wf xcat))
    gemm_tile<<<dim3(256, 8), 256, 0, stream>>>(wF, xct, xf, nullptr, bfv, nullptr, 384, 384, 0, 1024, 0, 1024, 2, 0, 0, 0, 1024);

    // pooling + per-batch classifier constant
    reduce1_kernel<<<dim3(BB, 4, 8), 256, 0, stream>>>(xf, pmx, psm);
    reduce2_kernel<<<dim3(BB, 4), 256, 0, stream>>>(pmx, psm, xmx, xav);
    cvec_kernel<<<dim3(BB, 8), 256, 0, stream>>>(label, Wl, gl, bl, Wc1, bc1, gc1, bb1, xmx, xav, cv);

    // c1 = relu(gc1*Wc1[:, :1024] xf + cvec[b])
    gemm_tile<<<dim3(256, 4), 256, 0, stream>>>(wC1, xf, c1, nullptr, cv, nullptr, 1024, 1024, 0, 512, 0, 512, 1, 1, 0, 0, 512);
    // c2 = relu(bn(Wc2 c1 + bc2))
    gemm_tile<<<dim3(256, 2), 256, 0, stream>>>(wC2, c1, c2, nullptr, bC2, nullptr, 512, 512, 0, 256, 0, 256, 1, 0, 0, 0, 256);
    // c3 = Wc3 c2 + bc3 (no act), f32 out, only cols < 64 stored
    gemm_tile<<<dim3(256, 1), 256, 0, stream>>>(wC3, c2, nullptr, c3, bC3, nullptr, 256, 256, 0, 64, 0, 128, 0, 0, 0, 0, 64);

    // (M x 64) -> (B,50,N)
    reformat_kernel<<<dim3(BB * 50 * NN / 256), 256, 0, stream>>>(c3, (float*)d_out);
}

// Round 6
// 550.981 us; speedup vs baseline: 3.1500x; 1.2490x over previous
//
#include <hip/hip_runtime.h>
#include <cstdint>
#include <cstddef>

#define DEVINL __device__ __forceinline__

typedef float    f32x4 __attribute__((ext_vector_type(4)));
typedef _Float16 f16x8 __attribute__((ext_vector_type(8)));
typedef _Float16 f16x4 __attribute__((ext_vector_type(4)));

// ---------------- constants ----------------
constexpr int BB = 16, NN = 2048, MM = 32768;

// ---------------- ws layout (bytes) ----------------
constexpr size_t OFF_WE1 = 0;                           // 128x64 f16 (Kp padded 6->64)
constexpr size_t OFF_WE2 = OFF_WE1 + 128 * 64 * 2;
constexpr size_t OFF_W1  = OFF_WE2 + 128 * 128 * 2;
constexpr size_t OFF_W2  = OFF_W1  + 3 * 128 * 128 * 2;
constexpr size_t OFF_WF  = OFF_W2  + 3 * 128 * 128 * 2;
constexpr size_t OFF_WC1 = OFF_WF  + 1024 * 384 * 2;
constexpr size_t OFF_WC2 = OFF_WC1 + 512 * 1024 * 2;
constexpr size_t OFF_WC3 = OFF_WC2 + 256 * 512 * 2;     // 128x256 (Opad 50->128)
constexpr size_t OFF_BC2 = OFF_WC3 + 128 * 256 * 2;     // 256 f32
constexpr size_t OFF_BC3 = OFF_BC2 + 256 * 4;           // 128 f32
constexpr size_t OFF_CVEC= OFF_BC3 + 128 * 4;           // 16x512 f32
constexpr size_t OFF_XMAX= OFF_CVEC+ 16 * 512 * 4;
constexpr size_t OFF_XAVG= OFF_XMAX+ 16 * 1024 * 4;
constexpr size_t OFF_PMAX= OFF_XAVG+ 16 * 1024 * 4;
constexpr size_t OFF_PSUM= OFF_PMAX+ 16 * 8 * 1024 * 4;
constexpr size_t OFF_IDX = OFF_PSUM+ 16 * 8 * 1024 * 4;
constexpr size_t OFF_THR = OFF_PMAX;                    // 32768 f32 (dead before pmax is written)
constexpr size_t OFF_R1  = 6ull << 20;                  // > OFF_IDX + 2MB
constexpr size_t OFF_X0  = OFF_R1;                      // 4MB  (M x 64 f16, k-padded)
constexpr size_t OFF_HT  = OFF_R1 + (4ull  << 20);      // 8MB  (M x 128 f16)
constexpr size_t OFF_TT  = OFF_R1 + (12ull << 20);      // 8MB
constexpr size_t OFF_MT  = OFF_R1 + (20ull << 20);      // 8MB
constexpr size_t OFF_C1  = OFF_R1;                      // 32MB (M x 512 f16), aliases x0/h/t/m (dead)
constexpr size_t OFF_XCAT= OFF_R1 + (32ull << 20);      // 24MB (M x 384 f16)
constexpr size_t OFF_C2  = OFF_XCAT;                    // 16MB (M x 256 f16), aliases xcat (dead)
constexpr size_t OFF_XF  = OFF_XCAT + (24ull << 20);    // 64MB (M x 1024 f16)
constexpr size_t OFF_C3  = OFF_XF;                      // 8MB  (M x 64 f32), aliases xf (dead)

// ---------------- weight folding: dst[o*Kp+k] = f16( W[o,k] * g[o] ), zero-padded ----------------
__global__ __launch_bounds__(256) void fold_w_kernel(
    const float* We1, const float* ge1, const float* We2, const float* ge2,
    const float* W1,  const float* g1,  const float* W2,  const float* g2,
    const float* Wf,  const float* gf,  const float* Wc1, const float* gc1,
    const float* Wc2, const float* gc2, const float* Wc3, char* ws)
{
    const int id = blockIdx.y;
    const float* src = nullptr; const float* g = nullptr; _Float16* dst = nullptr;
    int O = 0, K = 0, lds = 0, Kp = 0, Opad = 0;
    switch (id) {
        case 0:  src = We1; g = ge1; O = 128; K = 6;    lds = 6;    Kp = 64;   Opad = 128; dst = (_Float16*)(ws + OFF_WE1); break;
        case 1:  src = We2; g = ge2; O = 128; K = 128;  lds = 128;  Kp = 128;  Opad = 128; dst = (_Float16*)(ws + OFF_WE2); break;
        case 2: case 3: case 4: {
            int i = id - 2;
            src = W1 + (size_t)i * 16384; g = g1 + i * 128; O = 128; K = 128; lds = 128; Kp = 128; Opad = 128;
            dst = (_Float16*)(ws + OFF_W1) + (size_t)i * 16384; break; }
        case 5: case 6: case 7: {
            int i = id - 5;
            src = W2 + (size_t)i * 16384; g = g2 + i * 128; O = 128; K = 128; lds = 128; Kp = 128; Opad = 128;
            dst = (_Float16*)(ws + OFF_W2) + (size_t)i * 16384; break; }
        case 8:  src = Wf;  g = gf;  O = 1024; K = 384;  lds = 384;  Kp = 384;  Opad = 1024; dst = (_Float16*)(ws + OFF_WF);  break;
        case 9:  src = Wc1; g = gc1; O = 512;  K = 1024; lds = 3136; Kp = 1024; Opad = 512;  dst = (_Float16*)(ws + OFF_WC1); break;
        case 10: src = Wc2; g = gc2; O = 256;  K = 512;  lds = 512;  Kp = 512;  Opad = 256;  dst = (_Float16*)(ws + OFF_WC2); break;
        default: src = Wc3; g = nullptr; O = 50; K = 256; lds = 256; Kp = 256;  Opad = 128;  dst = (_Float16*)(ws + OFF_WC3); break;
    }
    int e = blockIdx.x * 256 + threadIdx.x;
    if (e >= Opad * Kp) return;
    int o = e / Kp, k = e - o * Kp;
    float v = 0.f;
    if (o < O && k < K) {
        v = src[(size_t)o * lds + k];
        if (g) v *= g[o];
    }
    dst[e] = (_Float16)v;
}

// ---------------- bias folding ----------------
__global__ __launch_bounds__(256) void fold_bias_kernel(
    const float* gc2, const float* bc2, const float* bb2, const float* bc3, char* ws)
{
    const int id = blockIdx.x, tid = threadIdx.x;
    if (id == 0) {
        ((float*)(ws + OFF_BC2))[tid] = gc2[tid] * bc2[tid] + bb2[tid];
    } else if (tid < 128) {
        ((float*)(ws + OFF_BC3))[tid] = (tid < 50) ? bc3[tid] : 0.f;
    }
}

// ---------------- x0 prep: (B,6,N) f32 -> (M x 64) f16 K-contig, zero pad ----------------
__global__ __launch_bounds__(256) void x0prep_kernel(const float* __restrict__ pts, _Float16* __restrict__ x0)
{
    int m = blockIdx.x * 256 + threadIdx.x;
    int b = m >> 11, n = m & 2047;
    const float* ps = pts + (size_t)b * 6 * 2048 + n;
    _Float16 tmp[64];
#pragma unroll
    for (int c = 0; c < 64; ++c) tmp[c] = (_Float16)0.f;
#pragma unroll
    for (int c = 0; c < 6; ++c) tmp[c] = (_Float16)ps[(size_t)c << 11];
    _Float16* dst = x0 + (size_t)m * 64;
#pragma unroll
    for (int v = 0; v < 8; ++v) *(f16x8*)(dst + v * 8) = *(const f16x8*)(tmp + v * 8);
}

// ---------------- KNN v5: two-pass threshold selection ----------------
// Pass 1 (knn_select): per-thread sorted top-16 DISTANCES ONLY via min/max
// sorting-insert (31 VALU, no cmp/cndmask/index); LDS merge of 8 partition
// lists -> thr[q] = 16th-smallest distance.
// Pass 2 (knn_collect): rescan, d <= thr[q] -> append index (LDS atomic slot).
// Distance expression shared (inline fn) so both passes are bit-identical.

DEVINL float knn_dist(const float4 pq, const float4 pm) {
    float t = pq.x * pm.x;
    t = fmaf(pq.y, pm.y, t);
    t = fmaf(pq.z, pm.z, t);
    return pq.w + pm.w - 2.f * t;
}

// sorted ascending insert of x into d0..d15 (distances only).
// dJ' = min(max(d_{J-1}, x), dJ), descending order uses old neighbors.
#define KNN_DINS(X) do { \
    const float x_ = (X); \
    d15 = fminf(fmaxf(d14, x_), d15); \
    d14 = fminf(fmaxf(d13, x_), d14); \
    d13 = fminf(fmaxf(d12, x_), d13); \
    d12 = fminf(fmaxf(d11, x_), d12); \
    d11 = fminf(fmaxf(d10, x_), d11); \
    d10 = fminf(fmaxf(d9,  x_), d10); \
    d9  = fminf(fmaxf(d8,  x_), d9);  \
    d8  = fminf(fmaxf(d7,  x_), d8);  \
    d7  = fminf(fmaxf(d6,  x_), d7);  \
    d6  = fminf(fmaxf(d5,  x_), d6);  \
    d5  = fminf(fmaxf(d4,  x_), d5);  \
    d4  = fminf(fmaxf(d3,  x_), d4);  \
    d3  = fminf(fmaxf(d2,  x_), d3);  \
    d2  = fminf(fmaxf(d1,  x_), d2);  \
    d1  = fminf(fmaxf(d0,  x_), d1);  \
    d0  = fminf(d0, x_); \
} while (0)

__global__ __launch_bounds__(256) void knn_select(const float* __restrict__ pts, float* __restrict__ thr)
{
    __shared__ float4 P[2048];
    const int tid = threadIdx.x;
    const int b = blockIdx.x;
    const float* pb = pts + (size_t)b * 6 * 2048;
    for (int i = tid; i < 2048; i += 256) {
        float x = pb[i];
        float y = pb[2048 + i];
        float z = pb[4096 + i];
        P[i] = make_float4(x, y, z, x * x + y * y + z * z);
    }
    __syncthreads();

    const int p = tid & 7;          // candidate partition (m == 8*it + p)
    const int g = tid >> 3;         // query within block (0..31)
    const int q = blockIdx.y * 32 + g;
    const float4 pq = P[q];

    float d0 = 3.4e38f, d1 = 3.4e38f, d2 = 3.4e38f, d3 = 3.4e38f,
          d4 = 3.4e38f, d5 = 3.4e38f, d6 = 3.4e38f, d7 = 3.4e38f,
          d8 = 3.4e38f, d9 = 3.4e38f, d10 = 3.4e38f, d11 = 3.4e38f,
          d12 = 3.4e38f, d13 = 3.4e38f, d14 = 3.4e38f, d15 = 3.4e38f;

    float4 nxt = P[p];
#pragma unroll 2
    for (int it = 0; it < 256; ++it) {
        const float4 pm = nxt;
        const int m = it * 8 + p;
        nxt = P[(m + 8) & 2047];    // prefetch next candidate (wraps harmlessly on last)
        KNN_DINS(knn_dist(pq, pm));
    }

    __syncthreads();                 // everyone done reading P; reuse its LDS
    float* md = (float*)P;           // md[j*256 + tid]
#define KNN_SPILL(J) md[J * 256 + tid] = d##J;
    KNN_SPILL(0)  KNN_SPILL(1)  KNN_SPILL(2)  KNN_SPILL(3)
    KNN_SPILL(4)  KNN_SPILL(5)  KNN_SPILL(6)  KNN_SPILL(7)
    KNN_SPILL(8)  KNN_SPILL(9)  KNN_SPILL(10) KNN_SPILL(11)
    KNN_SPILL(12) KNN_SPILL(13) KNN_SPILL(14) KNN_SPILL(15)
#undef KNN_SPILL
    __syncthreads();

    if (p == 0) {
        // merge the 7 other sorted (ascending) lists; early exit per list
        for (int s = 1; s < 8; ++s) {
#pragma unroll
            for (int j = 0; j < 16; ++j) {
                const float x = md[j * 256 + tid + s];
                if (x >= d15) break;
                KNN_DINS(x);
            }
        }
        thr[q + (b << 11)] = d15;    // 16th-smallest distance for query q of batch b
    }
}

__global__ __launch_bounds__(256) void knn_collect(const float* __restrict__ pts, const float* __restrict__ thr,
                                                   int* __restrict__ idxout)
{
    __shared__ float4 P[2048];
    __shared__ int   cnt[32];
    __shared__ float tq[32];
    const int tid = threadIdx.x;
    const int b = blockIdx.x;
    const float* pb = pts + (size_t)b * 6 * 2048;
    for (int i = tid; i < 2048; i += 256) {
        float x = pb[i];
        float y = pb[2048 + i];
        float z = pb[4096 + i];
        P[i] = make_float4(x, y, z, x * x + y * y + z * z);
    }
    if (tid < 32) {
        cnt[tid] = 0;
        tq[tid] = thr[(b << 11) + blockIdx.y * 32 + tid];
    }
    __syncthreads();

    const int p = tid & 7;
    const int g = tid >> 3;
    const int q = blockIdx.y * 32 + g;
    const float4 pq = P[q];
    const float t = tq[g];
    int* op = idxout + (((size_t)(b << 11) + q) << 4);

    float4 nxt = P[p];
    for (int it = 0; it < 256; ++it) {
        const float4 pm = nxt;
        const int m = it * 8 + p;
        nxt = P[(m + 8) & 2047];
        const float d = knn_dist(pq, pm);
        if (d <= t) {
            const int pos = atomicAdd(&cnt[g], 1);
            if (pos < 16) op[pos] = m;   // order-scrambled: consumer is a max over the set
        }
    }
}

// ---------------- GEMM v2 (m97-style): 128m x 128o tile, BK=64, global_load_lds staging ----------------
// 256 threads = 4 waves in 2x2: wave: o-half = (wave>>1)*64, m-half = (wave&1)*64.
// Per wave 4x4 frags of 16x16x32 f16 MFMA. LDS tiles row-major [row][64k] with
// XOR k-slot swizzle (slot ^= row&7) for conflict-free ds_read_b128.
// Requires: Kp % 64 == 0, Opad % 128 == 0. Stores f16 to Y (or f32 to Y32), cols < Olimit.
__global__ __launch_bounds__(256) void gemm_tile(
    const _Float16* __restrict__ W, const _Float16* __restrict__ X,
    _Float16* __restrict__ Y, float* __restrict__ Y32,
    const float* __restrict__ bias, const _Float16* __restrict__ Res,
    int Kp, int ldX, int xoff, int ldY, int yoff, int Opad,
    int act, int biasPerBatch, int ldR, int roff, int Olimit)
{
    __shared__ _Float16 As[128 * 64];
    __shared__ _Float16 Bs[128 * 64];
    const int tid  = threadIdx.x;
    const int lane = tid & 63, wave = tid >> 6;
    const int r = lane & 15, quad = lane >> 4;
    const int m_blk = blockIdx.x * 128, o_blk = blockIdx.y * 128;
    const int oh = (wave >> 1) * 64, mh = (wave & 1) * 64;

    f32x4 acc[4][4];
#pragma unroll
    for (int a = 0; a < 4; ++a)
#pragma unroll
        for (int c = 0; c < 4; ++c) acc[a][c] = (f32x4){0.f, 0.f, 0.f, 0.f};

    const int srow  = wave * 8 + (lane >> 3);   // + t*32 per chunk
    const int sslot = lane & 7;

    for (int k0 = 0; k0 < Kp; k0 += 64) {
        __syncthreads();
#pragma unroll
        for (int t = 0; t < 4; ++t) {
            const int rowA = t * 32 + srow;
            const int gk = k0 + (((sslot ^ (rowA & 7))) << 3);
            const _Float16* gA = W + (size_t)(o_blk + rowA) * Kp + gk;
            const _Float16* gB = X + (size_t)(m_blk + rowA) * ldX + xoff + gk;
            __builtin_amdgcn_global_load_lds(
                (const __attribute__((address_space(1))) unsigned int*)gA,
                (__attribute__((address_space(3))) unsigned int*)(As + t * 2048 + wave * 512),
                16, 0, 0);
            __builtin_amdgcn_global_load_lds(
                (const __attribute__((address_space(1))) unsigned int*)gB,
                (__attribute__((address_space(3))) unsigned int*)(Bs + t * 2048 + wave * 512),
                16, 0, 0);
        }
        __syncthreads();
#pragma unroll
        for (int ks = 0; ks < 2; ++ks) {
            f16x8 af[4], bf[4];
#pragma unroll
            for (int oi = 0; oi < 4; ++oi) {
                const int row = oh + oi * 16 + r;
                const int slot = (ks * 4 + quad) ^ (row & 7);
                af[oi] = *(const f16x8*)(As + row * 64 + slot * 8);
            }
#pragma unroll
            for (int mi = 0; mi < 4; ++mi) {
                const int row = mh + mi * 16 + r;
                const int slot = (ks * 4 + quad) ^ (row & 7);
                bf[mi] = *(const f16x8*)(Bs + row * 64 + slot * 8);
            }
#pragma unroll
            for (int oi = 0; oi < 4; ++oi)
#pragma unroll
                for (int mi = 0; mi < 4; ++mi)
                    acc[oi][mi] = __builtin_amdgcn_mfma_f32_16x16x32_f16(af[oi], bf[mi], acc[oi][mi], 0, 0, 0);
        }
    }

    const int bb = biasPerBatch ? (m_blk >> 11) * Opad : 0;
#pragma unroll
    for (int oi = 0; oi < 4; ++oi) {
        const int og = o_blk + oh + oi * 16 + quad * 4;   // first of 4 output cols
        if (og >= Olimit) continue;
        const f32x4 bv = *(const f32x4*)(bias + bb + og);
#pragma unroll
        for (int mi = 0; mi < 4; ++mi) {
            const int m = m_blk + mh + mi * 16 + r;
            f32x4 v = acc[oi][mi] + bv;
            if (Res) {
                f16x4 rr = *(const f16x4*)(Res + (size_t)m * ldR + roff + og);
#pragma unroll
                for (int j = 0; j < 4; ++j) v[j] += (float)rr[j];
            }
#pragma unroll
            for (int j = 0; j < 4; ++j) {
                float x = v[j];
                if (act == 1)      x = (x > 0.f) ? x : 0.0f;
                else if (act == 2) x = (x > 0.f) ? x : 0.2f * x;
                v[j] = x;
            }
            if (Y32) {
                *(f32x4*)(Y32 + (size_t)m * ldY + yoff + og) = v;
            } else {
                f16x4 ov;
#pragma unroll
                for (int j = 0; j < 4; ++j) ov[j] = (_Float16)v[j];
                *(f16x4*)(Y + (size_t)m * ldY + yoff + og) = ov;
            }
        }
    }
}

// ---------------- neighbor gather + channel max (relu outputs => ushort-monotonic f16 bits) ----------------
typedef short s16x8 __attribute__((ext_vector_type(8)));
__global__ __launch_bounds__(256) void gather_max_kernel(
    const short* __restrict__ T, const int* __restrict__ idx, short* __restrict__ Mo)
{
    const int tid = threadIdx.x;
    const int p = blockIdx.x * 16 + (tid >> 4);
    const int l = tid & 15;
    const int b = p >> 11;
    const int* ip = idx + (size_t)p * 16;
    size_t row = (size_t)((b << 11) + ip[0]);
    s16x8 cur = *(const s16x8*)(T + row * 128 + l * 8);
    unsigned short best[8];
#pragma unroll
    for (int e = 0; e < 8; ++e) best[e] = (unsigned short)cur[e];
#pragma unroll
    for (int j = 1; j < 16; ++j) {
        row = (size_t)((b << 11) + ip[j]);
        s16x8 v = *(const s16x8*)(T + row * 128 + l * 8);
#pragma unroll
        for (int e = 0; e < 8; ++e) {
            unsigned short u = (unsigned short)v[e];
            if (u > best[e]) best[e] = u;
        }
    }
    s16x8 ov;
#pragma unroll
    for (int e = 0; e < 8; ++e) ov[e] = (short)best[e];
    *(s16x8*)(Mo + (size_t)p * 128 + l * 8) = ov;
}

// ---------------- pooling reductions over n ----------------
__global__ __launch_bounds__(256) void reduce1_kernel(const _Float16* __restrict__ xf, float* __restrict__ pmax, float* __restrict__ psum)
{
    const int b = blockIdx.x, oc = blockIdx.y, ch = blockIdx.z, tid = threadIdx.x;
    const int o = oc * 256 + tid;
    const _Float16* p = xf + ((size_t)(b << 11) + ch * 256) * 1024 + o;
    float mx = -3.4e38f, sm = 0.f;
    for (int n = 0; n < 256; ++n) {
        float v = (float)p[(size_t)n * 1024];
        mx = fmaxf(mx, v); sm += v;
    }
    pmax[((size_t)(b * 8 + ch) << 10) + o] = mx;
    psum[((size_t)(b * 8 + ch) << 10) + o] = sm;
}

__global__ __launch_bounds__(256) void reduce2_kernel(const float* __restrict__ pmax, const float* __restrict__ psum,
                                                      float* __restrict__ xmax, float* __restrict__ xavg)
{
    const int b = blockIdx.x, oc = blockIdx.y, tid = threadIdx.x;
    const int o = oc * 256 + tid;
    float mx = -3.4e38f, sm = 0.f;
#pragma unroll
    for (int c = 0; c < 8; ++c) {
        mx = fmaxf(mx, pmax[((size_t)(b * 8 + c) << 10) + o]);
        sm += psum[((size_t)(b * 8 + c) << 10) + o];
    }
    xmax[((size_t)b << 10) + o] = mx;
    xavg[((size_t)b << 10) + o] = sm * (1.f / 2048.f);
}

// ---------------- per-batch constant vector for Wc1 (broadcast cols 1024..3135 + bias/bn) ----------------
__global__ __launch_bounds__(256) void cvec_kernel(
    const float* __restrict__ label, const float* __restrict__ Wl, const float* __restrict__ gl, const float* __restrict__ bl,
    const float* __restrict__ Wc1, const float* __restrict__ bc1, const float* __restrict__ gc1, const float* __restrict__ bb1,
    const float* __restrict__ xmax, const float* __restrict__ xavg, float* __restrict__ cvec)
{
    __shared__ float v[2112];
    __shared__ float red[256];
    const int b = blockIdx.x, og = blockIdx.y, tid = threadIdx.x;
    for (int i = tid; i < 1024; i += 256) v[i] = xmax[((size_t)b << 10) + i];
    for (int i = tid; i < 1024; i += 256) v[1024 + i] = xavg[((size_t)b << 10) + i];
    if (tid < 64) {
        float s = 0.f;
        for (int i = 0; i < 16; ++i) s += Wl[tid * 16 + i] * label[b * 16 + i];
        s = gl[tid] * s + bl[tid];
        v[2048 + tid] = (s > 0.f) ? s : 0.2f * s;
    }
    __syncthreads();
    const int o = og * 64 + (tid >> 2), part = tid & 3;
    const float* wrow = Wc1 + (size_t)o * 3136 + 1024 + part * 528;
    float s = 0.f;
    for (int j = 0; j < 528; ++j) s += wrow[j] * v[part * 528 + j];
    red[tid] = s;
    __syncthreads();
    if (part == 0) {
        float tot = red[tid] + red[tid + 1] + red[tid + 2] + red[tid + 3];
        cvec[((size_t)b << 9) + o] = gc1[o] * (tot + bc1[o]) + bb1[o];
    }
}

// ---------------- final layout (M x 64 f32) -> (B,50,N) f32 ----------------
__global__ __launch_bounds__(256) void reformat_kernel(const float* __restrict__ c3, float* __restrict__ out)
{
    int i = blockIdx.x * 256 + threadIdx.x;       // 16*50*2048 total
    int n = i & 2047;
    int t = i >> 11;        // b*50 + o
    int o = t % 50;
    int b = t / 50;
    out[i] = c3[((size_t)((b << 11) + n)) * 64 + o];
}

// ---------------- launch ----------------
extern "C" void kernel_launch(void* const* d_in, const int* in_sizes, int n_in,
                              void* d_out, int out_size, void* d_ws, size_t ws_size,
                              hipStream_t stream)
{
    (void)in_sizes; (void)n_in; (void)out_size; (void)ws_size;
    const float* points = (const float*)d_in[0];
    const float* label  = (const float*)d_in[1];
    const float* We1 = (const float*)d_in[2];
    const float* ge1 = (const float*)d_in[3];
    const float* be1 = (const float*)d_in[4];
    const float* We2 = (const float*)d_in[5];
    const float* ge2 = (const float*)d_in[6];
    const float* be2 = (const float*)d_in[7];
    const float* W1  = (const float*)d_in[8];
    const float* g1  = (const float*)d_in[9];
    const float* b1  = (const float*)d_in[10];
    const float* W2  = (const float*)d_in[11];
    const float* g2  = (const float*)d_in[12];
    const float* b2  = (const float*)d_in[13];
    const float* Wf  = (const float*)d_in[14];
    const float* gf  = (const float*)d_in[15];
    const float* bfv = (const float*)d_in[16];
    const float* Wl  = (const float*)d_in[17];
    const float* gl  = (const float*)d_in[18];
    const float* bl  = (const float*)d_in[19];
    const float* Wc1 = (const float*)d_in[20];
    const float* bc1 = (const float*)d_in[21];
    const float* gc1 = (const float*)d_in[22];
    const float* bb1 = (const float*)d_in[23];
    const float* Wc2 = (const float*)d_in[24];
    const float* bc2 = (const float*)d_in[25];
    const float* gc2 = (const float*)d_in[26];
    const float* bb2 = (const float*)d_in[27];
    const float* Wc3 = (const float*)d_in[28];
    const float* bc3 = (const float*)d_in[29];

    char* ws = (char*)d_ws;
    _Float16* x0  = (_Float16*)(ws + OFF_X0);
    _Float16* hT  = (_Float16*)(ws + OFF_HT);
    _Float16* tT  = (_Float16*)(ws + OFF_TT);
    _Float16* mT  = (_Float16*)(ws + OFF_MT);
    _Float16* xct = (_Float16*)(ws + OFF_XCAT);
    _Float16* xf  = (_Float16*)(ws + OFF_XF);
    _Float16* c1  = (_Float16*)(ws + OFF_C1);
    _Float16* c2  = (_Float16*)(ws + OFF_C2);
    float*    c3  = (float*)   (ws + OFF_C3);
    int*      idx = (int*)     (ws + OFF_IDX);
    float*    thr = (float*)   (ws + OFF_THR);

    _Float16* wE1 = (_Float16*)(ws + OFF_WE1);
    _Float16* wE2 = (_Float16*)(ws + OFF_WE2);
    _Float16* w1f = (_Float16*)(ws + OFF_W1);
    _Float16* w2f = (_Float16*)(ws + OFF_W2);
    _Float16* wF  = (_Float16*)(ws + OFF_WF);
    _Float16* wC1 = (_Float16*)(ws + OFF_WC1);
    _Float16* wC2 = (_Float16*)(ws + OFF_WC2);
    _Float16* wC3 = (_Float16*)(ws + OFF_WC3);
    float* bC2 = (float*)(ws + OFF_BC2);
    float* bC3 = (float*)(ws + OFF_BC3);
    float* cv  = (float*)(ws + OFF_CVEC);
    float* xmx = (float*)(ws + OFF_XMAX);
    float* xav = (float*)(ws + OFF_XAVG);
    float* pmx = (float*)(ws + OFF_PMAX);
    float* psm = (float*)(ws + OFF_PSUM);

    // prep
    fold_w_kernel<<<dim3(2048, 12), 256, 0, stream>>>(We1, ge1, We2, ge2, W1, g1, W2, g2, Wf, gf, Wc1, gc1, Wc2, gc2, Wc3, ws);
    fold_bias_kernel<<<dim3(2), 256, 0, stream>>>(gc2, bc2, bb2, bc3, ws);
    x0prep_kernel<<<dim3(MM / 256), 256, 0, stream>>>(points, x0);
    knn_select <<<dim3(BB, NN / 32), 256, 0, stream>>>(points, thr);
    knn_collect<<<dim3(BB, NN / 32), 256, 0, stream>>>(points, thr, idx);

    // e1: x0(Mx64,pad) -> tT(Mx128), relu
    gemm_tile<<<dim3(256, 1), 256, 0, stream>>>(wE1, x0, tT, nullptr, be1, nullptr, 64, 64, 0, 128, 0, 128, 1, 0, 0, 0, 128);
    // e2: tT -> hT, relu
    gemm_tile<<<dim3(256, 1), 256, 0, stream>>>(wE2, tT, hT, nullptr, be2, nullptr, 128, 128, 0, 128, 0, 128, 1, 0, 0, 0, 128);

    for (int i = 0; i < 3; ++i) {
        const _Float16* hin = (i == 0) ? hT : xct;
        int ldH  = (i == 0) ? 128 : 384;
        int offH = (i == 0) ? 0 : (i - 1) * 128;
        // t = relu(bn(W1 h))
        gemm_tile<<<dim3(256, 1), 256, 0, stream>>>(w1f + (size_t)i * 16384, hin, tT, nullptr, b1 + i * 128, nullptr,
                                                    128, ldH, offH, 128, 0, 128, 1, 0, 0, 0, 128);
        // m = neighbor max
        gather_max_kernel<<<dim3(MM / 16), 256, 0, stream>>>((const short*)tT, idx, (short*)mT);
        // h' = relu(bn(W2 m) + h) -> xcat slice i
        gemm_tile<<<dim3(256, 1), 256, 0, stream>>>(w2f + (size_t)i * 16384, mT, xct, nullptr, b2 + i * 128, hin,
                                                    128, 128, 0, 384, i * 128, 128, 1, 0, ldH, offH, 128);
    }

    // xf = leaky(bn(Wf xcat))
    gemm_tile<<<dim3(256, 8), 256, 0, stream>>>(wF, xct, xf, nullptr, bfv, nullptr, 384, 384, 0, 1024, 0, 1024, 2, 0, 0, 0, 1024);

    // pooling + per-batch classifier constant
    reduce1_kernel<<<dim3(BB, 4, 8), 256, 0, stream>>>(xf, pmx, psm);
    reduce2_kernel<<<dim3(BB, 4), 256, 0, stream>>>(pmx, psm, xmx, xav);
    cvec_kernel<<<dim3(BB, 8), 256, 0, stream>>>(label, Wl, gl, bl, Wc1, bc1, gc1, bb1, xmx, xav, cv);

    // c1 = relu(gc1*Wc1[:, :1024] xf + cvec[b])
    gemm_tile<<<dim3(256, 4), 256, 0, stream>>>(wC1, xf, c1, nullptr, cv, nullptr, 1024, 1024, 0, 512, 0, 512, 1, 1, 0, 0, 512);
    // c2 = relu(bn(Wc2 c1 + bc2))
    gemm_tile<<<dim3(256, 2), 256, 0, stream>>>(wC2, c1, c2, nullptr, bC2, nullptr, 512, 512, 0, 256, 0, 256, 1, 0, 0, 0, 256);
    // c3 = Wc3 c2 + bc3 (no act), f32 out, only cols < 64 stored
    gemm_tile<<<dim3(256, 1), 256, 0, stream>>>(wC3, c2, nullptr, c3, bC3, nullptr, 256, 256, 0, 64, 0, 128, 0, 0, 0, 0, 64);

    // (M x 64) -> (B,50,N)
    reformat_kernel<<<dim3(BB * 50 * NN / 256), 256, 0, stream>>>(c3, (float*)d_out);
}

// Round 7
// 499.756 us; speedup vs baseline: 3.4729x; 1.1025x over previous
//
#include <hip/hip_runtime.h>
#include <cstdint>
#include <cstddef>

#define DEVINL __device__ __forceinline__

typedef float    f32x4 __attribute__((ext_vector_type(4)));
typedef _Float16 f16x8 __attribute__((ext_vector_type(8)));
typedef _Float16 f16x4 __attribute__((ext_vector_type(4)));

// ---------------- constants ----------------
constexpr int BB = 16, NN = 2048, MM = 32768;

// ---------------- ws layout (bytes) ----------------
constexpr size_t OFF_WE1 = 0;                           // 128x64 f16 (Kp padded 6->64)
constexpr size_t OFF_WE2 = OFF_WE1 + 128 * 64 * 2;
constexpr size_t OFF_W1  = OFF_WE2 + 128 * 128 * 2;
constexpr size_t OFF_W2  = OFF_W1  + 3 * 128 * 128 * 2;
constexpr size_t OFF_WF  = OFF_W2  + 3 * 128 * 128 * 2;
constexpr size_t OFF_WC1 = OFF_WF  + 1024 * 384 * 2;
constexpr size_t OFF_WC2 = OFF_WC1 + 512 * 1024 * 2;
constexpr size_t OFF_WC3 = OFF_WC2 + 256 * 512 * 2;     // 128x256 (Opad 50->128)
constexpr size_t OFF_BC2 = OFF_WC3 + 128 * 256 * 2;     // 256 f32
constexpr size_t OFF_BC3 = OFF_BC2 + 256 * 4;           // 128 f32
constexpr size_t OFF_CVEC= OFF_BC3 + 128 * 4;           // 16x512 f32
constexpr size_t OFF_XMAX= OFF_CVEC+ 16 * 512 * 4;
constexpr size_t OFF_XAVG= OFF_XMAX+ 16 * 1024 * 4;
constexpr size_t OFF_PMAX= OFF_XAVG+ 16 * 1024 * 4;
constexpr size_t OFF_PSUM= OFF_PMAX+ 16 * 8 * 1024 * 4;
constexpr size_t OFF_IDX = OFF_PSUM+ 16 * 8 * 1024 * 4;
constexpr size_t OFF_THR = OFF_PMAX;                    // 32768 f32 (dead before pmax is written)
constexpr size_t OFF_R1  = 6ull << 20;                  // > OFF_IDX + 2MB
constexpr size_t OFF_X0  = OFF_R1;                      // 4MB  (M x 64 f16, k-padded)
constexpr size_t OFF_HT  = OFF_R1 + (4ull  << 20);      // 8MB  (M x 128 f16)
constexpr size_t OFF_TT  = OFF_R1 + (12ull << 20);      // 8MB
constexpr size_t OFF_MT  = OFF_R1 + (20ull << 20);      // 8MB
constexpr size_t OFF_C1  = OFF_R1;                      // 32MB (M x 512 f16), aliases x0/h/t/m (dead)
constexpr size_t OFF_XCAT= OFF_R1 + (32ull << 20);      // 24MB (M x 384 f16)
constexpr size_t OFF_C2  = OFF_XCAT;                    // 16MB (M x 256 f16), aliases xcat (dead)
constexpr size_t OFF_XF  = OFF_XCAT + (24ull << 20);    // 64MB (M x 1024 f16)
constexpr size_t OFF_C3  = OFF_XF;                      // 8MB  (M x 64 f32), aliases xf (dead)

// ---------------- weight folding: dst[o*Kp+k] = f16( W[o,k] * g[o] ), zero-padded ----------------
// compact 1D grid: exact block counts per segment (all segments are multiples of 256 elements)
__global__ __launch_bounds__(256) void fold_w_kernel(
    const float* We1, const float* ge1, const float* We2, const float* ge2,
    const float* W1,  const float* g1,  const float* W2,  const float* g2,
    const float* Wf,  const float* gf,  const float* Wc1, const float* gc1,
    const float* Wc2, const float* gc2, const float* Wc3, char* ws)
{
    const int bid = blockIdx.x;
    int id, base;
    if      (bid < 32)   { id = 0;  base = 0;    }
    else if (bid < 96)   { id = 1;  base = 32;   }
    else if (bid < 160)  { id = 2;  base = 96;   }
    else if (bid < 224)  { id = 3;  base = 160;  }
    else if (bid < 288)  { id = 4;  base = 224;  }
    else if (bid < 352)  { id = 5;  base = 288;  }
    else if (bid < 416)  { id = 6;  base = 352;  }
    else if (bid < 480)  { id = 7;  base = 416;  }
    else if (bid < 2016) { id = 8;  base = 480;  }
    else if (bid < 4064) { id = 9;  base = 2016; }
    else if (bid < 4576) { id = 10; base = 4064; }
    else                 { id = 11; base = 4576; }

    const float* src = nullptr; const float* g = nullptr; _Float16* dst = nullptr;
    int O = 0, K = 0, lds = 0, Kp = 0, Opad = 0;
    switch (id) {
        case 0:  src = We1; g = ge1; O = 128; K = 6;    lds = 6;    Kp = 64;   Opad = 128; dst = (_Float16*)(ws + OFF_WE1); break;
        case 1:  src = We2; g = ge2; O = 128; K = 128;  lds = 128;  Kp = 128;  Opad = 128; dst = (_Float16*)(ws + OFF_WE2); break;
        case 2: case 3: case 4: {
            int i = id - 2;
            src = W1 + (size_t)i * 16384; g = g1 + i * 128; O = 128; K = 128; lds = 128; Kp = 128; Opad = 128;
            dst = (_Float16*)(ws + OFF_W1) + (size_t)i * 16384; break; }
        case 5: case 6: case 7: {
            int i = id - 5;
            src = W2 + (size_t)i * 16384; g = g2 + i * 128; O = 128; K = 128; lds = 128; Kp = 128; Opad = 128;
            dst = (_Float16*)(ws + OFF_W2) + (size_t)i * 16384; break; }
        case 8:  src = Wf;  g = gf;  O = 1024; K = 384;  lds = 384;  Kp = 384;  Opad = 1024; dst = (_Float16*)(ws + OFF_WF);  break;
        case 9:  src = Wc1; g = gc1; O = 512;  K = 1024; lds = 3136; Kp = 1024; Opad = 512;  dst = (_Float16*)(ws + OFF_WC1); break;
        case 10: src = Wc2; g = gc2; O = 256;  K = 512;  lds = 512;  Kp = 512;  Opad = 256;  dst = (_Float16*)(ws + OFF_WC2); break;
        default: src = Wc3; g = nullptr; O = 50; K = 256; lds = 256; Kp = 256;  Opad = 128;  dst = (_Float16*)(ws + OFF_WC3); break;
    }
    int e = (bid - base) * 256 + threadIdx.x;
    if (e >= Opad * Kp) return;
    int o = e / Kp, k = e - o * Kp;
    float v = 0.f;
    if (o < O && k < K) {
        v = src[(size_t)o * lds + k];
        if (g) v *= g[o];
    }
    dst[e] = (_Float16)v;
}

// ---------------- bias folding ----------------
__global__ __launch_bounds__(256) void fold_bias_kernel(
    const float* gc2, const float* bc2, const float* bb2, const float* bc3, char* ws)
{
    const int id = blockIdx.x, tid = threadIdx.x;
    if (id == 0) {
        ((float*)(ws + OFF_BC2))[tid] = gc2[tid] * bc2[tid] + bb2[tid];
    } else if (tid < 128) {
        ((float*)(ws + OFF_BC3))[tid] = (tid < 50) ? bc3[tid] : 0.f;
    }
}

// ---------------- x0 prep: (B,6,N) f32 -> (M x 64) f16 K-contig, zero pad ----------------
__global__ __launch_bounds__(256) void x0prep_kernel(const float* __restrict__ pts, _Float16* __restrict__ x0)
{
    int m = blockIdx.x * 256 + threadIdx.x;
    int b = m >> 11, n = m & 2047;
    const float* ps = pts + (size_t)b * 6 * 2048 + n;
    _Float16 tmp[64];
#pragma unroll
    for (int c = 0; c < 64; ++c) tmp[c] = (_Float16)0.f;
#pragma unroll
    for (int c = 0; c < 6; ++c) tmp[c] = (_Float16)ps[(size_t)c << 11];
    _Float16* dst = x0 + (size_t)m * 64;
#pragma unroll
    for (int v = 0; v < 8; ++v) *(f16x8*)(dst + v * 8) = *(const f16x8*)(tmp + v * 8);
}

// ---------------- KNN v6: two-pass threshold selection, med3 insert network ----------------
// d' = pm.w - 2*q.p  (pq.w dropped: order-preserving per query; both passes share
// this exact expression so threshold comparisons stay bit-consistent).
// Insert of x into ascending d0..d15 is ONE v_med3_f32 per slot:
//   dJ' = median(x, d_{J-1}, dJ)  (valid since d_{J-1} <= dJ),  d0' = median(x, -BIG, d0).

DEVINL float knn_dist(const float4 pq, const float4 pm) {
    float t = pq.x * pm.x;
    t = fmaf(pq.y, pm.y, t);
    t = fmaf(pq.z, pm.z, t);
    return fmaf(-2.f, t, pm.w);
}

#define KNN_DINS(X) do { \
    const float x_ = (X); \
    d15 = __builtin_amdgcn_fmed3f(x_, d14, d15); \
    d14 = __builtin_amdgcn_fmed3f(x_, d13, d14); \
    d13 = __builtin_amdgcn_fmed3f(x_, d12, d13); \
    d12 = __builtin_amdgcn_fmed3f(x_, d11, d12); \
    d11 = __builtin_amdgcn_fmed3f(x_, d10, d11); \
    d10 = __builtin_amdgcn_fmed3f(x_, d9,  d10); \
    d9  = __builtin_amdgcn_fmed3f(x_, d8,  d9);  \
    d8  = __builtin_amdgcn_fmed3f(x_, d7,  d8);  \
    d7  = __builtin_amdgcn_fmed3f(x_, d6,  d7);  \
    d6  = __builtin_amdgcn_fmed3f(x_, d5,  d6);  \
    d5  = __builtin_amdgcn_fmed3f(x_, d4,  d5);  \
    d4  = __builtin_amdgcn_fmed3f(x_, d3,  d4);  \
    d3  = __builtin_amdgcn_fmed3f(x_, d2,  d3);  \
    d2  = __builtin_amdgcn_fmed3f(x_, d1,  d2);  \
    d1  = __builtin_amdgcn_fmed3f(x_, d0,  d1);  \
    d0  = __builtin_amdgcn_fmed3f(x_, -3.4e38f, d0); \
} while (0)

__global__ __launch_bounds__(256) void knn_select(const float* __restrict__ pts, float* __restrict__ thr)
{
    __shared__ float4 P[2048];
    const int tid = threadIdx.x;
    const int b = blockIdx.x;
    const float* pb = pts + (size_t)b * 6 * 2048;
    for (int i = tid; i < 2048; i += 256) {
        float x = pb[i];
        float y = pb[2048 + i];
        float z = pb[4096 + i];
        P[i] = make_float4(x, y, z, x * x + y * y + z * z);
    }
    __syncthreads();

    const int p = tid & 7;          // candidate partition (m == 8*it + p)
    const int g = tid >> 3;         // query within block (0..31)
    const int q = blockIdx.y * 32 + g;
    const float4 pq = P[q];

    float d0 = 3.4e38f, d1 = 3.4e38f, d2 = 3.4e38f, d3 = 3.4e38f,
          d4 = 3.4e38f, d5 = 3.4e38f, d6 = 3.4e38f, d7 = 3.4e38f,
          d8 = 3.4e38f, d9 = 3.4e38f, d10 = 3.4e38f, d11 = 3.4e38f,
          d12 = 3.4e38f, d13 = 3.4e38f, d14 = 3.4e38f, d15 = 3.4e38f;

    float4 nxt = P[p];
#pragma unroll 2
    for (int it = 0; it < 256; ++it) {
        const float4 pm = nxt;
        const int m = it * 8 + p;
        nxt = P[(m + 8) & 2047];    // prefetch next candidate (wraps harmlessly on last)
        KNN_DINS(knn_dist(pq, pm));
    }

    __syncthreads();                 // everyone done reading P; reuse its LDS
    float* md = (float*)P;           // md[j*256 + tid]
#define KNN_SPILL(J) md[J * 256 + tid] = d##J;
    KNN_SPILL(0)  KNN_SPILL(1)  KNN_SPILL(2)  KNN_SPILL(3)
    KNN_SPILL(4)  KNN_SPILL(5)  KNN_SPILL(6)  KNN_SPILL(7)
    KNN_SPILL(8)  KNN_SPILL(9)  KNN_SPILL(10) KNN_SPILL(11)
    KNN_SPILL(12) KNN_SPILL(13) KNN_SPILL(14) KNN_SPILL(15)
#undef KNN_SPILL
    __syncthreads();

    if (p == 0) {
        // merge the 7 other sorted (ascending) lists; early exit per list
        for (int s = 1; s < 8; ++s) {
#pragma unroll
            for (int j = 0; j < 16; ++j) {
                const float x = md[j * 256 + tid + s];
                if (x >= d15) break;
                KNN_DINS(x);
            }
        }
        thr[q + (b << 11)] = d15;    // 16th-smallest (primed) distance for query q of batch b
    }
}

__global__ __launch_bounds__(256) void knn_collect(const float* __restrict__ pts, const float* __restrict__ thr,
                                                   int* __restrict__ idxout)
{
    __shared__ float4 P[2048];
    __shared__ int   cnt[32];
    __shared__ float tq[32];
    const int tid = threadIdx.x;
    const int b = blockIdx.x;
    const float* pb = pts + (size_t)b * 6 * 2048;
    for (int i = tid; i < 2048; i += 256) {
        float x = pb[i];
        float y = pb[2048 + i];
        float z = pb[4096 + i];
        P[i] = make_float4(x, y, z, x * x + y * y + z * z);
    }
    if (tid < 32) {
        cnt[tid] = 0;
        tq[tid] = thr[(b << 11) + blockIdx.y * 32 + tid];
    }
    __syncthreads();

    const int p = tid & 7;
    const int g = tid >> 3;
    const int q = blockIdx.y * 32 + g;
    const float4 pq = P[q];
    const float t = tq[g];
    int* op = idxout + (((size_t)(b << 11) + q) << 4);

    float4 nxt = P[p];
    for (int it = 0; it < 256; ++it) {
        const float4 pm = nxt;
        const int m = it * 8 + p;
        nxt = P[(m + 8) & 2047];
        const float d = knn_dist(pq, pm);
        if (d <= t) {
            const int pos = atomicAdd(&cnt[g], 1);
            if (pos < 16) op[pos] = m;   // order-scrambled: consumer is a max over the set
        }
    }
}

// ---------------- GEMM v2 (m97-style): 128m x 128o tile, BK=64, global_load_lds staging ----------------
__global__ __launch_bounds__(256) void gemm_tile(
    const _Float16* __restrict__ W, const _Float16* __restrict__ X,
    _Float16* __restrict__ Y, float* __restrict__ Y32,
    const float* __restrict__ bias, const _Float16* __restrict__ Res,
    int Kp, int ldX, int xoff, int ldY, int yoff, int Opad,
    int act, int biasPerBatch, int ldR, int roff, int Olimit)
{
    __shared__ _Float16 As[128 * 64];
    __shared__ _Float16 Bs[128 * 64];
    const int tid  = threadIdx.x;
    const int lane = tid & 63, wave = tid >> 6;
    const int r = lane & 15, quad = lane >> 4;
    const int m_blk = blockIdx.x * 128, o_blk = blockIdx.y * 128;
    const int oh = (wave >> 1) * 64, mh = (wave & 1) * 64;

    f32x4 acc[4][4];
#pragma unroll
    for (int a = 0; a < 4; ++a)
#pragma unroll
        for (int c = 0; c < 4; ++c) acc[a][c] = (f32x4){0.f, 0.f, 0.f, 0.f};

    const int srow  = wave * 8 + (lane >> 3);   // + t*32 per chunk
    const int sslot = lane & 7;

    for (int k0 = 0; k0 < Kp; k0 += 64) {
        __syncthreads();
#pragma unroll
        for (int t = 0; t < 4; ++t) {
            const int rowA = t * 32 + srow;
            const int gk = k0 + (((sslot ^ (rowA & 7))) << 3);
            const _Float16* gA = W + (size_t)(o_blk + rowA) * Kp + gk;
            const _Float16* gB = X + (size_t)(m_blk + rowA) * ldX + xoff + gk;
            __builtin_amdgcn_global_load_lds(
                (const __attribute__((address_space(1))) unsigned int*)gA,
                (__attribute__((address_space(3))) unsigned int*)(As + t * 2048 + wave * 512),
                16, 0, 0);
            __builtin_amdgcn_global_load_lds(
                (const __attribute__((address_space(1))) unsigned int*)gB,
                (__attribute__((address_space(3))) unsigned int*)(Bs + t * 2048 + wave * 512),
                16, 0, 0);
        }
        __syncthreads();
#pragma unroll
        for (int ks = 0; ks < 2; ++ks) {
            f16x8 af[4], bf[4];
#pragma unroll
            for (int oi = 0; oi < 4; ++oi) {
                const int row = oh + oi * 16 + r;
                const int slot = (ks * 4 + quad) ^ (row & 7);
                af[oi] = *(const f16x8*)(As + row * 64 + slot * 8);
            }
#pragma unroll
            for (int mi = 0; mi < 4; ++mi) {
                const int row = mh + mi * 16 + r;
                const int slot = (ks * 4 + quad) ^ (row & 7);
                bf[mi] = *(const f16x8*)(Bs + row * 64 + slot * 8);
            }
#pragma unroll
            for (int oi = 0; oi < 4; ++oi)
#pragma unroll
                for (int mi = 0; mi < 4; ++mi)
                    acc[oi][mi] = __builtin_amdgcn_mfma_f32_16x16x32_f16(af[oi], bf[mi], acc[oi][mi], 0, 0, 0);
        }
    }

    const int bb = biasPerBatch ? (m_blk >> 11) * Opad : 0;
#pragma unroll
    for (int oi = 0; oi < 4; ++oi) {
        const int og = o_blk + oh + oi * 16 + quad * 4;   // first of 4 output cols
        if (og >= Olimit) continue;
        const f32x4 bv = *(const f32x4*)(bias + bb + og);
#pragma unroll
        for (int mi = 0; mi < 4; ++mi) {
            const int m = m_blk + mh + mi * 16 + r;
            f32x4 v = acc[oi][mi] + bv;
            if (Res) {
                f16x4 rr = *(const f16x4*)(Res + (size_t)m * ldR + roff + og);
#pragma unroll
                for (int j = 0; j < 4; ++j) v[j] += (float)rr[j];
            }
#pragma unroll
            for (int j = 0; j < 4; ++j) {
                float x = v[j];
                if (act == 1)      x = (x > 0.f) ? x : 0.0f;
                else if (act == 2) x = (x > 0.f) ? x : 0.2f * x;
                v[j] = x;
            }
            if (Y32) {
                *(f32x4*)(Y32 + (size_t)m * ldY + yoff + og) = v;
            } else {
                f16x4 ov;
#pragma unroll
                for (int j = 0; j < 4; ++j) ov[j] = (_Float16)v[j];
                *(f16x4*)(Y + (size_t)m * ldY + yoff + og) = ov;
            }
        }
    }
}

// ---------------- neighbor gather + channel max (relu outputs => ushort-monotonic f16 bits) ----------------
typedef short s16x8 __attribute__((ext_vector_type(8)));
__global__ __launch_bounds__(256) void gather_max_kernel(
    const short* __restrict__ T, const int* __restrict__ idx, short* __restrict__ Mo)
{
    const int tid = threadIdx.x;
    const int p = blockIdx.x * 16 + (tid >> 4);
    const int l = tid & 15;
    const int b = p >> 11;
    const int* ip = idx + (size_t)p * 16;
    size_t row = (size_t)((b << 11) + ip[0]);
    s16x8 cur = *(const s16x8*)(T + row * 128 + l * 8);
    unsigned short best[8];
#pragma unroll
    for (int e = 0; e < 8; ++e) best[e] = (unsigned short)cur[e];
#pragma unroll
    for (int j = 1; j < 16; ++j) {
        row = (size_t)((b << 11) + ip[j]);
        s16x8 v = *(const s16x8*)(T + row * 128 + l * 8);
#pragma unroll
        for (int e = 0; e < 8; ++e) {
            unsigned short u = (unsigned short)v[e];
            if (u > best[e]) best[e] = u;
        }
    }
    s16x8 ov;
#pragma unroll
    for (int e = 0; e < 8; ++e) ov[e] = (short)best[e];
    *(s16x8*)(Mo + (size_t)p * 128 + l * 8) = ov;
}

// ---------------- pooling reductions over n ----------------
__global__ __launch_bounds__(256) void reduce1_kernel(const _Float16* __restrict__ xf, float* __restrict__ pmax, float* __restrict__ psum)
{
    const int b = blockIdx.x, oc = blockIdx.y, ch = blockIdx.z, tid = threadIdx.x;
    const int o = oc * 256 + tid;
    const _Float16* p = xf + ((size_t)(b << 11) + ch * 256) * 1024 + o;
    float mx = -3.4e38f, sm = 0.f;
    for (int n = 0; n < 256; ++n) {
        float v = (float)p[(size_t)n * 1024];
        mx = fmaxf(mx, v); sm += v;
    }
    pmax[((size_t)(b * 8 + ch) << 10) + o] = mx;
    psum[((size_t)(b * 8 + ch) << 10) + o] = sm;
}

__global__ __launch_bounds__(256) void reduce2_kernel(const float* __restrict__ pmax, const float* __restrict__ psum,
                                                      float* __restrict__ xmax, float* __restrict__ xavg)
{
    const int b = blockIdx.x, oc = blockIdx.y, tid = threadIdx.x;
    const int o = oc * 256 + tid;
    float mx = -3.4e38f, sm = 0.f;
#pragma unroll
    for (int c = 0; c < 8; ++c) {
        mx = fmaxf(mx, pmax[((size_t)(b * 8 + c) << 10) + o]);
        sm += psum[((size_t)(b * 8 + c) << 10) + o];
    }
    xmax[((size_t)b << 10) + o] = mx;
    xavg[((size_t)b << 10) + o] = sm * (1.f / 2048.f);
}

// ---------------- per-batch constant vector for Wc1 (broadcast cols 1024..3135 + bias/bn) ----------------
__global__ __launch_bounds__(256) void cvec_kernel(
    const float* __restrict__ label, const float* __restrict__ Wl, const float* __restrict__ gl, const float* __restrict__ bl,
    const float* __restrict__ Wc1, const float* __restrict__ bc1, const float* __restrict__ gc1, const float* __restrict__ bb1,
    const float* __restrict__ xmax, const float* __restrict__ xavg, float* __restrict__ cvec)
{
    __shared__ float v[2112];
    __shared__ float red[256];
    const int b = blockIdx.x, og = blockIdx.y, tid = threadIdx.x;
    for (int i = tid; i < 1024; i += 256) v[i] = xmax[((size_t)b << 10) + i];
    for (int i = tid; i < 1024; i += 256) v[1024 + i] = xavg[((size_t)b << 10) + i];
    if (tid < 64) {
        float s = 0.f;
        for (int i = 0; i < 16; ++i) s += Wl[tid * 16 + i] * label[b * 16 + i];
        s = gl[tid] * s + bl[tid];
        v[2048 + tid] = (s > 0.f) ? s : 0.2f * s;
    }
    __syncthreads();
    const int o = og * 64 + (tid >> 2), part = tid & 3;
    const float* wrow = Wc1 + (size_t)o * 3136 + 1024 + part * 528;
    float s = 0.f;
    for (int j = 0; j < 528; ++j) s += wrow[j] * v[part * 528 + j];
    red[tid] = s;
    __syncthreads();
    if (part == 0) {
        float tot = red[tid] + red[tid + 1] + red[tid + 2] + red[tid + 3];
        cvec[((size_t)b << 9) + o] = gc1[o] * (tot + bc1[o]) + bb1[o];
    }
}

// ---------------- final layout (M x 64 f32) -> (B,50,N) f32, coalesced via LDS transpose ----------------
__global__ __launch_bounds__(256) void reformat_kernel(const float* __restrict__ c3, float* __restrict__ out)
{
    __shared__ float T[64][65];
    const int tid = threadIdx.x;
    const int b = blockIdx.x, nc = blockIdx.y;    // 16 x 32
    const int n0 = nc * 64;
    const int row = tid >> 2, cg = (tid & 3) * 16;
    const float* src = c3 + ((size_t)((b << 11) + n0 + row)) * 64 + cg;
#pragma unroll
    for (int v = 0; v < 4; ++v) {
        f32x4 t = *(const f32x4*)(src + v * 4);
#pragma unroll
        for (int j = 0; j < 4; ++j) T[row][cg + v * 4 + j] = t[j];
    }
    __syncthreads();
    for (int j = tid; j < 50 * 64; j += 256) {
        const int n = j & 63, o = j >> 6;
        out[((size_t)(b * 50 + o) << 11) + n0 + n] = T[n][o];
    }
}

// ---------------- launch ----------------
extern "C" void kernel_launch(void* const* d_in, const int* in_sizes, int n_in,
                              void* d_out, int out_size, void* d_ws, size_t ws_size,
                              hipStream_t stream)
{
    (void)in_sizes; (void)n_in; (void)out_size; (void)ws_size;
    const float* points = (const float*)d_in[0];
    const float* label  = (const float*)d_in[1];
    const float* We1 = (const float*)d_in[2];
    const float* ge1 = (const float*)d_in[3];
    const float* be1 = (const float*)d_in[4];
    const float* We2 = (const float*)d_in[5];
    const float* ge2 = (const float*)d_in[6];
    const float* be2 = (const float*)d_in[7];
    const float* W1  = (const float*)d_in[8];
    const float* g1  = (const float*)d_in[9];
    const float* b1  = (const float*)d_in[10];
    const float* W2  = (const float*)d_in[11];
    const float* g2  = (const float*)d_in[12];
    const float* b2  = (const float*)d_in[13];
    const float* Wf  = (const float*)d_in[14];
    const float* gf  = (const float*)d_in[15];
    const float* bfv = (const float*)d_in[16];
    const float* Wl  = (const float*)d_in[17];
    const float* gl  = (const float*)d_in[18];
    const float* bl  = (const float*)d_in[19];
    const float* Wc1 = (const float*)d_in[20];
    const float* bc1 = (const float*)d_in[21];
    const float* gc1 = (const float*)d_in[22];
    const float* bb1 = (const float*)d_in[23];
    const float* Wc2 = (const float*)d_in[24];
    const float* bc2 = (const float*)d_in[25];
    const float* gc2 = (const float*)d_in[26];
    const float* bb2 = (const float*)d_in[27];
    const float* Wc3 = (const float*)d_in[28];
    const float* bc3 = (const float*)d_in[29];

    char* ws = (char*)d_ws;
    _Float16* x0  = (_Float16*)(ws + OFF_X0);
    _Float16* hT  = (_Float16*)(ws + OFF_HT);
    _Float16* tT  = (_Float16*)(ws + OFF_TT);
    _Float16* mT  = (_Float16*)(ws + OFF_MT);
    _Float16* xct = (_Float16*)(ws + OFF_XCAT);
    _Float16* xf  = (_Float16*)(ws + OFF_XF);
    _Float16* c1  = (_Float16*)(ws + OFF_C1);
    _Float16* c2  = (_Float16*)(ws + OFF_C2);
    float*    c3  = (float*)   (ws + OFF_C3);
    int*      idx = (int*)     (ws + OFF_IDX);
    float*    thr = (float*)   (ws + OFF_THR);

    _Float16* wE1 = (_Float16*)(ws + OFF_WE1);
    _Float16* wE2 = (_Float16*)(ws + OFF_WE2);
    _Float16* w1f = (_Float16*)(ws + OFF_W1);
    _Float16* w2f = (_Float16*)(ws + OFF_W2);
    _Float16* wF  = (_Float16*)(ws + OFF_WF);
    _Float16* wC1 = (_Float16*)(ws + OFF_WC1);
    _Float16* wC2 = (_Float16*)(ws + OFF_WC2);
    _Float16* wC3 = (_Float16*)(ws + OFF_WC3);
    float* bC2 = (float*)(ws + OFF_BC2);
    float* bC3 = (float*)(ws + OFF_BC3);
    float* cv  = (float*)(ws + OFF_CVEC);
    float* xmx = (float*)(ws + OFF_XMAX);
    float* xav = (float*)(ws + OFF_XAVG);
    float* pmx = (float*)(ws + OFF_PMAX);
    float* psm = (float*)(ws + OFF_PSUM);

    // prep
    fold_w_kernel<<<dim3(4704), 256, 0, stream>>>(We1, ge1, We2, ge2, W1, g1, W2, g2, Wf, gf, Wc1, gc1, Wc2, gc2, Wc3, ws);
    fold_bias_kernel<<<dim3(2), 256, 0, stream>>>(gc2, bc2, bb2, bc3, ws);
    x0prep_kernel<<<dim3(MM / 256), 256, 0, stream>>>(points, x0);
    knn_select <<<dim3(BB, NN / 32), 256, 0, stream>>>(points, thr);
    knn_collect<<<dim3(BB, NN / 32), 256, 0, stream>>>(points, thr, idx);

    // e1: x0(Mx64,pad) -> tT(Mx128), relu
    gemm_tile<<<dim3(256, 1), 256, 0, stream>>>(wE1, x0, tT, nullptr, be1, nullptr, 64, 64, 0, 128, 0, 128, 1, 0, 0, 0, 128);
    // e2: tT -> hT, relu
    gemm_tile<<<dim3(256, 1), 256, 0, stream>>>(wE2, tT, hT, nullptr, be2, nullptr, 128, 128, 0, 128, 0, 128, 1, 0, 0, 0, 128);

    for (int i = 0; i < 3; ++i) {
        const _Float16* hin = (i == 0) ? hT : xct;
        int ldH  = (i == 0) ? 128 : 384;
        int offH = (i == 0) ? 0 : (i - 1) * 128;
        // t = relu(bn(W1 h))
        gemm_tile<<<dim3(256, 1), 256, 0, stream>>>(w1f + (size_t)i * 16384, hin, tT, nullptr, b1 + i * 128, nullptr,
                                                    128, ldH, offH, 128, 0, 128, 1, 0, 0, 0, 128);
        // m = neighbor max
        gather_max_kernel<<<dim3(MM / 16), 256, 0, stream>>>((const short*)tT, idx, (short*)mT);
        // h' = relu(bn(W2 m) + h) -> xcat slice i
        gemm_tile<<<dim3(256, 1), 256, 0, stream>>>(w2f + (size_t)i * 16384, mT, xct, nullptr, b2 + i * 128, hin,
                                                    128, 128, 0, 384, i * 128, 128, 1, 0, ldH, offH, 128);
    }

    // xf = leaky(bn(Wf xcat))
    gemm_tile<<<dim3(256, 8), 256, 0, stream>>>(wF, xct, xf, nullptr, bfv, nullptr, 384, 384, 0, 1024, 0, 1024, 2, 0, 0, 0, 1024);

    // pooling + per-batch classifier constant
    reduce1_kernel<<<dim3(BB, 4, 8), 256, 0, stream>>>(xf, pmx, psm);
    reduce2_kernel<<<dim3(BB, 4), 256, 0, stream>>>(pmx, psm, xmx, xav);
    cvec_kernel<<<dim3(BB, 8), 256, 0, stream>>>(label, Wl, gl, bl, Wc1, bc1, gc1, bb1, xmx, xav, cv);

    // c1 = relu(gc1*Wc1[:, :1024] xf + cvec[b])
    gemm_tile<<<dim3(256, 4), 256, 0, stream>>>(wC1, xf, c1, nullptr, cv, nullptr, 1024, 1024, 0, 512, 0, 512, 1, 1, 0, 0, 512);
    // c2 = relu(bn(Wc2 c1 + bc2))
    gemm_tile<<<dim3(256, 2), 256, 0, stream>>>(wC2, c1, c2, nullptr, bC2, nullptr, 512, 512, 0, 256, 0, 256, 1, 0, 0, 0, 256);
    // c3 = Wc3 c2 + bc3 (no act), f32 out, only cols < 64 stored
    gemm_tile<<<dim3(256, 1), 256, 0, stream>>>(wC3, c2, nullptr, c3, bC3, nullptr, 256, 256, 0, 64, 0, 128, 0, 0, 0, 0, 64);

    // (M x 64) -> (B,50,N)
    reformat_kernel<<<dim3(BB, NN / 64), 256, 0, stream>>>(c3, (float*)d_out);
}

// Round 9
// 471.081 us; speedup vs baseline: 3.6843x; 1.0609x over previous
//
#include <hip/hip_runtime.h>
#include <cstdint>
#include <cstddef>

#define DEVINL __device__ __forceinline__

typedef float    f32x4 __attribute__((ext_vector_type(4)));
typedef _Float16 f16x8 __attribute__((ext_vector_type(8)));
typedef _Float16 f16x4 __attribute__((ext_vector_type(4)));

// ---------------- constants ----------------
constexpr int BB = 16, NN = 2048, MM = 32768;

// ---------------- ws layout (bytes) ----------------
constexpr size_t OFF_WE1 = 0;                           // 128x64 f16 (Kp padded 6->64)
constexpr size_t OFF_WE2 = OFF_WE1 + 128 * 64 * 2;
constexpr size_t OFF_W1  = OFF_WE2 + 128 * 128 * 2;
constexpr size_t OFF_W2  = OFF_W1  + 3 * 128 * 128 * 2;
constexpr size_t OFF_WF  = OFF_W2  + 3 * 128 * 128 * 2;
constexpr size_t OFF_WC1 = OFF_WF  + 1024 * 384 * 2;
constexpr size_t OFF_WC2 = OFF_WC1 + 512 * 1024 * 2;
constexpr size_t OFF_WC3 = OFF_WC2 + 256 * 512 * 2;     // 128x256 (Opad 50->128)
constexpr size_t OFF_BC2 = OFF_WC3 + 128 * 256 * 2;     // 256 f32
constexpr size_t OFF_BC3 = OFF_BC2 + 256 * 4;           // 128 f32
constexpr size_t OFF_CVEC= OFF_BC3 + 128 * 4;           // 16x512 f32
constexpr size_t OFF_XMAX= OFF_CVEC+ 16 * 512 * 4;
constexpr size_t OFF_XAVG= OFF_XMAX+ 16 * 1024 * 4;
constexpr size_t OFF_PMAX= OFF_XAVG+ 16 * 1024 * 4;
constexpr size_t OFF_PSUM= OFF_PMAX+ 16 * 16 * 1024 * 4;
constexpr size_t OFF_IDX = OFF_PSUM+ 16 * 16 * 1024 * 4;
constexpr size_t OFF_R1  = 8ull << 20;                  // > OFF_IDX + 2MB
constexpr size_t OFF_X0  = OFF_R1;                      // 4MB  (M x 64 f16, k-padded)
constexpr size_t OFF_HT  = OFF_R1 + (4ull  << 20);      // 8MB  (M x 128 f16)
constexpr size_t OFF_TT  = OFF_R1 + (12ull << 20);      // 8MB
constexpr size_t OFF_MT  = OFF_R1 + (20ull << 20);      // 8MB
constexpr size_t OFF_C1  = OFF_R1;                      // 32MB (M x 512 f16), aliases x0/h/t/m (dead)
constexpr size_t OFF_XCAT= OFF_R1 + (32ull << 20);      // 24MB (M x 384 f16)
constexpr size_t OFF_C2  = OFF_XCAT;                    // 16MB (M x 256 f16), aliases xcat (dead)
constexpr size_t OFF_XF  = OFF_XCAT + (24ull << 20);    // 64MB (M x 1024 f16)
constexpr size_t OFF_C3  = OFF_XF;                      // 8MB  (M x 64 f32), aliases xf (dead)

// ---------------- fold-all: weights (f16, BN-folded), biases, x0 prep ----------------
__global__ __launch_bounds__(256) void fold_all_kernel(
    const float* We1, const float* ge1, const float* We2, const float* ge2,
    const float* W1,  const float* g1,  const float* W2,  const float* g2,
    const float* Wf,  const float* gf,  const float* Wc1, const float* gc1,
    const float* Wc2, const float* gc2, const float* Wc3,
    const float* gc2b, const float* bc2, const float* bb2, const float* bc3,
    const float* pts, char* ws)
{
    const int bid = blockIdx.x;
    const int tid = threadIdx.x;

    if (bid == 4704) {
        ((float*)(ws + OFF_BC2))[tid] = gc2b[tid] * bc2[tid] + bb2[tid];
        return;
    }
    if (bid == 4705) {
        if (tid < 128) ((float*)(ws + OFF_BC3))[tid] = (tid < 50) ? bc3[tid] : 0.f;
        return;
    }
    if (bid >= 4706) {           // x0 prep: (B,6,N) f32 -> (M x 64) f16 K-contig, zero pad
        int m = (bid - 4706) * 256 + tid;
        int b = m >> 11, n = m & 2047;
        const float* ps = pts + (size_t)b * 6 * 2048 + n;
        _Float16 tmp[64];
#pragma unroll
        for (int c = 0; c < 64; ++c) tmp[c] = (_Float16)0.f;
#pragma unroll
        for (int c = 0; c < 6; ++c) tmp[c] = (_Float16)ps[(size_t)c << 11];
        _Float16* dst = (_Float16*)(ws + OFF_X0) + (size_t)m * 64;
#pragma unroll
        for (int v = 0; v < 8; ++v) *(f16x8*)(dst + v * 8) = *(const f16x8*)(tmp + v * 8);
        return;
    }

    int id, base;
    if      (bid < 32)   { id = 0;  base = 0;    }
    else if (bid < 96)   { id = 1;  base = 32;   }
    else if (bid < 160)  { id = 2;  base = 96;   }
    else if (bid < 224)  { id = 3;  base = 160;  }
    else if (bid < 288)  { id = 4;  base = 224;  }
    else if (bid < 352)  { id = 5;  base = 288;  }
    else if (bid < 416)  { id = 6;  base = 352;  }
    else if (bid < 480)  { id = 7;  base = 416;  }
    else if (bid < 2016) { id = 8;  base = 480;  }
    else if (bid < 4064) { id = 9;  base = 2016; }
    else if (bid < 4576) { id = 10; base = 4064; }
    else                 { id = 11; base = 4576; }

    const float* src = nullptr; const float* g = nullptr; _Float16* dst = nullptr;
    int O = 0, K = 0, lds = 0, Kp = 0;
    switch (id) {
        case 0:  src = We1; g = ge1; O = 128; K = 6;    lds = 6;    Kp = 64;   dst = (_Float16*)(ws + OFF_WE1); break;
        case 1:  src = We2; g = ge2; O = 128; K = 128;  lds = 128;  Kp = 128;  dst = (_Float16*)(ws + OFF_WE2); break;
        case 2: case 3: case 4: {
            int i = id - 2;
            src = W1 + (size_t)i * 16384; g = g1 + i * 128; O = 128; K = 128; lds = 128; Kp = 128;
            dst = (_Float16*)(ws + OFF_W1) + (size_t)i * 16384; break; }
        case 5: case 6: case 7: {
            int i = id - 5;
            src = W2 + (size_t)i * 16384; g = g2 + i * 128; O = 128; K = 128; lds = 128; Kp = 128;
            dst = (_Float16*)(ws + OFF_W2) + (size_t)i * 16384; break; }
        case 8:  src = Wf;  g = gf;  O = 1024; K = 384;  lds = 384;  Kp = 384;  dst = (_Float16*)(ws + OFF_WF);  break;
        case 9:  src = Wc1; g = gc1; O = 512;  K = 1024; lds = 3136; Kp = 1024; dst = (_Float16*)(ws + OFF_WC1); break;
        case 10: src = Wc2; g = gc2; O = 256;  K = 512;  lds = 512;  Kp = 512;  dst = (_Float16*)(ws + OFF_WC2); break;
        default: src = Wc3; g = nullptr; O = 50; K = 256; lds = 256; Kp = 256;  dst = (_Float16*)(ws + OFF_WC3); break;
    }
    int e = (bid - base) * 256 + tid;
    int o = e / Kp, k = e - o * Kp;
    float v = 0.f;
    if (o < O && k < K) {
        v = src[(size_t)o * lds + k];
        if (g) v *= g[o];
    }
    dst[e] = (_Float16)v;
}

// ---------------- KNN (fused): med3 distance-select + threshold collect ----------------
DEVINL float knn_dist(const float4 pq, const float4 pm) {
    float t = pq.x * pm.x;
    t = fmaf(pq.y, pm.y, t);
    t = fmaf(pq.z, pm.z, t);
    return fmaf(-2.f, t, pm.w);
}

#define KNN_DINS(X) do { \
    const float x_ = (X); \
    d15 = __builtin_amdgcn_fmed3f(x_, d14, d15); \
    d14 = __builtin_amdgcn_fmed3f(x_, d13, d14); \
    d13 = __builtin_amdgcn_fmed3f(x_, d12, d13); \
    d12 = __builtin_amdgcn_fmed3f(x_, d11, d12); \
    d11 = __builtin_amdgcn_fmed3f(x_, d10, d11); \
    d10 = __builtin_amdgcn_fmed3f(x_, d9,  d10); \
    d9  = __builtin_amdgcn_fmed3f(x_, d8,  d9);  \
    d8  = __builtin_amdgcn_fmed3f(x_, d7,  d8);  \
    d7  = __builtin_amdgcn_fmed3f(x_, d6,  d7);  \
    d6  = __builtin_amdgcn_fmed3f(x_, d5,  d6);  \
    d5  = __builtin_amdgcn_fmed3f(x_, d4,  d5);  \
    d4  = __builtin_amdgcn_fmed3f(x_, d3,  d4);  \
    d3  = __builtin_amdgcn_fmed3f(x_, d2,  d3);  \
    d2  = __builtin_amdgcn_fmed3f(x_, d1,  d2);  \
    d1  = __builtin_amdgcn_fmed3f(x_, d0,  d1);  \
    d0  = __builtin_amdgcn_fmed3f(x_, -3.4e38f, d0); \
} while (0)

__global__ __launch_bounds__(256) void knn_kernel(const float* __restrict__ pts, int* __restrict__ idxout)
{
    __shared__ float4 P[2048];       // 32KB, stays intact for the rescan
    __shared__ float  md[4096];      // 16KB merge buffer
    __shared__ float  tq[32];
    __shared__ int    cnt[32];
    const int tid = threadIdx.x;
    const int b = blockIdx.x;
    const float* pb = pts + (size_t)b * 6 * 2048;
    for (int i = tid; i < 2048; i += 256) {
        float x = pb[i];
        float y = pb[2048 + i];
        float z = pb[4096 + i];
        P[i] = make_float4(x, y, z, x * x + y * y + z * z);
    }
    __syncthreads();

    const int p = tid & 7;          // candidate partition (m == 8*it + p)
    const int g = tid >> 3;         // query within block (0..31)
    const int q = blockIdx.y * 32 + g;
    const float4 pq = P[q];

    float d0 = 3.4e38f, d1 = 3.4e38f, d2 = 3.4e38f, d3 = 3.4e38f,
          d4 = 3.4e38f, d5 = 3.4e38f, d6 = 3.4e38f, d7 = 3.4e38f,
          d8 = 3.4e38f, d9 = 3.4e38f, d10 = 3.4e38f, d11 = 3.4e38f,
          d12 = 3.4e38f, d13 = 3.4e38f, d14 = 3.4e38f, d15 = 3.4e38f;

    float4 nxt = P[p];
#pragma unroll 2
    for (int it = 0; it < 256; ++it) {
        const float4 pm = nxt;
        const int m = it * 8 + p;
        nxt = P[(m + 8) & 2047];    // prefetch next candidate (wraps harmlessly on last)
        KNN_DINS(knn_dist(pq, pm));
    }

#define KNN_SPILL(J) md[J * 256 + tid] = d##J;
    KNN_SPILL(0)  KNN_SPILL(1)  KNN_SPILL(2)  KNN_SPILL(3)
    KNN_SPILL(4)  KNN_SPILL(5)  KNN_SPILL(6)  KNN_SPILL(7)
    KNN_SPILL(8)  KNN_SPILL(9)  KNN_SPILL(10) KNN_SPILL(11)
    KNN_SPILL(12) KNN_SPILL(13) KNN_SPILL(14) KNN_SPILL(15)
#undef KNN_SPILL
    if (tid < 32) cnt[tid] = 0;
    __syncthreads();

    if (p == 0) {
        // merge the 7 other sorted (ascending) lists; early exit per list
        for (int s = 1; s < 8; ++s) {
#pragma unroll
            for (int j = 0; j < 16; ++j) {
                const float x = md[j * 256 + tid + s];
                if (x >= d15) break;
                KNN_DINS(x);
            }
        }
        tq[g] = d15;                 // 16th-smallest (primed) distance
    }
    __syncthreads();

    // rescan with the threshold; same P, same knn_dist => bit-identical distances
    const float t = tq[g];
    int* op = idxout + (((size_t)(b << 11) + q) << 4);
    float4 nxt2 = P[p];
    for (int it = 0; it < 256; ++it) {
        const float4 pm = nxt2;
        const int m = it * 8 + p;
        nxt2 = P[(m + 8) & 2047];
        const float d = knn_dist(pq, pm);
        if (d <= t) {
            const int pos = atomicAdd(&cnt[g], 1);
            if (pos < 16) op[pos] = m;   // order-scrambled: consumer is a max over the set
        }
    }
}

// ---------------- GEMM v3: TM(64|128) x 128o tile, BK=64, global_load_lds staging,
// LDS-staged coalesced f16 store epilogue. Requires Kp%64==0, O tile full (f16 path).
template<int TM>
__global__ __launch_bounds__(256) void gemm_tile(
    const _Float16* __restrict__ W, const _Float16* __restrict__ X,
    _Float16* __restrict__ Y, float* __restrict__ Y32,
    const float* __restrict__ bias, const _Float16* __restrict__ Res,
    int Kp, int ldX, int xoff, int ldY, int yoff, int Opad,
    int act, int biasPerBatch, int ldR, int roff, int Olimit)
{
    constexpr int MI = TM / 32;                 // m-frags per wave
    __shared__ _Float16 SH[128 * 64 + TM * 64]; // As | Bs ; reused as output tile
    _Float16* As = SH;
    _Float16* Bs = SH + 128 * 64;

    const int tid  = threadIdx.x;
    const int lane = tid & 63, wave = tid >> 6;
    const int r = lane & 15, quad = lane >> 4;
    const int m_blk = blockIdx.x * TM, o_blk = blockIdx.y * 128;
    const int oh = (wave >> 1) * 64, mh = (wave & 1) * (TM / 2);

    f32x4 acc[4][MI];
#pragma unroll
    for (int a = 0; a < 4; ++a)
#pragma unroll
        for (int c = 0; c < MI; ++c) acc[a][c] = (f32x4){0.f, 0.f, 0.f, 0.f};

    const int srow  = wave * 8 + (lane >> 3);
    const int sslot = lane & 7;

    for (int k0 = 0; k0 < Kp; k0 += 64) {
        __syncthreads();
#pragma unroll
        for (int t = 0; t < 4; ++t) {           // A: 128 rows
            const int rowA = t * 32 + srow;
            const int gk = k0 + ((sslot ^ (rowA & 7)) << 3);
            const _Float16* gA = W + (size_t)(o_blk + rowA) * Kp + gk;
            __builtin_amdgcn_global_load_lds(
                (const __attribute__((address_space(1))) unsigned int*)gA,
                (__attribute__((address_space(3))) unsigned int*)(As + t * 2048 + wave * 512),
                16, 0, 0);
        }
#pragma unroll
        for (int t = 0; t < TM / 32; ++t) {     // B: TM rows
            const int rowB = t * 32 + srow;
            const int gk = k0 + ((sslot ^ (rowB & 7)) << 3);
            const _Float16* gB = X + (size_t)(m_blk + rowB) * ldX + xoff + gk;
            __builtin_amdgcn_global_load_lds(
                (const __attribute__((address_space(1))) unsigned int*)gB,
                (__attribute__((address_space(3))) unsigned int*)(Bs + t * 2048 + wave * 512),
                16, 0, 0);
        }
        __syncthreads();
#pragma unroll
        for (int ks = 0; ks < 2; ++ks) {
            f16x8 af[4], bf[MI];
#pragma unroll
            for (int oi = 0; oi < 4; ++oi) {
                const int row = oh + oi * 16 + r;
                const int slot = (ks * 4 + quad) ^ (row & 7);
                af[oi] = *(const f16x8*)(As + row * 64 + slot * 8);
            }
#pragma unroll
            for (int mi = 0; mi < MI; ++mi) {
                const int row = mh + mi * 16 + r;
                const int slot = (ks * 4 + quad) ^ (row & 7);
                bf[mi] = *(const f16x8*)(Bs + row * 64 + slot * 8);
            }
#pragma unroll
            for (int oi = 0; oi < 4; ++oi)
#pragma unroll
                for (int mi = 0; mi < MI; ++mi)
                    acc[oi][mi] = __builtin_amdgcn_mfma_f32_16x16x32_f16(af[oi], bf[mi], acc[oi][mi], 0, 0, 0);
        }
    }

    const int bb = biasPerBatch ? (m_blk >> 11) * Opad : 0;
    __syncthreads();   // done reading As/Bs; SH is reusable

    if (Y32) {
        // direct f32 store (only the small final layer)
#pragma unroll
        for (int oi = 0; oi < 4; ++oi) {
            const int og = o_blk + oh + oi * 16 + quad * 4;
            if (og >= Olimit) continue;
            const f32x4 bv = *(const f32x4*)(bias + bb + og);
#pragma unroll
            for (int mi = 0; mi < MI; ++mi) {
                const int m = m_blk + mh + mi * 16 + r;
                f32x4 v = acc[oi][mi] + bv;
#pragma unroll
                for (int j = 0; j < 4; ++j) {
                    float x = v[j];
                    if (act == 1)      x = (x > 0.f) ? x : 0.0f;
                    else if (act == 2) x = (x > 0.f) ? x : 0.2f * x;
                    v[j] = x;
                }
                *(f32x4*)(Y32 + (size_t)m * ldY + yoff + og) = v;
            }
        }
        return;
    }

    // f16 path: stage [TM][128] tile in LDS (XOR-swizzled), then coalesced writeback
    _Float16* OT = SH;
#pragma unroll
    for (int oi = 0; oi < 4; ++oi) {
        const int ol = oh + oi * 16 + quad * 4;       // local o (0..127), 4-aligned
        const f32x4 bv = *(const f32x4*)(bias + bb + o_blk + ol);
#pragma unroll
        for (int mi = 0; mi < MI; ++mi) {
            const int row = mh + mi * 16 + r;         // local m
            f32x4 v = acc[oi][mi] + bv;
            if (Res) {
                f16x4 rr = *(const f16x4*)(Res + (size_t)(m_blk + row) * ldR + roff + o_blk + ol);
#pragma unroll
                for (int j = 0; j < 4; ++j) v[j] += (float)rr[j];
            }
            f16x4 ov;
#pragma unroll
            for (int j = 0; j < 4; ++j) {
                float x = v[j];
                if (act == 1)      x = (x > 0.f) ? x : 0.0f;
                else if (act == 2) x = (x > 0.f) ? x : 0.2f * x;
                ov[j] = (_Float16)x;
            }
            const int s = ((ol >> 2) ^ (row & 31)) << 2;   // swizzled 8B slot
            *(f16x4*)(OT + row * 128 + s) = ov;
        }
    }
    __syncthreads();
#pragma unroll
    for (int it2 = 0; it2 < TM / 16; ++it2) {
        const int row = it2 * 16 + (tid >> 4);
        const int c = tid & 15;                        // 8 f16 per lane, contiguous
        const int s0 = ((c * 2) ^ (row & 31)) << 2;
        const int s1 = ((c * 2 + 1) ^ (row & 31)) << 2;
        f16x4 a = *(const f16x4*)(OT + row * 128 + s0);
        f16x4 b2 = *(const f16x4*)(OT + row * 128 + s1);
        f16x8 o8;
        o8[0] = a[0]; o8[1] = a[1]; o8[2] = a[2]; o8[3] = a[3];
        o8[4] = b2[0]; o8[5] = b2[1]; o8[6] = b2[2]; o8[7] = b2[3];
        *(f16x8*)(Y + (size_t)(m_blk + row) * ldY + yoff + o_blk + c * 8) = o8;  // FIX: + o_blk
    }
}

// ---------------- neighbor gather + channel max (relu outputs => ushort-monotonic f16 bits) ----------------
typedef short s16x8 __attribute__((ext_vector_type(8)));
__global__ __launch_bounds__(256) void gather_max_kernel(
    const short* __restrict__ T, const int* __restrict__ idx, short* __restrict__ Mo)
{
    const int tid = threadIdx.x;
    const int p = blockIdx.x * 16 + (tid >> 4);
    const int l = tid & 15;
    const int b = p >> 11;
    const int* ip = idx + (size_t)p * 16;
    size_t row = (size_t)((b << 11) + ip[0]);
    s16x8 cur = *(const s16x8*)(T + row * 128 + l * 8);
    unsigned short best[8];
#pragma unroll
    for (int e = 0; e < 8; ++e) best[e] = (unsigned short)cur[e];
#pragma unroll
    for (int j = 1; j < 16; ++j) {
        row = (size_t)((b << 11) + ip[j]);
        s16x8 v = *(const s16x8*)(T + row * 128 + l * 8);
#pragma unroll
        for (int e = 0; e < 8; ++e) {
            unsigned short u = (unsigned short)v[e];
            if (u > best[e]) best[e] = u;
        }
    }
    s16x8 ov;
#pragma unroll
    for (int e = 0; e < 8; ++e) ov[e] = (short)best[e];
    *(s16x8*)(Mo + (size_t)p * 128 + l * 8) = ov;
}

// ---------------- pooling reductions over n ----------------
__global__ __launch_bounds__(256) void reduce1_kernel(const _Float16* __restrict__ xf, float* __restrict__ pmax, float* __restrict__ psum)
{
    const int b = blockIdx.x, oc = blockIdx.y, ch = blockIdx.z, tid = threadIdx.x;
    const int o = oc * 256 + tid;
    const _Float16* p = xf + ((size_t)(b << 11) + ch * 256) * 1024 + o;
    float mx = -3.4e38f, sm = 0.f;
    for (int n = 0; n < 256; ++n) {
        float v = (float)p[(size_t)n * 1024];
        mx = fmaxf(mx, v); sm += v;
    }
    pmax[((size_t)(b * 8 + ch) << 10) + o] = mx;
    psum[((size_t)(b * 8 + ch) << 10) + o] = sm;
}

__global__ __launch_bounds__(256) void reduce2_kernel(const float* __restrict__ pmax, const float* __restrict__ psum,
                                                      float* __restrict__ xmax, float* __restrict__ xavg)
{
    const int b = blockIdx.x, oc = blockIdx.y, tid = threadIdx.x;
    const int o = oc * 256 + tid;
    float mx = -3.4e38f, sm = 0.f;
#pragma unroll
    for (int c = 0; c < 8; ++c) {
        mx = fmaxf(mx, pmax[((size_t)(b * 8 + c) << 10) + o]);
        sm += psum[((size_t)(b * 8 + c) << 10) + o];
    }
    xmax[((size_t)b << 10) + o] = mx;
    xavg[((size_t)b << 10) + o] = sm * (1.f / 2048.f);
}

// ---------------- per-batch constant vector for Wc1 (broadcast cols 1024..3135 + bias/bn) ----------------
__global__ __launch_bounds__(256) void cvec_kernel(
    const float* __restrict__ label, const float* __restrict__ Wl, const float* __restrict__ gl, const float* __restrict__ bl,
    const float* __restrict__ Wc1, const float* __restrict__ bc1, const float* __restrict__ gc1, const float* __restrict__ bb1,
    const float* __restrict__ xmax, const float* __restrict__ xavg, float* __restrict__ cvec)
{
    __shared__ float v[2112];
    __shared__ float red[256];
    const int b = blockIdx.x, og = blockIdx.y, tid = threadIdx.x;
    for (int i = tid; i < 1024; i += 256) v[i] = xmax[((size_t)b << 10) + i];
    for (int i = tid; i < 1024; i += 256) v[1024 + i] = xavg[((size_t)b << 10) + i];
    if (tid < 64) {
        float s = 0.f;
        for (int i = 0; i < 16; ++i) s += Wl[tid * 16 + i] * label[b * 16 + i];
        s = gl[tid] * s + bl[tid];
        v[2048 + tid] = (s > 0.f) ? s : 0.2f * s;
    }
    __syncthreads();
    const int o = og * 64 + (tid >> 2), part = tid & 3;
    const float* wrow = Wc1 + (size_t)o * 3136 + 1024 + part * 528;
    float s = 0.f;
    for (int j = 0; j < 528; ++j) s += wrow[j] * v[part * 528 + j];
    red[tid] = s;
    __syncthreads();
    if (part == 0) {
        float tot = red[tid] + red[tid + 1] + red[tid + 2] + red[tid + 3];
        cvec[((size_t)b << 9) + o] = gc1[o] * (tot + bc1[o]) + bb1[o];
    }
}

// ---------------- final layout (M x 64 f32) -> (B,50,N) f32, coalesced via LDS transpose ----------------
__global__ __launch_bounds__(256) void reformat_kernel(const float* __restrict__ c3, float* __restrict__ out)
{
    __shared__ float T[64][65];
    const int tid = threadIdx.x;
    const int b = blockIdx.x, nc = blockIdx.y;    // 16 x 32
    const int n0 = nc * 64;
    const int row = tid >> 2, cg = (tid & 3) * 16;
    const float* src = c3 + ((size_t)((b << 11) + n0 + row)) * 64 + cg;
#pragma unroll
    for (int v = 0; v < 4; ++v) {
        f32x4 t = *(const f32x4*)(src + v * 4);
#pragma unroll
        for (int j = 0; j < 4; ++j) T[row][cg + v * 4 + j] = t[j];
    }
    __syncthreads();
    for (int j = tid; j < 50 * 64; j += 256) {
        const int n = j & 63, o = j >> 6;
        out[((size_t)(b * 50 + o) << 11) + n0 + n] = T[n][o];
    }
}

// ---------------- launch ----------------
extern "C" void kernel_launch(void* const* d_in, const int* in_sizes, int n_in,
                              void* d_out, int out_size, void* d_ws, size_t ws_size,
                              hipStream_t stream)
{
    (void)in_sizes; (void)n_in; (void)out_size; (void)ws_size;
    const float* points = (const float*)d_in[0];
    const float* label  = (const float*)d_in[1];
    const float* We1 = (const float*)d_in[2];
    const float* ge1 = (const float*)d_in[3];
    const float* be1 = (const float*)d_in[4];
    const float* We2 = (const float*)d_in[5];
    const float* ge2 = (const float*)d_in[6];
    const float* be2 = (const float*)d_in[7];
    const float* W1  = (const float*)d_in[8];
    const float* g1  = (const float*)d_in[9];
    const float* b1  = (const float*)d_in[10];
    const float* W2  = (const float*)d_in[11];
    const float* g2  = (const float*)d_in[12];
    const float* b2  = (const float*)d_in[13];
    const float* Wf  = (const float*)d_in[14];
    const float* gf  = (const float*)d_in[15];
    const float* bfv = (const float*)d_in[16];
    const float* Wl  = (const float*)d_in[17];
    const float* gl  = (const float*)d_in[18];
    const float* bl  = (const float*)d_in[19];
    const float* Wc1 = (const float*)d_in[20];
    const float* bc1 = (const float*)d_in[21];
    const float* gc1 = (const float*)d_in[22];
    const float* bb1 = (const float*)d_in[23];
    const float* Wc2 = (const float*)d_in[24];
    const float* bc2 = (const float*)d_in[25];
    const float* gc2 = (const float*)d_in[26];
    const float* bb2 = (const float*)d_in[27];
    const float* Wc3 = (const float*)d_in[28];
    const float* bc3 = (const float*)d_in[29];

    char* ws = (char*)d_ws;
    _Float16* hT  = (_Float16*)(ws + OFF_HT);
    _Float16* tT  = (_Float16*)(ws + OFF_TT);
    _Float16* mT  = (_Float16*)(ws + OFF_MT);
    _Float16* xct = (_Float16*)(ws + OFF_XCAT);
    _Float16* xf  = (_Float16*)(ws + OFF_XF);
    _Float16* c1  = (_Float16*)(ws + OFF_C1);
    _Float16* c2  = (_Float16*)(ws + OFF_C2);
    float*    c3  = (float*)   (ws + OFF_C3);
    int*      idx = (int*)     (ws + OFF_IDX);
    _Float16* x0  = (_Float16*)(ws + OFF_X0);

    _Float16* wE1 = (_Float16*)(ws + OFF_WE1);
    _Float16* wE2 = (_Float16*)(ws + OFF_WE2);
    _Float16* w1f = (_Float16*)(ws + OFF_W1);
    _Float16* w2f = (_Float16*)(ws + OFF_W2);
    _Float16* wF  = (_Float16*)(ws + OFF_WF);
    _Float16* wC1 = (_Float16*)(ws + OFF_WC1);
    _Float16* wC2 = (_Float16*)(ws + OFF_WC2);
    _Float16* wC3 = (_Float16*)(ws + OFF_WC3);
    float* bC2 = (float*)(ws + OFF_BC2);
    float* bC3 = (float*)(ws + OFF_BC3);
    float* cv  = (float*)(ws + OFF_CVEC);
    float* xmx = (float*)(ws + OFF_XMAX);
    float* xav = (float*)(ws + OFF_XAVG);
    float* pmx = (float*)(ws + OFF_PMAX);
    float* psm = (float*)(ws + OFF_PSUM);

    // prep (weights + biases + x0, one launch)
    fold_all_kernel<<<dim3(4834), 256, 0, stream>>>(We1, ge1, We2, ge2, W1, g1, W2, g2,
                                                    Wf, gf, Wc1, gc1, Wc2, gc2, Wc3,
                                                    gc2, bc2, bb2, bc3, points, ws);
    knn_kernel<<<dim3(BB, NN / 32), 256, 0, stream>>>(points, idx);

    // e1: x0(Mx64,pad) -> tT(Mx128), relu
    gemm_tile<64><<<dim3(512, 1), 256, 0, stream>>>(wE1, x0, tT, nullptr, be1, nullptr, 64, 64, 0, 128, 0, 128, 1, 0, 0, 0, 128);
    // e2: tT -> hT, relu
    gemm_tile<64><<<dim3(512, 1), 256, 0, stream>>>(wE2, tT, hT, nullptr, be2, nullptr, 128, 128, 0, 128, 0, 128, 1, 0, 0, 0, 128);

    for (int i = 0; i < 3; ++i) {
        const _Float16* hin = (i == 0) ? hT : xct;
        int ldH  = (i == 0) ? 128 : 384;
        int offH = (i == 0) ? 0 : (i - 1) * 128;
        // t = relu(bn(W1 h))
        gemm_tile<64><<<dim3(512, 1), 256, 0, stream>>>(w1f + (size_t)i * 16384, hin, tT, nullptr, b1 + i * 128, nullptr,
                                                        128, ldH, offH, 128, 0, 128, 1, 0, 0, 0, 128);
        // m = neighbor max
        gather_max_kernel<<<dim3(MM / 16), 256, 0, stream>>>((const short*)tT, idx, (short*)mT);
        // h' = relu(bn(W2 m) + h) -> xcat slice i
        gemm_tile<64><<<dim3(512, 1), 256, 0, stream>>>(w2f + (size_t)i * 16384, mT, xct, nullptr, b2 + i * 128, hin,
                                                        128, 128, 0, 384, i * 128, 128, 1, 0, ldH, offH, 128);
    }

    // xf = leaky(bn(Wf xcat))
    gemm_tile<128><<<dim3(256, 8), 256, 0, stream>>>(wF, xct, xf, nullptr, bfv, nullptr, 384, 384, 0, 1024, 0, 1024, 2, 0, 0, 0, 1024);

    // pooling + per-batch classifier constant
    reduce1_kernel<<<dim3(BB, 4, 8), 256, 0, stream>>>(xf, pmx, psm);
    reduce2_kernel<<<dim3(BB, 4), 256, 0, stream>>>(pmx, psm, xmx, xav);
    cvec_kernel<<<dim3(BB, 8), 256, 0, stream>>>(label, Wl, gl, bl, Wc1, bc1, gc1, bb1, xmx, xav, cv);

    // c1 = relu(gc1*Wc1[:, :1024] xf + cvec[b])
    gemm_tile<128><<<dim3(256, 4), 256, 0, stream>>>(wC1, xf, c1, nullptr, cv, nullptr, 1024, 1024, 0, 512, 0, 512, 1, 1, 0, 0, 512);
    // c2 = relu(bn(Wc2 c1 + bc2))
    gemm_tile<128><<<dim3(256, 2), 256, 0, stream>>>(wC2, c1, c2, nullptr, bC2, nullptr, 512, 512, 0, 256, 0, 256, 1, 0, 0, 0, 256);
    // c3 = Wc3 c2 + bc3 (no act), f32 out, only cols < 64 stored
    gemm_tile<128><<<dim3(256, 1), 256, 0, stream>>>(wC3, c2, nullptr, c3, bC3, nullptr, 256, 256, 0, 64, 0, 128, 0, 0, 0, 0, 64);

    // (M x 64) -> (B,50,N)
    reformat_kernel<<<dim3(BB, NN / 64), 256, 0, stream>>>(c3, (float*)d_out);
}

// Round 10
// 432.113 us; speedup vs baseline: 4.0165x; 1.0902x over previous
//
#include <hip/hip_runtime.h>
#include <cstdint>
#include <cstddef>

#define DEVINL __device__ __forceinline__

typedef float    f32x4 __attribute__((ext_vector_type(4)));
typedef _Float16 f16x8 __attribute__((ext_vector_type(8)));
typedef _Float16 f16x4 __attribute__((ext_vector_type(4)));

// ---------------- constants ----------------
constexpr int BB = 16, NN = 2048, MM = 32768;

// ---------------- ws layout (bytes) ----------------
constexpr size_t OFF_WE1 = 0;                           // 128x64 f16 (Kp padded 6->64)
constexpr size_t OFF_WE2 = OFF_WE1 + 128 * 64 * 2;
constexpr size_t OFF_W1  = OFF_WE2 + 128 * 128 * 2;
constexpr size_t OFF_W2  = OFF_W1  + 3 * 128 * 128 * 2;
constexpr size_t OFF_WF  = OFF_W2  + 3 * 128 * 128 * 2;
constexpr size_t OFF_WC1 = OFF_WF  + 1024 * 384 * 2;
constexpr size_t OFF_WC2 = OFF_WC1 + 512 * 1024 * 2;
constexpr size_t OFF_WC3 = OFF_WC2 + 256 * 512 * 2;     // 128x256 (Opad 50->128)
constexpr size_t OFF_BC2 = OFF_WC3 + 128 * 256 * 2;     // 256 f32
constexpr size_t OFF_BC3 = OFF_BC2 + 256 * 4;           // 128 f32
constexpr size_t OFF_CVEC= OFF_BC3 + 128 * 4;           // 16x512 f32
constexpr size_t OFF_PMAX= OFF_CVEC+ 16 * 512 * 4;
constexpr size_t OFF_PSUM= OFF_PMAX+ 16 * 8 * 1024 * 4;
constexpr size_t OFF_IDX = OFF_PSUM+ 16 * 8 * 1024 * 4;
constexpr size_t OFF_R1  = 8ull << 20;                  // > OFF_IDX + 2MB
constexpr size_t OFF_X0  = OFF_R1;                      // 4MB  (M x 64 f16, k-padded)
constexpr size_t OFF_HT  = OFF_R1 + (4ull  << 20);      // 8MB  (M x 128 f16)
constexpr size_t OFF_TT  = OFF_R1 + (12ull << 20);      // 8MB
constexpr size_t OFF_MT  = OFF_R1 + (20ull << 20);      // 8MB
constexpr size_t OFF_C1  = OFF_R1;                      // 32MB (M x 512 f16), aliases x0/h/t/m (dead)
constexpr size_t OFF_XCAT= OFF_R1 + (32ull << 20);      // 24MB (M x 384 f16)
constexpr size_t OFF_C2  = OFF_XCAT;                    // 16MB (M x 256 f16), aliases xcat (dead)
constexpr size_t OFF_XF  = OFF_XCAT + (24ull << 20);    // 64MB (M x 1024 f16)

// ---------------- fold-all: weights (f16, BN-folded), biases, x0 prep ----------------
__global__ __launch_bounds__(256) void fold_all_kernel(
    const float* We1, const float* ge1, const float* We2, const float* ge2,
    const float* W1,  const float* g1,  const float* W2,  const float* g2,
    const float* Wf,  const float* gf,  const float* Wc1, const float* gc1,
    const float* Wc2, const float* gc2, const float* Wc3,
    const float* gc2b, const float* bc2, const float* bb2, const float* bc3,
    const float* pts, char* ws)
{
    const int bid = blockIdx.x;
    const int tid = threadIdx.x;

    if (bid == 4704) {
        ((float*)(ws + OFF_BC2))[tid] = gc2b[tid] * bc2[tid] + bb2[tid];
        return;
    }
    if (bid == 4705) {
        if (tid < 128) ((float*)(ws + OFF_BC3))[tid] = (tid < 50) ? bc3[tid] : 0.f;
        return;
    }
    if (bid >= 4706) {           // x0 prep: (B,6,N) f32 -> (M x 64) f16 K-contig, zero pad
        int m = (bid - 4706) * 256 + tid;
        int b = m >> 11, n = m & 2047;
        const float* ps = pts + (size_t)b * 6 * 2048 + n;
        _Float16 tmp[64];
#pragma unroll
        for (int c = 0; c < 64; ++c) tmp[c] = (_Float16)0.f;
#pragma unroll
        for (int c = 0; c < 6; ++c) tmp[c] = (_Float16)ps[(size_t)c << 11];
        _Float16* dst = (_Float16*)(ws + OFF_X0) + (size_t)m * 64;
#pragma unroll
        for (int v = 0; v < 8; ++v) *(f16x8*)(dst + v * 8) = *(const f16x8*)(tmp + v * 8);
        return;
    }

    int id, base;
    if      (bid < 32)   { id = 0;  base = 0;    }
    else if (bid < 96)   { id = 1;  base = 32;   }
    else if (bid < 160)  { id = 2;  base = 96;   }
    else if (bid < 224)  { id = 3;  base = 160;  }
    else if (bid < 288)  { id = 4;  base = 224;  }
    else if (bid < 352)  { id = 5;  base = 288;  }
    else if (bid < 416)  { id = 6;  base = 352;  }
    else if (bid < 480)  { id = 7;  base = 416;  }
    else if (bid < 2016) { id = 8;  base = 480;  }
    else if (bid < 4064) { id = 9;  base = 2016; }
    else if (bid < 4576) { id = 10; base = 4064; }
    else                 { id = 11; base = 4576; }

    const float* src = nullptr; const float* g = nullptr; _Float16* dst = nullptr;
    int O = 0, K = 0, lds = 0, Kp = 0;
    switch (id) {
        case 0:  src = We1; g = ge1; O = 128; K = 6;    lds = 6;    Kp = 64;   dst = (_Float16*)(ws + OFF_WE1); break;
        case 1:  src = We2; g = ge2; O = 128; K = 128;  lds = 128;  Kp = 128;  dst = (_Float16*)(ws + OFF_WE2); break;
        case 2: case 3: case 4: {
            int i = id - 2;
            src = W1 + (size_t)i * 16384; g = g1 + i * 128; O = 128; K = 128; lds = 128; Kp = 128;
            dst = (_Float16*)(ws + OFF_W1) + (size_t)i * 16384; break; }
        case 5: case 6: case 7: {
            int i = id - 5;
            src = W2 + (size_t)i * 16384; g = g2 + i * 128; O = 128; K = 128; lds = 128; Kp = 128;
            dst = (_Float16*)(ws + OFF_W2) + (size_t)i * 16384; break; }
        case 8:  src = Wf;  g = gf;  O = 1024; K = 384;  lds = 384;  Kp = 384;  dst = (_Float16*)(ws + OFF_WF);  break;
        case 9:  src = Wc1; g = gc1; O = 512;  K = 1024; lds = 3136; Kp = 1024; dst = (_Float16*)(ws + OFF_WC1); break;
        case 10: src = Wc2; g = gc2; O = 256;  K = 512;  lds = 512;  Kp = 512;  dst = (_Float16*)(ws + OFF_WC2); break;
        default: src = Wc3; g = nullptr; O = 50; K = 256; lds = 256; Kp = 256;  dst = (_Float16*)(ws + OFF_WC3); break;
    }
    int e = (bid - base) * 256 + tid;
    int o = e / Kp, k = e - o * Kp;
    float v = 0.f;
    if (o < O && k < K) {
        v = src[(size_t)o * lds + k];
        if (g) v *= g[o];
    }
    dst[e] = (_Float16)v;
}

// ---------------- KNN v7: fused select+collect, in-wave bitonic tournament merge ----------------
DEVINL float knn_dist(const float4 pq, const float4 pm) {
    float t = pq.x * pm.x;
    t = fmaf(pq.y, pm.y, t);
    t = fmaf(pq.z, pm.z, t);
    return fmaf(-2.f, t, pm.w);
}

#define KNN_DINS(X) do { \
    const float x_ = (X); \
    d15 = __builtin_amdgcn_fmed3f(x_, d14, d15); \
    d14 = __builtin_amdgcn_fmed3f(x_, d13, d14); \
    d13 = __builtin_amdgcn_fmed3f(x_, d12, d13); \
    d12 = __builtin_amdgcn_fmed3f(x_, d11, d12); \
    d11 = __builtin_amdgcn_fmed3f(x_, d10, d11); \
    d10 = __builtin_amdgcn_fmed3f(x_, d9,  d10); \
    d9  = __builtin_amdgcn_fmed3f(x_, d8,  d9);  \
    d8  = __builtin_amdgcn_fmed3f(x_, d7,  d8);  \
    d7  = __builtin_amdgcn_fmed3f(x_, d6,  d7);  \
    d6  = __builtin_amdgcn_fmed3f(x_, d5,  d6);  \
    d5  = __builtin_amdgcn_fmed3f(x_, d4,  d5);  \
    d4  = __builtin_amdgcn_fmed3f(x_, d3,  d4);  \
    d3  = __builtin_amdgcn_fmed3f(x_, d2,  d3);  \
    d2  = __builtin_amdgcn_fmed3f(x_, d1,  d2);  \
    d1  = __builtin_amdgcn_fmed3f(x_, d0,  d1);  \
    d0  = __builtin_amdgcn_fmed3f(x_, -3.4e38f, d0); \
} while (0)

// compare-exchange (ascending)
#define KNN_CE(A, B) { const float lo_ = fminf(A, B), hi_ = fmaxf(A, B); A = lo_; B = hi_; }

// merge own ascending d0..d15 with lane^OFF's ascending list, keep lowest 16 sorted.
// e_i = min(A_i, B_{15-i}) is bitonic and contains the lowest 16; then 4-stage clean.
#define KNN_MERGE(OFF) do { \
    const float n0  = __shfl_xor(d0,  OFF), n1  = __shfl_xor(d1,  OFF), \
                n2  = __shfl_xor(d2,  OFF), n3  = __shfl_xor(d3,  OFF), \
                n4  = __shfl_xor(d4,  OFF), n5  = __shfl_xor(d5,  OFF), \
                n6  = __shfl_xor(d6,  OFF), n7  = __shfl_xor(d7,  OFF), \
                n8  = __shfl_xor(d8,  OFF), n9  = __shfl_xor(d9,  OFF), \
                n10 = __shfl_xor(d10, OFF), n11 = __shfl_xor(d11, OFF), \
                n12 = __shfl_xor(d12, OFF), n13 = __shfl_xor(d13, OFF), \
                n14 = __shfl_xor(d14, OFF), n15 = __shfl_xor(d15, OFF); \
    d0  = fminf(d0,  n15); d1  = fminf(d1,  n14); d2  = fminf(d2,  n13); d3  = fminf(d3,  n12); \
    d4  = fminf(d4,  n11); d5  = fminf(d5,  n10); d6  = fminf(d6,  n9);  d7  = fminf(d7,  n8);  \
    d8  = fminf(d8,  n7);  d9  = fminf(d9,  n6);  d10 = fminf(d10, n5);  d11 = fminf(d11, n4);  \
    d12 = fminf(d12, n3);  d13 = fminf(d13, n2);  d14 = fminf(d14, n1);  d15 = fminf(d15, n0);  \
    KNN_CE(d0, d8)  KNN_CE(d1, d9)  KNN_CE(d2, d10) KNN_CE(d3, d11) \
    KNN_CE(d4, d12) KNN_CE(d5, d13) KNN_CE(d6, d14) KNN_CE(d7, d15) \
    KNN_CE(d0, d4)  KNN_CE(d1, d5)  KNN_CE(d2, d6)  KNN_CE(d3, d7)  \
    KNN_CE(d8, d12) KNN_CE(d9, d13) KNN_CE(d10,d14) KNN_CE(d11,d15) \
    KNN_CE(d0, d2)  KNN_CE(d1, d3)  KNN_CE(d4, d6)  KNN_CE(d5, d7)  \
    KNN_CE(d8, d10) KNN_CE(d9, d11) KNN_CE(d12,d14) KNN_CE(d13,d15) \
    KNN_CE(d0, d1)  KNN_CE(d2, d3)  KNN_CE(d4, d5)  KNN_CE(d6, d7)  \
    KNN_CE(d8, d9)  KNN_CE(d10,d11) KNN_CE(d12,d13) KNN_CE(d14,d15) \
} while (0)

__global__ __launch_bounds__(256) void knn_kernel(const float* __restrict__ pts, int* __restrict__ idxout)
{
    __shared__ float4 P[2048];       // 32KB, stays intact for the rescan
    __shared__ int    cnt[32];
    const int tid = threadIdx.x;
    const int b = blockIdx.x;
    const float* pb = pts + (size_t)b * 6 * 2048;
    for (int i = tid; i < 2048; i += 256) {
        float x = pb[i];
        float y = pb[2048 + i];
        float z = pb[4096 + i];
        P[i] = make_float4(x, y, z, x * x + y * y + z * z);
    }
    if (tid < 32) cnt[tid] = 0;
    __syncthreads();

    const int p = tid & 7;          // candidate partition (m == 8*it + p)
    const int g = tid >> 3;         // query within block (0..31)
    const int q = blockIdx.y * 32 + g;
    const float4 pq = P[q];

    float d0 = 3.4e38f, d1 = 3.4e38f, d2 = 3.4e38f, d3 = 3.4e38f,
          d4 = 3.4e38f, d5 = 3.4e38f, d6 = 3.4e38f, d7 = 3.4e38f,
          d8 = 3.4e38f, d9 = 3.4e38f, d10 = 3.4e38f, d11 = 3.4e38f,
          d12 = 3.4e38f, d13 = 3.4e38f, d14 = 3.4e38f, d15 = 3.4e38f;

    float4 nxt = P[p];
#pragma unroll 2
    for (int it = 0; it < 256; ++it) {
        const float4 pm = nxt;
        const int m = it * 8 + p;
        nxt = P[(m + 8) & 2047];    // prefetch next candidate (wraps harmlessly on last)
        const float dd = knn_dist(pq, pm);
        if (__any(dd < d15)) {      // wave-uniform skip when no lane would insert
            KNN_DINS(dd);
        }
    }

    // tournament merge of the 8 partition lists (lanes p=0..7 of each query group)
    KNN_MERGE(1);
    KNN_MERGE(2);
    KNN_MERGE(4);
    // every lane now holds the global sorted top-16 distances; d15 = threshold

    // rescan with the threshold; same P, same knn_dist => bit-identical distances
    const float t = d15;
    int* op = idxout + (((size_t)(b << 11) + q) << 4);
    float4 nxt2 = P[p];
    for (int it = 0; it < 256; ++it) {
        const float4 pm = nxt2;
        const int m = it * 8 + p;
        nxt2 = P[(m + 8) & 2047];
        const float d = knn_dist(pq, pm);
        if (d <= t) {
            const int pos = atomicAdd(&cnt[g], 1);
            if (pos < 16) op[pos] = m;   // order-scrambled: consumer is a max over the set
        }
    }
}

// ---------------- GEMM v3: TM(64|128) x 128o tile, BK=64, global_load_lds staging,
// LDS-staged coalesced f16 store epilogue; f32 path stores transposed to (B,50,N).
template<int TM>
__global__ __launch_bounds__(256) void gemm_tile(
    const _Float16* __restrict__ W, const _Float16* __restrict__ X,
    _Float16* __restrict__ Y, float* __restrict__ Y32,
    const float* __restrict__ bias, const _Float16* __restrict__ Res,
    int Kp, int ldX, int xoff, int ldY, int yoff, int Opad,
    int act, int biasPerBatch, int ldR, int roff, int Olimit)
{
    constexpr int MI = TM / 32;                 // m-frags per wave
    __shared__ _Float16 SH[128 * 64 + TM * 64]; // As | Bs ; reused as output tile
    _Float16* As = SH;
    _Float16* Bs = SH + 128 * 64;

    const int tid  = threadIdx.x;
    const int lane = tid & 63, wave = tid >> 6;
    const int r = lane & 15, quad = lane >> 4;
    const int m_blk = blockIdx.x * TM, o_blk = blockIdx.y * 128;
    const int oh = (wave >> 1) * 64, mh = (wave & 1) * (TM / 2);

    f32x4 acc[4][MI];
#pragma unroll
    for (int a = 0; a < 4; ++a)
#pragma unroll
        for (int c = 0; c < MI; ++c) acc[a][c] = (f32x4){0.f, 0.f, 0.f, 0.f};

    const int srow  = wave * 8 + (lane >> 3);
    const int sslot = lane & 7;

    for (int k0 = 0; k0 < Kp; k0 += 64) {
        __syncthreads();
#pragma unroll
        for (int t = 0; t < 4; ++t) {           // A: 128 rows
            const int rowA = t * 32 + srow;
            const int gk = k0 + ((sslot ^ (rowA & 7)) << 3);
            const _Float16* gA = W + (size_t)(o_blk + rowA) * Kp + gk;
            __builtin_amdgcn_global_load_lds(
                (const __attribute__((address_space(1))) unsigned int*)gA,
                (__attribute__((address_space(3))) unsigned int*)(As + t * 2048 + wave * 512),
                16, 0, 0);
        }
#pragma unroll
        for (int t = 0; t < TM / 32; ++t) {     // B: TM rows
            const int rowB = t * 32 + srow;
            const int gk = k0 + ((sslot ^ (rowB & 7)) << 3);
            const _Float16* gB = X + (size_t)(m_blk + rowB) * ldX + xoff + gk;
            __builtin_amdgcn_global_load_lds(
                (const __attribute__((address_space(1))) unsigned int*)gB,
                (__attribute__((address_space(3))) unsigned int*)(Bs + t * 2048 + wave * 512),
                16, 0, 0);
        }
        __syncthreads();
#pragma unroll
        for (int ks = 0; ks < 2; ++ks) {
            f16x8 af[4], bf[MI];
#pragma unroll
            for (int oi = 0; oi < 4; ++oi) {
                const int row = oh + oi * 16 + r;
                const int slot = (ks * 4 + quad) ^ (row & 7);
                af[oi] = *(const f16x8*)(As + row * 64 + slot * 8);
            }
#pragma unroll
            for (int mi = 0; mi < MI; ++mi) {
                const int row = mh + mi * 16 + r;
                const int slot = (ks * 4 + quad) ^ (row & 7);
                bf[mi] = *(const f16x8*)(Bs + row * 64 + slot * 8);
            }
#pragma unroll
            for (int oi = 0; oi < 4; ++oi)
#pragma unroll
                for (int mi = 0; mi < MI; ++mi)
                    acc[oi][mi] = __builtin_amdgcn_mfma_f32_16x16x32_f16(af[oi], bf[mi], acc[oi][mi], 0, 0, 0);
        }
    }

    const int bb = biasPerBatch ? (m_blk >> 11) * Opad : 0;
    __syncthreads();   // done reading As/Bs; SH is reusable

    if (Y32) {
        // f32 path: store transposed to (B, 50, N): Y32[(b*50+o)*2048 + n], o < Olimit
#pragma unroll
        for (int oi = 0; oi < 4; ++oi) {
            const int og = o_blk + oh + oi * 16 + quad * 4;
            const f32x4 bv = *(const f32x4*)(bias + bb + og);
#pragma unroll
            for (int mi = 0; mi < MI; ++mi) {
                const int m = m_blk + mh + mi * 16 + r;
                const int bidx = m >> 11, n = m & 2047;
                f32x4 v = acc[oi][mi] + bv;
#pragma unroll
                for (int j = 0; j < 4; ++j) {
                    float x = v[j];
                    if (act == 1)      x = (x > 0.f) ? x : 0.0f;
                    else if (act == 2) x = (x > 0.f) ? x : 0.2f * x;
                    const int o = og + j;
                    if (o < Olimit)
                        Y32[((size_t)(bidx * 50 + o) << 11) + n] = x;
                }
            }
        }
        return;
    }

    // f16 path: stage [TM][128] tile in LDS (XOR-swizzled), then coalesced writeback
    _Float16* OT = SH;
#pragma unroll
    for (int oi = 0; oi < 4; ++oi) {
        const int ol = oh + oi * 16 + quad * 4;       // local o (0..127), 4-aligned
        const f32x4 bv = *(const f32x4*)(bias + bb + o_blk + ol);
#pragma unroll
        for (int mi = 0; mi < MI; ++mi) {
            const int row = mh + mi * 16 + r;         // local m
            f32x4 v = acc[oi][mi] + bv;
            if (Res) {
                f16x4 rr = *(const f16x4*)(Res + (size_t)(m_blk + row) * ldR + roff + o_blk + ol);
#pragma unroll
                for (int j = 0; j < 4; ++j) v[j] += (float)rr[j];
            }
            f16x4 ov;
#pragma unroll
            for (int j = 0; j < 4; ++j) {
                float x = v[j];
                if (act == 1)      x = (x > 0.f) ? x : 0.0f;
                else if (act == 2) x = (x > 0.f) ? x : 0.2f * x;
                ov[j] = (_Float16)x;
            }
            const int s = ((ol >> 2) ^ (row & 31)) << 2;   // swizzled 8B slot
            *(f16x4*)(OT + row * 128 + s) = ov;
        }
    }
    __syncthreads();
#pragma unroll
    for (int it2 = 0; it2 < TM / 16; ++it2) {
        const int row = it2 * 16 + (tid >> 4);
        const int c = tid & 15;                        // 8 f16 per lane, contiguous
        const int s0 = ((c * 2) ^ (row & 31)) << 2;
        const int s1 = ((c * 2 + 1) ^ (row & 31)) << 2;
        f16x4 a = *(const f16x4*)(OT + row * 128 + s0);
        f16x4 b2 = *(const f16x4*)(OT + row * 128 + s1);
        f16x8 o8;
        o8[0] = a[0]; o8[1] = a[1]; o8[2] = a[2]; o8[3] = a[3];
        o8[4] = b2[0]; o8[5] = b2[1]; o8[6] = b2[2]; o8[7] = b2[3];
        *(f16x8*)(Y + (size_t)(m_blk + row) * ldY + yoff + o_blk + c * 8) = o8;
    }
}

// ---------------- neighbor gather + channel max (relu outputs => ushort-monotonic f16 bits) ----------------
typedef short s16x8 __attribute__((ext_vector_type(8)));
__global__ __launch_bounds__(256) void gather_max_kernel(
    const short* __restrict__ T, const int* __restrict__ idx, short* __restrict__ Mo)
{
    const int tid = threadIdx.x;
    const int p = blockIdx.x * 16 + (tid >> 4);
    const int l = tid & 15;
    const int b = p >> 11;
    const int* ip = idx + (size_t)p * 16;
    size_t row = (size_t)((b << 11) + ip[0]);
    s16x8 cur = *(const s16x8*)(T + row * 128 + l * 8);
    unsigned short best[8];
#pragma unroll
    for (int e = 0; e < 8; ++e) best[e] = (unsigned short)cur[e];
#pragma unroll
    for (int j = 1; j < 16; ++j) {
        row = (size_t)((b << 11) + ip[j]);
        s16x8 v = *(const s16x8*)(T + row * 128 + l * 8);
#pragma unroll
        for (int e = 0; e < 8; ++e) {
            unsigned short u = (unsigned short)v[e];
            if (u > best[e]) best[e] = u;
        }
    }
    s16x8 ov;
#pragma unroll
    for (int e = 0; e < 8; ++e) ov[e] = (short)best[e];
    *(s16x8*)(Mo + (size_t)p * 128 + l * 8) = ov;
}

// ---------------- pooling reduction over n (stage 1: per-256-chunk partials) ----------------
__global__ __launch_bounds__(256) void reduce1_kernel(const _Float16* __restrict__ xf, float* __restrict__ pmax, float* __restrict__ psum)
{
    const int b = blockIdx.x, oc = blockIdx.y, ch = blockIdx.z, tid = threadIdx.x;
    const int o = oc * 256 + tid;
    const _Float16* p = xf + ((size_t)(b << 11) + ch * 256) * 1024 + o;
    float mx = -3.4e38f, sm = 0.f;
    for (int n = 0; n < 256; ++n) {
        float v = (float)p[(size_t)n * 1024];
        mx = fmaxf(mx, v); sm += v;
    }
    pmax[((size_t)(b * 8 + ch) << 10) + o] = mx;
    psum[((size_t)(b * 8 + ch) << 10) + o] = sm;
}

// ---------------- per-batch constant vector for Wc1 (absorbs reduce2 + label path) ----------------
__global__ __launch_bounds__(256) void cvec_kernel(
    const float* __restrict__ label, const float* __restrict__ Wl, const float* __restrict__ gl, const float* __restrict__ bl,
    const float* __restrict__ Wc1, const float* __restrict__ bc1, const float* __restrict__ gc1, const float* __restrict__ bb1,
    const float* __restrict__ pmax, const float* __restrict__ psum, float* __restrict__ cvec)
{
    __shared__ float v[2112];
    __shared__ float red[256];
    const int b = blockIdx.x, og = blockIdx.y, tid = threadIdx.x;
    for (int i = tid; i < 1024; i += 256) {
        float mx = -3.4e38f, sm = 0.f;
#pragma unroll
        for (int c = 0; c < 8; ++c) {
            mx = fmaxf(mx, pmax[((size_t)(b * 8 + c) << 10) + i]);
            sm += psum[((size_t)(b * 8 + c) << 10) + i];
        }
        v[i] = mx;
        v[1024 + i] = sm * (1.f / 2048.f);
    }
    if (tid < 64) {
        float s = 0.f;
        for (int i = 0; i < 16; ++i) s += Wl[tid * 16 + i] * label[b * 16 + i];
        s = gl[tid] * s + bl[tid];
        v[2048 + tid] = (s > 0.f) ? s : 0.2f * s;
    }
    __syncthreads();
    const int o = og * 64 + (tid >> 2), part = tid & 3;
    const float* wrow = Wc1 + (size_t)o * 3136 + 1024 + part * 528;
    float s = 0.f;
    for (int j = 0; j < 528; ++j) s += wrow[j] * v[part * 528 + j];
    red[tid] = s;
    __syncthreads();
    if (part == 0) {
        float tot = red[tid] + red[tid + 1] + red[tid + 2] + red[tid + 3];
        cvec[((size_t)b << 9) + o] = gc1[o] * (tot + bc1[o]) + bb1[o];
    }
}

// ---------------- launch ----------------
extern "C" void kernel_launch(void* const* d_in, const int* in_sizes, int n_in,
                              void* d_out, int out_size, void* d_ws, size_t ws_size,
                              hipStream_t stream)
{
    (void)in_sizes; (void)n_in; (void)out_size; (void)ws_size;
    const float* points = (const float*)d_in[0];
    const float* label  = (const float*)d_in[1];
    const float* We1 = (const float*)d_in[2];
    const float* ge1 = (const float*)d_in[3];
    const float* be1 = (const float*)d_in[4];
    const float* We2 = (const float*)d_in[5];
    const float* ge2 = (const float*)d_in[6];
    const float* be2 = (const float*)d_in[7];
    const float* W1  = (const float*)d_in[8];
    const float* g1  = (const float*)d_in[9];
    const float* b1  = (const float*)d_in[10];
    const float* W2  = (const float*)d_in[11];
    const float* g2  = (const float*)d_in[12];
    const float* b2  = (const float*)d_in[13];
    const float* Wf  = (const float*)d_in[14];
    const float* gf  = (const float*)d_in[15];
    const float* bfv = (const float*)d_in[16];
    const float* Wl  = (const float*)d_in[17];
    const float* gl  = (const float*)d_in[18];
    const float* bl  = (const float*)d_in[19];
    const float* Wc1 = (const float*)d_in[20];
    const float* bc1 = (const float*)d_in[21];
    const float* gc1 = (const float*)d_in[22];
    const float* bb1 = (const float*)d_in[23];
    const float* Wc2 = (const float*)d_in[24];
    const float* bc2 = (const float*)d_in[25];
    const float* gc2 = (const float*)d_in[26];
    const float* bb2 = (const float*)d_in[27];
    const float* Wc3 = (const float*)d_in[28];
    const float* bc3 = (const float*)d_in[29];

    char* ws = (char*)d_ws;
    _Float16* hT  = (_Float16*)(ws + OFF_HT);
    _Float16* tT  = (_Float16*)(ws + OFF_TT);
    _Float16* mT  = (_Float16*)(ws + OFF_MT);
    _Float16* xct = (_Float16*)(ws + OFF_XCAT);
    _Float16* xf  = (_Float16*)(ws + OFF_XF);
    _Float16* c1  = (_Float16*)(ws + OFF_C1);
    _Float16* c2  = (_Float16*)(ws + OFF_C2);
    int*      idx = (int*)     (ws + OFF_IDX);
    _Float16* x0  = (_Float16*)(ws + OFF_X0);

    _Float16* wE1 = (_Float16*)(ws + OFF_WE1);
    _Float16* wE2 = (_Float16*)(ws + OFF_WE2);
    _Float16* w1f = (_Float16*)(ws + OFF_W1);
    _Float16* w2f = (_Float16*)(ws + OFF_W2);
    _Float16* wF  = (_Float16*)(ws + OFF_WF);
    _Float16* wC1 = (_Float16*)(ws + OFF_WC1);
    _Float16* wC2 = (_Float16*)(ws + OFF_WC2);
    _Float16* wC3 = (_Float16*)(ws + OFF_WC3);
    float* bC2 = (float*)(ws + OFF_BC2);
    float* bC3 = (float*)(ws + OFF_BC3);
    float* cv  = (float*)(ws + OFF_CVEC);
    float* pmx = (float*)(ws + OFF_PMAX);
    float* psm = (float*)(ws + OFF_PSUM);

    // prep (weights + biases + x0, one launch)
    fold_all_kernel<<<dim3(4834), 256, 0, stream>>>(We1, ge1, We2, ge2, W1, g1, W2, g2,
                                                    Wf, gf, Wc1, gc1, Wc2, gc2, Wc3,
                                                    gc2, bc2, bb2, bc3, points, ws);
    knn_kernel<<<dim3(BB, NN / 32), 256, 0, stream>>>(points, idx);

    // e1: x0(Mx64,pad) -> tT(Mx128), relu
    gemm_tile<64><<<dim3(512, 1), 256, 0, stream>>>(wE1, x0, tT, nullptr, be1, nullptr, 64, 64, 0, 128, 0, 128, 1, 0, 0, 0, 128);
    // e2: tT -> hT, relu
    gemm_tile<64><<<dim3(512, 1), 256, 0, stream>>>(wE2, tT, hT, nullptr, be2, nullptr, 128, 128, 0, 128, 0, 128, 1, 0, 0, 0, 128);

    for (int i = 0; i < 3; ++i) {
        const _Float16* hin = (i == 0) ? hT : xct;
        int ldH  = (i == 0) ? 128 : 384;
        int offH = (i == 0) ? 0 : (i - 1) * 128;
        // t = relu(bn(W1 h))
        gemm_tile<64><<<dim3(512, 1), 256, 0, stream>>>(w1f + (size_t)i * 16384, hin, tT, nullptr, b1 + i * 128, nullptr,
                                                        128, ldH, offH, 128, 0, 128, 1, 0, 0, 0, 128);
        // m = neighbor max
        gather_max_kernel<<<dim3(MM / 16), 256, 0, stream>>>((const short*)tT, idx, (short*)mT);
        // h' = relu(bn(W2 m) + h) -> xcat slice i
        gemm_tile<64><<<dim3(512, 1), 256, 0, stream>>>(w2f + (size_t)i * 16384, mT, xct, nullptr, b2 + i * 128, hin,
                                                        128, 128, 0, 384, i * 128, 128, 1, 0, ldH, offH, 128);
    }

    // xf = leaky(bn(Wf xcat))
    gemm_tile<128><<<dim3(256, 8), 256, 0, stream>>>(wF, xct, xf, nullptr, bfv, nullptr, 384, 384, 0, 1024, 0, 1024, 2, 0, 0, 0, 1024);

    // pooling partials + per-batch classifier constant (cvec absorbs reduce2)
    reduce1_kernel<<<dim3(BB, 4, 8), 256, 0, stream>>>(xf, pmx, psm);
    cvec_kernel<<<dim3(BB, 8), 256, 0, stream>>>(label, Wl, gl, bl, Wc1, bc1, gc1, bb1, pmx, psm, cv);

    // c1 = relu(gc1*Wc1[:, :1024] xf + cvec[b])
    gemm_tile<128><<<dim3(256, 4), 256, 0, stream>>>(wC1, xf, c1, nullptr, cv, nullptr, 1024, 1024, 0, 512, 0, 512, 1, 1, 0, 0, 512);
    // c2 = relu(bn(Wc2 c1 + bc2))
    gemm_tile<128><<<dim3(256, 2), 256, 0, stream>>>(wC2, c1, c2, nullptr, bC2, nullptr, 512, 512, 0, 256, 0, 256, 1, 0, 0, 0, 256);
    // c3 = Wc3 c2 + bc3 (no act), f32, stored transposed directly to (B,50,N) output
    gemm_tile<128><<<dim3(256, 1), 256, 0, stream>>>(wC3, c2, nullptr, (float*)d_out, bC3, nullptr, 256, 256, 0, 0, 0, 128, 0, 0, 0, 0, 50);
}